// Round 1
// baseline (5790.323 us; speedup 1.0000x reference)
//
#include <hip/hip_runtime.h>

#define HID 128
#define OUTD 64
#define FMDIM 404

// ---------------- encoder: out = LN(relu(x @ W + b)) ----------------
// block = 128 threads, R rows per block. in_dim runtime (16 or 404).
template<int R>
__global__ void enc_kernel(const float* __restrict__ x, const float* __restrict__ W,
                           const float* __restrict__ bias, const float* __restrict__ g,
                           const float* __restrict__ beta, float* __restrict__ out,
                           int n, int in_dim)
{
    __shared__ float xs[R][FMDIM];
    __shared__ float sh[4];
    const int j = threadIdx.x;           // 0..127
    const int base = blockIdx.x * R;

    for (int r = 0; r < R; ++r) {
        int row = base + r;
        if (row < n) {
            for (int k = j; k < in_dim; k += 128)
                xs[r][k] = x[(size_t)row * in_dim + k];
        }
    }
    __syncthreads();

    float acc[R];
#pragma unroll
    for (int r = 0; r < R; ++r) acc[r] = bias[j];
    for (int k = 0; k < in_dim; ++k) {
        float w = W[(size_t)k * HID + j];
#pragma unroll
        for (int r = 0; r < R; ++r) acc[r] = fmaf(xs[r][k], w, acc[r]);
    }
#pragma unroll
    for (int r = 0; r < R; ++r) acc[r] = fmaxf(acc[r], 0.f);

    const float gv = g[j], bv = beta[j];
    for (int r = 0; r < R; ++r) {
        float v = acc[r];
        float s = v, q = v * v;
        for (int o = 32; o > 0; o >>= 1) { s += __shfl_down(s, o); q += __shfl_down(q, o); }
        if ((j & 63) == 0) { sh[(j >> 6) * 2] = s; sh[(j >> 6) * 2 + 1] = q; }
        __syncthreads();
        float S = sh[0] + sh[2], Q = sh[1] + sh[3];
        float mu = S * (1.f / HID);
        float rstd = rsqrtf(Q * (1.f / HID) - mu * mu + 1e-5f);
        int row = base + r;
        if (row < n) out[(size_t)row * HID + j] = (v - mu) * rstd * gv + bv;
        __syncthreads();
    }
}

// ---------------- degree count ----------------
__global__ void deg_kernel(const int* __restrict__ src, const int* __restrict__ dst,
                           float* __restrict__ deg_u, float* __restrict__ deg_m, int E)
{
    int e = blockIdx.x * blockDim.x + threadIdx.x;
    if (e < E) {
        atomicAdd(&deg_u[src[e]], 1.f);
        atomicAdd(&deg_m[dst[e]], 1.f);
    }
}

// ---------------- scatter-add of D-dim rows: out[gdst[e]] += feat[gsrc[e]] ----------------
template<int D>
__global__ void scatter_add_kernel(const float* __restrict__ feat,
                                   const int* __restrict__ gsrc, const int* __restrict__ gdst,
                                   float* __restrict__ out, int E)
{
    constexpr int C = D / 4;                 // float4 chunks per row
    int tid = blockIdx.x * blockDim.x + threadIdx.x;
    int e = tid / C, c = tid % C;
    if (e >= E) return;
    int s = gsrc[e], d = gdst[e];
    float4 v = *reinterpret_cast<const float4*>(feat + (size_t)s * D + (size_t)c * 4);
    float* o = out + (size_t)d * D + (size_t)c * 4;
    atomicAdd(o + 0, v.x);
    atomicAdd(o + 1, v.y);
    atomicAdd(o + 2, v.z);
    atomicAdd(o + 3, v.w);
}

// ---------------- layer-1 combine: out = relu(LN(agg/deg @ wl + bl + feat @ wr)) ----------------
// block = 128 threads, R rows. In-place over agg is safe (row-local).
template<int R>
__global__ void sage1_kernel(const float* __restrict__ agg, const float* __restrict__ deg,
                             const float* __restrict__ feat,
                             const float* __restrict__ wl, const float* __restrict__ bl,
                             const float* __restrict__ wr,
                             const float* __restrict__ g, const float* __restrict__ beta,
                             float* __restrict__ out, int n)
{
    __shared__ float ms[R][HID];
    __shared__ float fs[R][HID];
    __shared__ float sh[4];
    const int j = threadIdx.x;
    const int base = blockIdx.x * R;
    for (int r = 0; r < R; ++r) {
        int row = base + r;
        if (row < n) {
            float idg = 1.f / fmaxf(deg[row], 1.f);
            ms[r][j] = agg[(size_t)row * HID + j] * idg;
            fs[r][j] = feat[(size_t)row * HID + j];
        }
    }
    __syncthreads();
    float acc[R];
#pragma unroll
    for (int r = 0; r < R; ++r) acc[r] = bl[j];
    for (int k = 0; k < HID; ++k) {
        float a = wl[k * HID + j];
        float b = wr[k * HID + j];
#pragma unroll
        for (int r = 0; r < R; ++r) acc[r] = fmaf(ms[r][k], a, fmaf(fs[r][k], b, acc[r]));
    }
    const float gv = g[j], bv = beta[j];
    for (int r = 0; r < R; ++r) {
        float v = acc[r];
        float s = v, q = v * v;
        for (int o = 32; o > 0; o >>= 1) { s += __shfl_down(s, o); q += __shfl_down(q, o); }
        if ((j & 63) == 0) { sh[(j >> 6) * 2] = s; sh[(j >> 6) * 2 + 1] = q; }
        __syncthreads();
        float S = sh[0] + sh[2], Q = sh[1] + sh[3];
        float mu = S * (1.f / HID);
        float rstd = rsqrtf(Q * (1.f / HID) - mu * mu + 1e-5f);
        float ov = fmaxf((v - mu) * rstd * gv + bv, 0.f);
        int row = base + r;
        if (row < n) out[(size_t)row * HID + j] = ov;
        __syncthreads();
    }
}

// ---------------- projection: out = feat @ w  (128 -> 64), no bias ----------------
template<int R>
__global__ void proj_kernel(const float* __restrict__ feat, const float* __restrict__ w,
                            float* __restrict__ out, int n)
{
    __shared__ float fs[R][HID];
    const int j = threadIdx.x;           // 0..63
    const int base = blockIdx.x * R;
    for (int r = 0; r < R; ++r) {
        int row = base + r;
        if (row < n)
            for (int k = j; k < HID; k += 64) fs[r][k] = feat[(size_t)row * HID + k];
    }
    __syncthreads();
    float acc[R];
#pragma unroll
    for (int r = 0; r < R; ++r) acc[r] = 0.f;
    for (int k = 0; k < HID; ++k) {
        float wv = w[k * OUTD + j];
#pragma unroll
        for (int r = 0; r < R; ++r) acc[r] = fmaf(fs[r][k], wv, acc[r]);
    }
    for (int r = 0; r < R; ++r) {
        int row = base + r;
        if (row < n) out[(size_t)row * OUTD + j] = acc[r];
    }
}

// ---------------- final: out = LN(agg/deg + bl + feat @ wr) ----------------
// agg is already projected to 64. block = 64 threads, R rows. LN over 64 = wave reduce.
template<int R>
__global__ void final_kernel(const float* __restrict__ agg, const float* __restrict__ deg,
                             const float* __restrict__ feat,
                             const float* __restrict__ bl, const float* __restrict__ wr,
                             const float* __restrict__ g, const float* __restrict__ beta,
                             float* __restrict__ out, int n)
{
    __shared__ float fs[R][HID];
    const int j = threadIdx.x;           // 0..63
    const int base = blockIdx.x * R;
    for (int r = 0; r < R; ++r) {
        int row = base + r;
        if (row < n)
            for (int k = j; k < HID; k += 64) fs[r][k] = feat[(size_t)row * HID + k];
    }
    __syncthreads();
    float acc[R];
#pragma unroll
    for (int r = 0; r < R; ++r) {
        int row = base + r;
        if (row < n) {
            float idg = 1.f / fmaxf(deg[row], 1.f);
            acc[r] = agg[(size_t)row * OUTD + j] * idg + bl[j];
        } else acc[r] = 0.f;
    }
    for (int k = 0; k < HID; ++k) {
        float wv = wr[k * OUTD + j];
#pragma unroll
        for (int r = 0; r < R; ++r) acc[r] = fmaf(fs[r][k], wv, acc[r]);
    }
    const float gv = g[j], bv = beta[j];
    for (int r = 0; r < R; ++r) {
        float v = acc[r];
        float s = v, q = v * v;
        for (int o = 32; o > 0; o >>= 1) { s += __shfl_down(s, o); q += __shfl_down(q, o); }
        s = __shfl(s, 0); q = __shfl(q, 0);
        float mu = s * (1.f / OUTD);
        float rstd = rsqrtf(q * (1.f / OUTD) - mu * mu + 1e-5f);
        int row = base + r;
        if (row < n) out[(size_t)row * OUTD + j] = (v - mu) * rstd * gv + bv;
    }
}

extern "C" void kernel_launch(void* const* d_in, const int* in_sizes, int n_in,
                              void* d_out, int out_size, void* d_ws, size_t ws_size,
                              hipStream_t stream)
{
    const float* x_user   = (const float*)d_in[0];
    const float* x_movie  = (const float*)d_in[1];
    const int*   src      = (const int*)d_in[2];   // user ids
    const int*   dst      = (const int*)d_in[3];   // movie ids
    const float* enc_u_w  = (const float*)d_in[4];
    const float* enc_u_b  = (const float*)d_in[5];
    const float* enc_u_g  = (const float*)d_in[6];
    const float* enc_u_be = (const float*)d_in[7];
    const float* enc_m_w  = (const float*)d_in[8];
    const float* enc_m_b  = (const float*)d_in[9];
    const float* enc_m_g  = (const float*)d_in[10];
    const float* enc_m_be = (const float*)d_in[11];
    const float* c1_m_wl  = (const float*)d_in[12];
    const float* c1_m_bl  = (const float*)d_in[13];
    const float* c1_m_wr  = (const float*)d_in[14];
    const float* c1_u_wl  = (const float*)d_in[15];
    const float* c1_u_bl  = (const float*)d_in[16];
    const float* c1_u_wr  = (const float*)d_in[17];
    const float* ln1_u_g  = (const float*)d_in[18];
    const float* ln1_u_b  = (const float*)d_in[19];
    const float* ln1_m_g  = (const float*)d_in[20];
    const float* ln1_m_b  = (const float*)d_in[21];
    const float* c2_m_wl  = (const float*)d_in[22];
    const float* c2_m_bl  = (const float*)d_in[23];
    const float* c2_m_wr  = (const float*)d_in[24];
    const float* c2_u_wl  = (const float*)d_in[25];
    const float* c2_u_bl  = (const float*)d_in[26];
    const float* c2_u_wr  = (const float*)d_in[27];
    const float* ln2_u_g  = (const float*)d_in[28];
    const float* ln2_u_b  = (const float*)d_in[29];
    const float* ln2_m_g  = (const float*)d_in[30];
    const float* ln2_m_b  = (const float*)d_in[31];

    const int NU = in_sizes[0] / 16;
    const int NM = in_sizes[1] / FMDIM;
    const int E  = in_sizes[2];

    float* ws = (float*)d_ws;
    // layout (floats): hu[NU*128] | hm[NM*128] | am1[NM*128] | au1[NU*128] | deg_u[NU] | deg_m[NM]
    float* hu  = ws;
    float* hm  = hu  + (size_t)NU * HID;
    float* am1 = hm  + (size_t)NM * HID;
    float* au1 = am1 + (size_t)NM * HID;
    float* dgu = au1 + (size_t)NU * HID;
    float* dgm = dgu + NU;
    // layer-2 reuse: p_u + agg_u2 overlay hu; p_m + agg_m2 overlay hm
    float* pu  = hu;
    float* au2 = hu + (size_t)NU * OUTD;
    float* pm  = hm;
    float* am2 = hm + (size_t)NM * OUTD;
    float* m1  = am1;   // in-place
    float* u1  = au1;   // in-place

    float* out_u = (float*)d_out;
    float* out_m = out_u + (size_t)NU * OUTD;

    // zero agg buffers + degree counters (contiguous)
    hipMemsetAsync(am1, 0, ((size_t)NM * HID + (size_t)NU * HID + NU + NM) * sizeof(float), stream);

    // encoders
    enc_kernel<8><<<(NU + 7) / 8, 128, 0, stream>>>(x_user, enc_u_w, enc_u_b, enc_u_g, enc_u_be, hu, NU, 16);
    enc_kernel<8><<<(NM + 7) / 8, 128, 0, stream>>>(x_movie, enc_m_w, enc_m_b, enc_m_g, enc_m_be, hm, NM, FMDIM);

    // degrees
    deg_kernel<<<(E + 255) / 256, 256, 0, stream>>>(src, dst, dgu, dgm, E);

    // layer-1 aggregation (128-d)
    {
        int blk = (int)(((size_t)E * (HID / 4) + 255) / 256);
        scatter_add_kernel<HID><<<blk, 256, 0, stream>>>(hu, src, dst, am1, E);
        scatter_add_kernel<HID><<<blk, 256, 0, stream>>>(hm, dst, src, au1, E);
    }

    // layer-1 combine + LN + relu (in-place over agg buffers)
    sage1_kernel<8><<<(NM + 7) / 8, 128, 0, stream>>>(am1, dgm, hm, c1_m_wl, c1_m_bl, c1_m_wr, ln1_m_g, ln1_m_b, m1, NM);
    sage1_kernel<8><<<(NU + 7) / 8, 128, 0, stream>>>(au1, dgu, hu, c1_u_wl, c1_u_bl, c1_u_wr, ln1_u_g, ln1_u_b, u1, NU);

    // layer-2: project sources 128->64 BEFORE aggregating (mean is linear)
    proj_kernel<8><<<(NU + 7) / 8, 64, 0, stream>>>(u1, c2_m_wl, pu, NU);
    proj_kernel<8><<<(NM + 7) / 8, 64, 0, stream>>>(m1, c2_u_wl, pm, NM);

    hipMemsetAsync(au2, 0, (size_t)NU * OUTD * sizeof(float), stream);
    hipMemsetAsync(am2, 0, (size_t)NM * OUTD * sizeof(float), stream);

    {
        int blk = (int)(((size_t)E * (OUTD / 4) + 255) / 256);
        scatter_add_kernel<OUTD><<<blk, 256, 0, stream>>>(pu, src, dst, am2, E);
        scatter_add_kernel<OUTD><<<blk, 256, 0, stream>>>(pm, dst, src, au2, E);
    }

    // final combine + LN -> d_out (u first, then m)
    final_kernel<8><<<(NU + 7) / 8, 64, 0, stream>>>(au2, dgu, u1, c2_u_bl, c2_u_wr, ln2_u_g, ln2_u_b, out_u, NU);
    final_kernel<8><<<(NM + 7) / 8, 64, 0, stream>>>(am2, dgm, m1, c2_m_bl, c2_m_wr, ln2_m_g, ln2_m_b, out_m, NM);
}

// Round 2
// 1009.635 us; speedup vs baseline: 5.7351x; 5.7351x over previous
//
#include <hip/hip_runtime.h>

#define HID 128
#define OUTD 64
#define FMDIM 404

// ======================= encoder: out = LN(relu(x @ W + b)) =======================
template<int R>
__global__ void enc_kernel(const float* __restrict__ x, const float* __restrict__ W,
                           const float* __restrict__ bias, const float* __restrict__ g,
                           const float* __restrict__ beta, float* __restrict__ out,
                           int n, int in_dim)
{
    __shared__ float xs[R][FMDIM];
    __shared__ float sh[4];
    const int j = threadIdx.x;           // 0..127
    const int base = blockIdx.x * R;

    for (int r = 0; r < R; ++r) {
        int row = base + r;
        if (row < n) {
            for (int k = j; k < in_dim; k += 128)
                xs[r][k] = x[(size_t)row * in_dim + k];
        }
    }
    __syncthreads();

    float acc[R];
#pragma unroll
    for (int r = 0; r < R; ++r) acc[r] = bias[j];
    for (int k = 0; k < in_dim; ++k) {
        float w = W[(size_t)k * HID + j];
#pragma unroll
        for (int r = 0; r < R; ++r) acc[r] = fmaf(xs[r][k], w, acc[r]);
    }
#pragma unroll
    for (int r = 0; r < R; ++r) acc[r] = fmaxf(acc[r], 0.f);

    const float gv = g[j], bv = beta[j];
    for (int r = 0; r < R; ++r) {
        float v = acc[r];
        float s = v, q = v * v;
        for (int o = 32; o > 0; o >>= 1) { s += __shfl_down(s, o); q += __shfl_down(q, o); }
        if ((j & 63) == 0) { sh[(j >> 6) * 2] = s; sh[(j >> 6) * 2 + 1] = q; }
        __syncthreads();
        float S = sh[0] + sh[2], Q = sh[1] + sh[3];
        float mu = S * (1.f / HID);
        float rstd = rsqrtf(Q * (1.f / HID) - mu * mu + 1e-5f);
        int row = base + r;
        if (row < n) out[(size_t)row * HID + j] = (v - mu) * rstd * gv + bv;
        __syncthreads();
    }
}

// ======================= CSR build =======================
// Joint degree array: rows [0, NM) = movies (incoming from dst), rows [NM, NM+NU) = users.
__global__ void deg_csr_kernel(const int* __restrict__ src, const int* __restrict__ dst,
                               int* __restrict__ deg, int NM, int E)
{
    int e = blockIdx.x * blockDim.x + threadIdx.x;
    if (e < E) {
        atomicAdd(&deg[dst[e]], 1);
        atomicAdd(&deg[NM + src[e]], 1);
    }
}

// Block-level exclusive scan, chunk = 256 threads * 16 = 4096 elems. In-place safe.
__global__ void scan_partial_kernel(int* __restrict__ data, int* __restrict__ partials, int N)
{
    __shared__ int sh[256];
    const int tid = threadIdx.x;
    const int base = blockIdx.x * 4096 + tid * 16;
    int vals[16];
    int s = 0;
#pragma unroll
    for (int i = 0; i < 16; ++i) {
        int v = (base + i < N) ? data[base + i] : 0;
        vals[i] = s;                 // thread-local exclusive
        s += v;
    }
    sh[tid] = s;
    __syncthreads();
    for (int off = 1; off < 256; off <<= 1) {
        int t = 0;
        if (tid >= off) t = sh[tid - off];
        __syncthreads();
        sh[tid] += t;
        __syncthreads();
    }
    int excl = (tid == 0) ? 0 : sh[tid - 1];
    if (tid == 255) partials[blockIdx.x] = sh[255];
#pragma unroll
    for (int i = 0; i < 16; ++i)
        if (base + i < N) data[base + i] = excl + vals[i];
}

__global__ void scan_partials_kernel(int* __restrict__ partials, int nP)
{
    if (threadIdx.x == 0 && blockIdx.x == 0) {
        int run = 0;
        for (int p = 0; p < nP; ++p) { int t = partials[p]; partials[p] = run; run += t; }
    }
}

__global__ void scan_add_kernel(int* __restrict__ data, const int* __restrict__ partials,
                                int N, int total)
{
    int idx = blockIdx.x * blockDim.x + threadIdx.x;
    if (idx < N) data[idx] += partials[idx >> 12];
    if (idx == 0) data[N] = total;   // rowptr[N] = 2E
}

__global__ void fill_kernel(const int* __restrict__ src, const int* __restrict__ dst,
                            const int* __restrict__ rowptr, int* __restrict__ cursor,
                            int* __restrict__ nbr, int NM, int E)
{
    int e = blockIdx.x * blockDim.x + threadIdx.x;
    if (e >= E) return;
    int s = src[e], d = dst[e];
    int p0 = atomicAdd(&cursor[d], 1);
    nbr[rowptr[d] + p0] = s;
    int p1 = atomicAdd(&cursor[NM + s], 1);
    nbr[rowptr[NM + s] + p1] = d;
}

// ======================= CSR mean-gather =======================
// out[row] = mean over neighbors of feat[nbr], D floats per row. float4 lanes.
template<int D>
__global__ void gather_mean_kernel(const float* __restrict__ feat,
                                   const int* __restrict__ rowptr, int rowbase,
                                   const int* __restrict__ nbr,
                                   float* __restrict__ out, int nRows)
{
    constexpr int LPR = D / 4;                       // lanes per row (float4)
    constexpr int RPB = 256 / LPR;                   // rows per block
    const int lane = threadIdx.x % LPR;
    const int r    = threadIdx.x / LPR;
    const int row  = blockIdx.x * RPB + r;
    if (row >= nRows) return;

    const int beg = rowptr[rowbase + row];
    const int end = rowptr[rowbase + row + 1];
    const float4* f4 = reinterpret_cast<const float4*>(feat);

    float ax = 0.f, ay = 0.f, az = 0.f, aw = 0.f;
    float bx = 0.f, by = 0.f, bz = 0.f, bw = 0.f;
    int i = beg;
    for (; i + 1 < end; i += 2) {
        int n0 = nbr[i], n1 = nbr[i + 1];
        float4 v0 = f4[(size_t)n0 * LPR + lane];
        float4 v1 = f4[(size_t)n1 * LPR + lane];
        ax += v0.x; ay += v0.y; az += v0.z; aw += v0.w;
        bx += v1.x; by += v1.y; bz += v1.z; bw += v1.w;
    }
    if (i < end) {
        int n0 = nbr[i];
        float4 v0 = f4[(size_t)n0 * LPR + lane];
        ax += v0.x; ay += v0.y; az += v0.z; aw += v0.w;
    }
    ax += bx; ay += by; az += bz; aw += bw;

    const int cnt = end - beg;
    const float inv = (cnt > 0) ? (1.f / (float)cnt) : 0.f;
    float4 o; o.x = ax * inv; o.y = ay * inv; o.z = az * inv; o.w = aw * inv;
    reinterpret_cast<float4*>(out)[(size_t)row * LPR + lane] = o;
}

// ======================= layer-1 combine: out = relu(LN(mean @ wl + bl + feat @ wr)) =======================
template<int R>
__global__ void sage1_kernel(const float* __restrict__ mean,
                             const float* __restrict__ feat,
                             const float* __restrict__ wl, const float* __restrict__ bl,
                             const float* __restrict__ wr,
                             const float* __restrict__ g, const float* __restrict__ beta,
                             float* __restrict__ out, int n)
{
    __shared__ float ms[R][HID];
    __shared__ float fs[R][HID];
    __shared__ float sh[4];
    const int j = threadIdx.x;
    const int base = blockIdx.x * R;
    for (int r = 0; r < R; ++r) {
        int row = base + r;
        if (row < n) {
            ms[r][j] = mean[(size_t)row * HID + j];
            fs[r][j] = feat[(size_t)row * HID + j];
        }
    }
    __syncthreads();
    float acc[R];
#pragma unroll
    for (int r = 0; r < R; ++r) acc[r] = bl[j];
    for (int k = 0; k < HID; ++k) {
        float a = wl[k * HID + j];
        float b = wr[k * HID + j];
#pragma unroll
        for (int r = 0; r < R; ++r) acc[r] = fmaf(ms[r][k], a, fmaf(fs[r][k], b, acc[r]));
    }
    const float gv = g[j], bv = beta[j];
    for (int r = 0; r < R; ++r) {
        float v = acc[r];
        float s = v, q = v * v;
        for (int o = 32; o > 0; o >>= 1) { s += __shfl_down(s, o); q += __shfl_down(q, o); }
        if ((j & 63) == 0) { sh[(j >> 6) * 2] = s; sh[(j >> 6) * 2 + 1] = q; }
        __syncthreads();
        float S = sh[0] + sh[2], Q = sh[1] + sh[3];
        float mu = S * (1.f / HID);
        float rstd = rsqrtf(Q * (1.f / HID) - mu * mu + 1e-5f);
        float ov = fmaxf((v - mu) * rstd * gv + bv, 0.f);
        int row = base + r;
        if (row < n) out[(size_t)row * HID + j] = ov;
        __syncthreads();
    }
}

// ======================= projection: out = feat @ w (128 -> 64) =======================
template<int R>
__global__ void proj_kernel(const float* __restrict__ feat, const float* __restrict__ w,
                            float* __restrict__ out, int n)
{
    __shared__ float fs[R][HID];
    const int j = threadIdx.x;           // 0..63
    const int base = blockIdx.x * R;
    for (int r = 0; r < R; ++r) {
        int row = base + r;
        if (row < n)
            for (int k = j; k < HID; k += 64) fs[r][k] = feat[(size_t)row * HID + k];
    }
    __syncthreads();
    float acc[R];
#pragma unroll
    for (int r = 0; r < R; ++r) acc[r] = 0.f;
    for (int k = 0; k < HID; ++k) {
        float wv = w[k * OUTD + j];
#pragma unroll
        for (int r = 0; r < R; ++r) acc[r] = fmaf(fs[r][k], wv, acc[r]);
    }
    for (int r = 0; r < R; ++r) {
        int row = base + r;
        if (row < n) out[(size_t)row * OUTD + j] = acc[r];
    }
}

// ======================= final: out = LN(meanproj + bl + feat @ wr) =======================
template<int R>
__global__ void final_kernel(const float* __restrict__ meanproj,
                             const float* __restrict__ feat,
                             const float* __restrict__ bl, const float* __restrict__ wr,
                             const float* __restrict__ g, const float* __restrict__ beta,
                             float* __restrict__ out, int n)
{
    __shared__ float fs[R][HID];
    const int j = threadIdx.x;           // 0..63
    const int base = blockIdx.x * R;
    for (int r = 0; r < R; ++r) {
        int row = base + r;
        if (row < n)
            for (int k = j; k < HID; k += 64) fs[r][k] = feat[(size_t)row * HID + k];
    }
    __syncthreads();
    float acc[R];
#pragma unroll
    for (int r = 0; r < R; ++r) {
        int row = base + r;
        acc[r] = (row < n) ? (meanproj[(size_t)row * OUTD + j] + bl[j]) : 0.f;
    }
    for (int k = 0; k < HID; ++k) {
        float wv = wr[k * OUTD + j];
#pragma unroll
        for (int r = 0; r < R; ++r) acc[r] = fmaf(fs[r][k], wv, acc[r]);
    }
    const float gv = g[j], bv = beta[j];
    for (int r = 0; r < R; ++r) {
        float v = acc[r];
        float s = v, q = v * v;
        for (int o = 32; o > 0; o >>= 1) { s += __shfl_down(s, o); q += __shfl_down(q, o); }
        s = __shfl(s, 0); q = __shfl(q, 0);
        float mu = s * (1.f / OUTD);
        float rstd = rsqrtf(q * (1.f / OUTD) - mu * mu + 1e-5f);
        int row = base + r;
        if (row < n) out[(size_t)row * OUTD + j] = (v - mu) * rstd * gv + bv;
    }
}

extern "C" void kernel_launch(void* const* d_in, const int* in_sizes, int n_in,
                              void* d_out, int out_size, void* d_ws, size_t ws_size,
                              hipStream_t stream)
{
    const float* x_user   = (const float*)d_in[0];
    const float* x_movie  = (const float*)d_in[1];
    const int*   src      = (const int*)d_in[2];   // user ids
    const int*   dst      = (const int*)d_in[3];   // movie ids
    const float* enc_u_w  = (const float*)d_in[4];
    const float* enc_u_b  = (const float*)d_in[5];
    const float* enc_u_g  = (const float*)d_in[6];
    const float* enc_u_be = (const float*)d_in[7];
    const float* enc_m_w  = (const float*)d_in[8];
    const float* enc_m_b  = (const float*)d_in[9];
    const float* enc_m_g  = (const float*)d_in[10];
    const float* enc_m_be = (const float*)d_in[11];
    const float* c1_m_wl  = (const float*)d_in[12];
    const float* c1_m_bl  = (const float*)d_in[13];
    const float* c1_m_wr  = (const float*)d_in[14];
    const float* c1_u_wl  = (const float*)d_in[15];
    const float* c1_u_bl  = (const float*)d_in[16];
    const float* c1_u_wr  = (const float*)d_in[17];
    const float* ln1_u_g  = (const float*)d_in[18];
    const float* ln1_u_b  = (const float*)d_in[19];
    const float* ln1_m_g  = (const float*)d_in[20];
    const float* ln1_m_b  = (const float*)d_in[21];
    const float* c2_m_wl  = (const float*)d_in[22];
    const float* c2_m_bl  = (const float*)d_in[23];
    const float* c2_m_wr  = (const float*)d_in[24];
    const float* c2_u_wl  = (const float*)d_in[25];
    const float* c2_u_bl  = (const float*)d_in[26];
    const float* c2_u_wr  = (const float*)d_in[27];
    const float* ln2_u_g  = (const float*)d_in[28];
    const float* ln2_u_b  = (const float*)d_in[29];
    const float* ln2_m_g  = (const float*)d_in[30];
    const float* ln2_m_b  = (const float*)d_in[31];

    const int NU = in_sizes[0] / 16;
    const int NM = in_sizes[1] / FMDIM;
    const int E  = in_sizes[2];
    const int N  = NM + NU;                         // joint CSR row count

    float* ws = (float*)d_ws;
    // float region: hu[NU*128] | hm[NM*128] | am1[NM*128] | au1[NU*128]
    float* hu  = ws;
    float* hm  = hu  + (size_t)NU * HID;
    float* am1 = hm  + (size_t)NM * HID;
    float* au1 = am1 + (size_t)NM * HID;
    // int region after floats: rowptr[N+1] | cursor[N] | partials[64] | nbr[2E]
    int* rp      = (int*)(au1 + (size_t)NU * HID);
    int* cursor  = rp + (N + 1);
    int* partials= cursor + N;
    int* nbr     = partials + 64;
    // layer-2 overlays (hu/hm dead after layer-1 combine)
    float* pu  = hu;                          // NU*64
    float* au2 = hu + (size_t)NU * OUTD;      // NU*64
    float* pm  = hm;                          // NM*64
    float* am2 = hm + (size_t)NM * OUTD;      // NM*64
    float* m1  = am1;   // in-place over movie mean
    float* u1  = au1;   // in-place over user mean

    float* out_u = (float*)d_out;
    float* out_m = out_u + (size_t)NU * OUTD;

    // zero deg(rowptr) + cursor (contiguous)
    hipMemsetAsync(rp, 0, (size_t)(2 * N + 1) * sizeof(int), stream);

    // encoders
    enc_kernel<8><<<(NU + 7) / 8, 128, 0, stream>>>(x_user, enc_u_w, enc_u_b, enc_u_g, enc_u_be, hu, NU, 16);
    enc_kernel<8><<<(NM + 7) / 8, 128, 0, stream>>>(x_movie, enc_m_w, enc_m_b, enc_m_g, enc_m_be, hm, NM, FMDIM);

    // CSR build (shared by both layers)
    deg_csr_kernel<<<(E + 255) / 256, 256, 0, stream>>>(src, dst, rp, NM, E);
    {
        int nP = (N + 4095) / 4096;
        scan_partial_kernel<<<nP, 256, 0, stream>>>(rp, partials, N);
        scan_partials_kernel<<<1, 64, 0, stream>>>(partials, nP);
        scan_add_kernel<<<(N + 255) / 256, 256, 0, stream>>>(rp, partials, N, 2 * E);
    }
    fill_kernel<<<(E + 255) / 256, 256, 0, stream>>>(src, dst, rp, cursor, nbr, NM, E);

    // layer-1 mean aggregation via gather (no atomics)
    gather_mean_kernel<HID><<<(NM + 7) / 8, 256, 0, stream>>>(hu, rp, 0,  nbr, am1, NM);
    gather_mean_kernel<HID><<<(NU + 7) / 8, 256, 0, stream>>>(hm, rp, NM, nbr, au1, NU);

    // layer-1 combine + LN + relu (in-place over mean buffers)
    sage1_kernel<8><<<(NM + 7) / 8, 128, 0, stream>>>(am1, hm, c1_m_wl, c1_m_bl, c1_m_wr, ln1_m_g, ln1_m_b, m1, NM);
    sage1_kernel<8><<<(NU + 7) / 8, 128, 0, stream>>>(au1, hu, c1_u_wl, c1_u_bl, c1_u_wr, ln1_u_g, ln1_u_b, u1, NU);

    // layer-2: project sources 128->64 BEFORE aggregating (mean is linear)
    proj_kernel<8><<<(NU + 7) / 8, 64, 0, stream>>>(u1, c2_m_wl, pu, NU);
    proj_kernel<8><<<(NM + 7) / 8, 64, 0, stream>>>(m1, c2_u_wl, pm, NM);

    // layer-2 mean aggregation via gather (64-d)
    gather_mean_kernel<OUTD><<<(NM + 15) / 16, 256, 0, stream>>>(pu, rp, 0,  nbr, am2, NM);
    gather_mean_kernel<OUTD><<<(NU + 15) / 16, 256, 0, stream>>>(pm, rp, NM, nbr, au2, NU);

    // final combine + LN -> d_out (u first, then m)
    final_kernel<8><<<(NU + 7) / 8, 64, 0, stream>>>(au2, u1, c2_u_bl, c2_u_wr, ln2_u_g, ln2_u_b, out_u, NU);
    final_kernel<8><<<(NM + 7) / 8, 64, 0, stream>>>(am2, m1, c2_m_bl, c2_m_wr, ln2_m_g, ln2_m_b, out_m, NM);
}

// Round 3
// 979.880 us; speedup vs baseline: 5.9092x; 1.0304x over previous
//
#include <hip/hip_runtime.h>

#define HID 128
#define OUTD 64
#define FMDIM 404

// ======================= encoder: out = LN(relu(x @ W + b)) =======================
// block = 128 threads, R rows per block. in_dim runtime (16 or 404), divisible by 4.
template<int R>
__global__ void enc_kernel(const float* __restrict__ x, const float* __restrict__ W,
                           const float* __restrict__ bias, const float* __restrict__ g,
                           const float* __restrict__ beta, float* __restrict__ out,
                           int n, int in_dim)
{
    __shared__ float4 xs[R][FMDIM / 4];      // 101 float4 per row max
    __shared__ float sh[R][4];
    const int j = threadIdx.x;               // 0..127
    const int base = blockIdx.x * R;
    const int c4 = in_dim >> 2;
    const float4* x4 = reinterpret_cast<const float4*>(x);

    for (int r = 0; r < R; ++r) {
        int row = base + r;
        if (row < n) {
            for (int k = j; k < c4; k += 128)
                xs[r][k] = x4[(size_t)row * c4 + k];
        }
    }
    __syncthreads();

    float acc[R];
#pragma unroll
    for (int r = 0; r < R; ++r) acc[r] = 0.f;

    for (int k4 = 0; k4 < c4; ++k4) {
        const float* wp = W + (size_t)(4 * k4) * HID + j;
        float w0 = wp[0 * HID];
        float w1 = wp[1 * HID];
        float w2 = wp[2 * HID];
        float w3 = wp[3 * HID];
#pragma unroll
        for (int r = 0; r < R; ++r) {
            float4 v = xs[r][k4];
            acc[r] = fmaf(v.x, w0, acc[r]);
            acc[r] = fmaf(v.y, w1, acc[r]);
            acc[r] = fmaf(v.z, w2, acc[r]);
            acc[r] = fmaf(v.w, w3, acc[r]);
        }
    }

    const float bj = bias[j];
#pragma unroll
    for (int r = 0; r < R; ++r) {
        float v = fmaxf(acc[r] + bj, 0.f);
        acc[r] = v;
        float s = v, q = v * v;
        for (int o = 32; o > 0; o >>= 1) { s += __shfl_down(s, o); q += __shfl_down(q, o); }
        if ((j & 63) == 0) { sh[r][(j >> 6) * 2] = s; sh[r][(j >> 6) * 2 + 1] = q; }
    }
    __syncthreads();

    const float gv = g[j], bv = beta[j];
#pragma unroll
    for (int r = 0; r < R; ++r) {
        int row = base + r;
        if (row < n) {
            float S = sh[r][0] + sh[r][2], Q = sh[r][1] + sh[r][3];
            float mu = S * (1.f / HID);
            float rstd = rsqrtf(Q * (1.f / HID) - mu * mu + 1e-5f);
            out[(size_t)row * HID + j] = (acc[r] - mu) * rstd * gv + bv;
        }
    }
}

// ======================= CSR build =======================
__global__ void deg_csr_kernel(const int* __restrict__ src, const int* __restrict__ dst,
                               int* __restrict__ deg, int NM, int E)
{
    int e = blockIdx.x * blockDim.x + threadIdx.x;
    if (e < E) {
        atomicAdd(&deg[dst[e]], 1);
        atomicAdd(&deg[NM + src[e]], 1);
    }
}

__global__ void scan_partial_kernel(int* __restrict__ data, int* __restrict__ partials, int N)
{
    __shared__ int sh[256];
    const int tid = threadIdx.x;
    const int base = blockIdx.x * 4096 + tid * 16;
    int vals[16];
    int s = 0;
#pragma unroll
    for (int i = 0; i < 16; ++i) {
        int v = (base + i < N) ? data[base + i] : 0;
        vals[i] = s;
        s += v;
    }
    sh[tid] = s;
    __syncthreads();
    for (int off = 1; off < 256; off <<= 1) {
        int t = 0;
        if (tid >= off) t = sh[tid - off];
        __syncthreads();
        sh[tid] += t;
        __syncthreads();
    }
    int excl = (tid == 0) ? 0 : sh[tid - 1];
    if (tid == 255) partials[blockIdx.x] = sh[255];
#pragma unroll
    for (int i = 0; i < 16; ++i)
        if (base + i < N) data[base + i] = excl + vals[i];
}

__global__ void scan_partials_kernel(int* __restrict__ partials, int nP)
{
    if (threadIdx.x == 0 && blockIdx.x == 0) {
        int run = 0;
        for (int p = 0; p < nP; ++p) { int t = partials[p]; partials[p] = run; run += t; }
    }
}

__global__ void scan_add_kernel(int* __restrict__ data, const int* __restrict__ partials,
                                int N, int total)
{
    int idx = blockIdx.x * blockDim.x + threadIdx.x;
    if (idx < N) data[idx] += partials[idx >> 12];
    if (idx == 0) data[N] = total;
}

__global__ void fill_kernel(const int* __restrict__ src, const int* __restrict__ dst,
                            const int* __restrict__ rowptr, int* __restrict__ cursor,
                            int* __restrict__ nbr, int NM, int E)
{
    int e = blockIdx.x * blockDim.x + threadIdx.x;
    if (e >= E) return;
    int s = src[e], d = dst[e];
    int p0 = atomicAdd(&cursor[d], 1);
    nbr[rowptr[d] + p0] = s;
    int p1 = atomicAdd(&cursor[NM + s], 1);
    nbr[rowptr[NM + s] + p1] = d;
}

// ======================= CSR mean-gather =======================
template<int D>
__global__ void gather_mean_kernel(const float* __restrict__ feat,
                                   const int* __restrict__ rowptr, int rowbase,
                                   const int* __restrict__ nbr,
                                   float* __restrict__ out, int nRows)
{
    constexpr int LPR = D / 4;
    constexpr int RPB = 256 / LPR;
    const int lane = threadIdx.x % LPR;
    const int r    = threadIdx.x / LPR;
    const int row  = blockIdx.x * RPB + r;
    if (row >= nRows) return;

    const int beg = rowptr[rowbase + row];
    const int end = rowptr[rowbase + row + 1];
    const float4* f4 = reinterpret_cast<const float4*>(feat);

    float ax = 0.f, ay = 0.f, az = 0.f, aw = 0.f;
    float bx = 0.f, by = 0.f, bz = 0.f, bw = 0.f;
    int i = beg;
    for (; i + 1 < end; i += 2) {
        int n0 = nbr[i], n1 = nbr[i + 1];
        float4 v0 = f4[(size_t)n0 * LPR + lane];
        float4 v1 = f4[(size_t)n1 * LPR + lane];
        ax += v0.x; ay += v0.y; az += v0.z; aw += v0.w;
        bx += v1.x; by += v1.y; bz += v1.z; bw += v1.w;
    }
    if (i < end) {
        int n0 = nbr[i];
        float4 v0 = f4[(size_t)n0 * LPR + lane];
        ax += v0.x; ay += v0.y; az += v0.z; aw += v0.w;
    }
    ax += bx; ay += by; az += bz; aw += bw;

    const int cnt = end - beg;
    const float inv = (cnt > 0) ? (1.f / (float)cnt) : 0.f;
    float4 o; o.x = ax * inv; o.y = ay * inv; o.z = az * inv; o.w = aw * inv;
    reinterpret_cast<float4*>(out)[(size_t)row * LPR + lane] = o;
}

// ======================= layer-1 combine: out = relu(LN(mean @ wl + bl + feat @ wr)) =======================
template<int R>
__global__ void sage1_kernel(const float* __restrict__ mean,
                             const float* __restrict__ feat,
                             const float* __restrict__ wl, const float* __restrict__ bl,
                             const float* __restrict__ wr,
                             const float* __restrict__ g, const float* __restrict__ beta,
                             float* __restrict__ out, int n)
{
    __shared__ float4 ms[R][HID / 4];        // 32 chunks
    __shared__ float4 fs[R][HID / 4];
    __shared__ float sh[R][4];
    const int j = threadIdx.x;               // 0..127
    const int base = blockIdx.x * R;
    const float4* m4 = reinterpret_cast<const float4*>(mean);
    const float4* f4 = reinterpret_cast<const float4*>(feat);

    for (int t = j; t < R * 32; t += 128) {
        int r = t >> 5, k = t & 31;
        int row = base + r;
        if (row < n) {
            ms[r][k] = m4[(size_t)row * 32 + k];
            fs[r][k] = f4[(size_t)row * 32 + k];
        }
    }
    __syncthreads();

    float acc[R];
#pragma unroll
    for (int r = 0; r < R; ++r) acc[r] = 0.f;

    for (int k4 = 0; k4 < 32; ++k4) {
        const float* ap = wl + (size_t)(4 * k4) * HID + j;
        const float* bp = wr + (size_t)(4 * k4) * HID + j;
        float a0 = ap[0 * HID], a1 = ap[1 * HID], a2 = ap[2 * HID], a3 = ap[3 * HID];
        float b0 = bp[0 * HID], b1 = bp[1 * HID], b2 = bp[2 * HID], b3 = bp[3 * HID];
#pragma unroll
        for (int r = 0; r < R; ++r) {
            float4 mv = ms[r][k4];
            float4 fv = fs[r][k4];
            acc[r] = fmaf(mv.x, a0, fmaf(fv.x, b0, acc[r]));
            acc[r] = fmaf(mv.y, a1, fmaf(fv.y, b1, acc[r]));
            acc[r] = fmaf(mv.z, a2, fmaf(fv.z, b2, acc[r]));
            acc[r] = fmaf(mv.w, a3, fmaf(fv.w, b3, acc[r]));
        }
    }

    const float blj = bl[j];
#pragma unroll
    for (int r = 0; r < R; ++r) {
        float v = acc[r] + blj;
        acc[r] = v;
        float s = v, q = v * v;
        for (int o = 32; o > 0; o >>= 1) { s += __shfl_down(s, o); q += __shfl_down(q, o); }
        if ((j & 63) == 0) { sh[r][(j >> 6) * 2] = s; sh[r][(j >> 6) * 2 + 1] = q; }
    }
    __syncthreads();

    const float gv = g[j], bv = beta[j];
#pragma unroll
    for (int r = 0; r < R; ++r) {
        int row = base + r;
        if (row < n) {
            float S = sh[r][0] + sh[r][2], Q = sh[r][1] + sh[r][3];
            float mu = S * (1.f / HID);
            float rstd = rsqrtf(Q * (1.f / HID) - mu * mu + 1e-5f);
            out[(size_t)row * HID + j] = fmaxf((acc[r] - mu) * rstd * gv + bv, 0.f);
        }
    }
}

// ======================= projection: out = feat @ w (128 -> 64) =======================
template<int R>
__global__ void proj_kernel(const float* __restrict__ feat, const float* __restrict__ w,
                            float* __restrict__ out, int n)
{
    __shared__ float4 fs[R][HID / 4];        // 32 chunks
    const int j = threadIdx.x;               // 0..63
    const int base = blockIdx.x * R;
    const float4* f4 = reinterpret_cast<const float4*>(feat);

    for (int t = j; t < R * 32; t += 64) {
        int r = t >> 5, k = t & 31;
        int row = base + r;
        if (row < n) fs[r][k] = f4[(size_t)row * 32 + k];
    }
    __syncthreads();

    float acc[R];
#pragma unroll
    for (int r = 0; r < R; ++r) acc[r] = 0.f;

    for (int k4 = 0; k4 < 32; ++k4) {
        const float* wp = w + (size_t)(4 * k4) * OUTD + j;
        float w0 = wp[0 * OUTD], w1 = wp[1 * OUTD], w2 = wp[2 * OUTD], w3 = wp[3 * OUTD];
#pragma unroll
        for (int r = 0; r < R; ++r) {
            float4 v = fs[r][k4];
            acc[r] = fmaf(v.x, w0, acc[r]);
            acc[r] = fmaf(v.y, w1, acc[r]);
            acc[r] = fmaf(v.z, w2, acc[r]);
            acc[r] = fmaf(v.w, w3, acc[r]);
        }
    }
    for (int r = 0; r < R; ++r) {
        int row = base + r;
        if (row < n) out[(size_t)row * OUTD + j] = acc[r];
    }
}

// ======================= final: out = LN(meanproj + bl + feat @ wr) =======================
template<int R>
__global__ void final_kernel(const float* __restrict__ meanproj,
                             const float* __restrict__ feat,
                             const float* __restrict__ bl, const float* __restrict__ wr,
                             const float* __restrict__ g, const float* __restrict__ beta,
                             float* __restrict__ out, int n)
{
    __shared__ float4 fs[R][HID / 4];
    const int j = threadIdx.x;               // 0..63
    const int base = blockIdx.x * R;
    const float4* f4 = reinterpret_cast<const float4*>(feat);

    for (int t = j; t < R * 32; t += 64) {
        int r = t >> 5, k = t & 31;
        int row = base + r;
        if (row < n) fs[r][k] = f4[(size_t)row * 32 + k];
    }
    __syncthreads();

    const float blj = bl[j];
    float acc[R];
#pragma unroll
    for (int r = 0; r < R; ++r) {
        int row = base + r;
        acc[r] = (row < n) ? (meanproj[(size_t)row * OUTD + j] + blj) : 0.f;
    }

    for (int k4 = 0; k4 < 32; ++k4) {
        const float* wp = wr + (size_t)(4 * k4) * OUTD + j;
        float w0 = wp[0 * OUTD], w1 = wp[1 * OUTD], w2 = wp[2 * OUTD], w3 = wp[3 * OUTD];
#pragma unroll
        for (int r = 0; r < R; ++r) {
            float4 v = fs[r][k4];
            acc[r] = fmaf(v.x, w0, acc[r]);
            acc[r] = fmaf(v.y, w1, acc[r]);
            acc[r] = fmaf(v.z, w2, acc[r]);
            acc[r] = fmaf(v.w, w3, acc[r]);
        }
    }

    const float gv = g[j], bv = beta[j];
#pragma unroll
    for (int r = 0; r < R; ++r) {
        float v = acc[r];
        float s = v, q = v * v;
        for (int o = 32; o > 0; o >>= 1) { s += __shfl_down(s, o); q += __shfl_down(q, o); }
        s = __shfl(s, 0); q = __shfl(q, 0);
        float mu = s * (1.f / OUTD);
        float rstd = rsqrtf(q * (1.f / OUTD) - mu * mu + 1e-5f);
        int row = base + r;
        if (row < n) out[(size_t)row * OUTD + j] = (v - mu) * rstd * gv + bv;
    }
}

extern "C" void kernel_launch(void* const* d_in, const int* in_sizes, int n_in,
                              void* d_out, int out_size, void* d_ws, size_t ws_size,
                              hipStream_t stream)
{
    const float* x_user   = (const float*)d_in[0];
    const float* x_movie  = (const float*)d_in[1];
    const int*   src      = (const int*)d_in[2];
    const int*   dst      = (const int*)d_in[3];
    const float* enc_u_w  = (const float*)d_in[4];
    const float* enc_u_b  = (const float*)d_in[5];
    const float* enc_u_g  = (const float*)d_in[6];
    const float* enc_u_be = (const float*)d_in[7];
    const float* enc_m_w  = (const float*)d_in[8];
    const float* enc_m_b  = (const float*)d_in[9];
    const float* enc_m_g  = (const float*)d_in[10];
    const float* enc_m_be = (const float*)d_in[11];
    const float* c1_m_wl  = (const float*)d_in[12];
    const float* c1_m_bl  = (const float*)d_in[13];
    const float* c1_m_wr  = (const float*)d_in[14];
    const float* c1_u_wl  = (const float*)d_in[15];
    const float* c1_u_bl  = (const float*)d_in[16];
    const float* c1_u_wr  = (const float*)d_in[17];
    const float* ln1_u_g  = (const float*)d_in[18];
    const float* ln1_u_b  = (const float*)d_in[19];
    const float* ln1_m_g  = (const float*)d_in[20];
    const float* ln1_m_b  = (const float*)d_in[21];
    const float* c2_m_wl  = (const float*)d_in[22];
    const float* c2_m_bl  = (const float*)d_in[23];
    const float* c2_m_wr  = (const float*)d_in[24];
    const float* c2_u_wl  = (const float*)d_in[25];
    const float* c2_u_bl  = (const float*)d_in[26];
    const float* c2_u_wr  = (const float*)d_in[27];
    const float* ln2_u_g  = (const float*)d_in[28];
    const float* ln2_u_b  = (const float*)d_in[29];
    const float* ln2_m_g  = (const float*)d_in[30];
    const float* ln2_m_b  = (const float*)d_in[31];

    const int NU = in_sizes[0] / 16;
    const int NM = in_sizes[1] / FMDIM;
    const int E  = in_sizes[2];
    const int N  = NM + NU;

    float* ws = (float*)d_ws;
    float* hu  = ws;
    float* hm  = hu  + (size_t)NU * HID;
    float* am1 = hm  + (size_t)NM * HID;
    float* au1 = am1 + (size_t)NM * HID;
    int* rp      = (int*)(au1 + (size_t)NU * HID);
    int* cursor  = rp + (N + 1);
    int* partials= cursor + N;
    int* nbr     = partials + 64;
    float* pu  = hu;
    float* au2 = hu + (size_t)NU * OUTD;
    float* pm  = hm;
    float* am2 = hm + (size_t)NM * OUTD;
    float* m1  = am1;
    float* u1  = au1;

    float* out_u = (float*)d_out;
    float* out_m = out_u + (size_t)NU * OUTD;

    hipMemsetAsync(rp, 0, (size_t)(2 * N + 1) * sizeof(int), stream);

    enc_kernel<8><<<(NU + 7) / 8, 128, 0, stream>>>(x_user, enc_u_w, enc_u_b, enc_u_g, enc_u_be, hu, NU, 16);
    enc_kernel<8><<<(NM + 7) / 8, 128, 0, stream>>>(x_movie, enc_m_w, enc_m_b, enc_m_g, enc_m_be, hm, NM, FMDIM);

    deg_csr_kernel<<<(E + 255) / 256, 256, 0, stream>>>(src, dst, rp, NM, E);
    {
        int nP = (N + 4095) / 4096;
        scan_partial_kernel<<<nP, 256, 0, stream>>>(rp, partials, N);
        scan_partials_kernel<<<1, 64, 0, stream>>>(partials, nP);
        scan_add_kernel<<<(N + 255) / 256, 256, 0, stream>>>(rp, partials, N, 2 * E);
    }
    fill_kernel<<<(E + 255) / 256, 256, 0, stream>>>(src, dst, rp, cursor, nbr, NM, E);

    gather_mean_kernel<HID><<<(NM + 7) / 8, 256, 0, stream>>>(hu, rp, 0,  nbr, am1, NM);
    gather_mean_kernel<HID><<<(NU + 7) / 8, 256, 0, stream>>>(hm, rp, NM, nbr, au1, NU);

    sage1_kernel<8><<<(NM + 7) / 8, 128, 0, stream>>>(am1, hm, c1_m_wl, c1_m_bl, c1_m_wr, ln1_m_g, ln1_m_b, m1, NM);
    sage1_kernel<8><<<(NU + 7) / 8, 128, 0, stream>>>(au1, hu, c1_u_wl, c1_u_bl, c1_u_wr, ln1_u_g, ln1_u_b, u1, NU);

    proj_kernel<8><<<(NU + 7) / 8, 64, 0, stream>>>(u1, c2_m_wl, pu, NU);
    proj_kernel<8><<<(NM + 7) / 8, 64, 0, stream>>>(m1, c2_u_wl, pm, NM);

    gather_mean_kernel<OUTD><<<(NM + 15) / 16, 256, 0, stream>>>(pu, rp, 0,  nbr, am2, NM);
    gather_mean_kernel<OUTD><<<(NU + 15) / 16, 256, 0, stream>>>(pm, rp, NM, nbr, au2, NU);

    final_kernel<8><<<(NU + 7) / 8, 64, 0, stream>>>(au2, u1, c2_u_bl, c2_u_wr, ln2_u_g, ln2_u_b, out_u, NU);
    final_kernel<8><<<(NM + 7) / 8, 64, 0, stream>>>(am2, m1, c2_m_bl, c2_m_wr, ln2_m_g, ln2_m_b, out_m, NM);
}

// Round 9
// 834.960 us; speedup vs baseline: 6.9349x; 1.1736x over previous
//
#include <hip/hip_runtime.h>
#include <hip/hip_bf16.h>

#define HID 128
#define OUTD 64
#define FMDIM 404

using bf16x8 = __attribute__((ext_vector_type(8))) short;   // 8 bf16 in 4 VGPRs
using f32x4  = __attribute__((ext_vector_type(4))) float;

static __device__ __forceinline__ short f2b(float f) {
    __hip_bfloat16 h = __float2bfloat16(f);          // RNE
    return *reinterpret_cast<short*>(&h);
}

// guarded float4 load: address always in-bounds, value zero when k0+4 > Kin (Kin % 4 == 0)
static __device__ __forceinline__ float4 ld4_guard(const float* rowp, int k0, int Kin) {
    bool ok = (k0 + 4 <= Kin);
    const float4* p = reinterpret_cast<const float4*>(rowp + (ok ? k0 : 0));
    float4 v = *p;
    return ok ? v : float4{0.f, 0.f, 0.f, 0.f};
}

static __device__ __forceinline__ bf16x8 ldcvt8(const float* rowp, int k0, int Kin) {
    float4 f0 = ld4_guard(rowp, k0, Kin);
    float4 f1 = ld4_guard(rowp, k0 + 4, Kin);
    bf16x8 r;
    r[0] = f2b(f0.x); r[1] = f2b(f0.y); r[2] = f2b(f0.z); r[3] = f2b(f0.w);
    r[4] = f2b(f1.x); r[5] = f2b(f1.y); r[6] = f2b(f1.z); r[7] = f2b(f1.w);
    return r;
}

// ======================= weight repack: f32 W[K][N] -> bf16 frag layout =======================
// out[((nt*KT + kk)*64 + lane)*8 + j] = W[kk*32 + (lane>>4)*8 + j][nt*16 + (lane&15)], 0 if k>=K
__global__ void repack_w_kernel(const float* __restrict__ W, short* __restrict__ out,
                                int K, int N, int KT)
{
    int idx = blockIdx.x * blockDim.x + threadIdx.x;
    int total = (N >> 4) * KT * 512;
    if (idx >= total) return;
    int j    = idx & 7;
    int lane = (idx >> 3) & 63;
    int grp  = idx >> 9;
    int kk   = grp % KT, nt = grp / KT;
    int k    = kk * 32 + (lane >> 4) * 8 + j;
    int col  = nt * 16 + (lane & 15);
    out[idx] = (k < K) ? f2b(W[(size_t)k * N + col]) : (short)0;
}

// ======================= MFMA GEMM from f32 activations + LN epilogue, f32 out =======================
// out = LN-ish( A1@W1 [+ A2@W2] + bias ).  EPI 0: relu then LN (encoder); 1: LN then relu (sage1).
// A row-major f32 [M][Kin], Kin % 4 == 0, zero-extended in-register to KT*32.
// One 16-row tile per wave; in-place out-over-A1 safe (reads of rows finish before writes).
template<int NT, int KT, bool DUAL, int EPI>
__global__ __launch_bounds__(256) void mfma_f32_kernel(
    const float* __restrict__ A1, const float* __restrict__ A2, int Kin1, int Kin2,
    const bf16x8* __restrict__ W1, const bf16x8* __restrict__ W2,
    const float* __restrict__ bias, const float* __restrict__ g, const float* __restrict__ beta,
    float* __restrict__ out, int mtiles)
{
    constexpr int N = NT * 16;
    const int lane = threadIdx.x & 63;
    const int wave = threadIdx.x >> 6;
    const int t = blockIdx.x * 4 + wave;
    if (t >= mtiles) return;

    const int lr = lane & 15;                 // A-row / D-col within tile
    const int lk = lane >> 4;                 // k-group
    const int row = t * 16 + lr;
    const float* a1p = A1 + (size_t)row * Kin1;
    const float* a2p = DUAL ? (A2 + (size_t)row * Kin2) : nullptr;

    f32x4 acc[NT];
#pragma unroll
    for (int n = 0; n < NT; ++n) acc[n] = f32x4{0.f, 0.f, 0.f, 0.f};

#pragma unroll
    for (int kk = 0; kk < KT; ++kk) {
        const int k0 = kk * 32 + lk * 8;
        bf16x8 a1 = ldcvt8(a1p, k0, Kin1);
        bf16x8 a2;
        if constexpr (DUAL) a2 = ldcvt8(a2p, k0, Kin2);
#pragma unroll
        for (int n = 0; n < NT; ++n) {
            bf16x8 b1 = W1[(size_t)(n * KT + kk) * 64 + lane];
            acc[n] = __builtin_amdgcn_mfma_f32_16x16x32_bf16(a1, b1, acc[n], 0, 0, 0);
            if constexpr (DUAL) {
                bf16x8 b2 = W2[(size_t)(n * KT + kk) * 64 + lane];
                acc[n] = __builtin_amdgcn_mfma_f32_16x16x32_bf16(a2, b2, acc[n], 0, 0, 0);
            }
        }
    }

    // epilogue: bias, (relu), LN over N cols, (relu), f32 store.
    // C/D layout: col = n*16 + lr, row = rowbase + lk*4 + q.
    const int rowbase = t * 16;
    float v[NT][4];
#pragma unroll
    for (int n = 0; n < NT; ++n) {
        const float bc = bias[n * 16 + lr];
#pragma unroll
        for (int q = 0; q < 4; ++q) {
            float x = acc[n][q] + bc;
            if constexpr (EPI == 0) x = fmaxf(x, 0.f);
            v[n][q] = x;
        }
    }
    float gcol[NT], becol[NT];
#pragma unroll
    for (int n = 0; n < NT; ++n) { gcol[n] = g[n * 16 + lr]; becol[n] = beta[n * 16 + lr]; }
#pragma unroll
    for (int q = 0; q < 4; ++q) {
        float s = 0.f, ss = 0.f;
#pragma unroll
        for (int n = 0; n < NT; ++n) { s += v[n][q]; ss += v[n][q] * v[n][q]; }
#pragma unroll
        for (int m = 1; m < 16; m <<= 1) {
            s  += __shfl_xor(s, m);
            ss += __shfl_xor(ss, m);
        }
        const float mu   = s * (1.f / N);
        const float rstd = rsqrtf(ss * (1.f / N) - mu * mu + 1e-5f);
#pragma unroll
        for (int n = 0; n < NT; ++n) {
            float o = (v[n][q] - mu) * rstd * gcol[n] + becol[n];
            if constexpr (EPI == 1) o = fmaxf(o, 0.f);
            out[(size_t)(rowbase + lk * 4 + q) * N + n * 16 + lr] = o;
        }
    }
}

// ======================= CSR build (r3-proven) =======================
__global__ void deg_csr_kernel(const int* __restrict__ src, const int* __restrict__ dst,
                               int* __restrict__ deg, int NM, int E)
{
    int e = blockIdx.x * blockDim.x + threadIdx.x;
    if (e < E) {
        atomicAdd(&deg[dst[e]], 1);
        atomicAdd(&deg[NM + src[e]], 1);
    }
}

__global__ void scan_partial_kernel(int* __restrict__ data, int* __restrict__ partials, int N)
{
    __shared__ int sh[256];
    const int tid = threadIdx.x;
    const int base = blockIdx.x * 4096 + tid * 16;
    int vals[16];
    int s = 0;
#pragma unroll
    for (int i = 0; i < 16; ++i) {
        int v = (base + i < N) ? data[base + i] : 0;
        vals[i] = s;
        s += v;
    }
    sh[tid] = s;
    __syncthreads();
    for (int off = 1; off < 256; off <<= 1) {
        int t = 0;
        if (tid >= off) t = sh[tid - off];
        __syncthreads();
        sh[tid] += t;
        __syncthreads();
    }
    int excl = (tid == 0) ? 0 : sh[tid - 1];
    if (tid == 255) partials[blockIdx.x] = sh[255];
#pragma unroll
    for (int i = 0; i < 16; ++i)
        if (base + i < N) data[base + i] = excl + vals[i];
}

__global__ void scan_partials_kernel(int* __restrict__ partials, int nP)
{
    if (threadIdx.x == 0 && blockIdx.x == 0) {
        int run = 0;
        for (int p = 0; p < nP; ++p) { int t = partials[p]; partials[p] = run; run += t; }
    }
}

__global__ void scan_add_kernel(int* __restrict__ data, const int* __restrict__ partials,
                                int N, int total)
{
    int idx = blockIdx.x * blockDim.x + threadIdx.x;
    if (idx < N) data[idx] += partials[idx >> 12];
    if (idx == 0) data[N] = total;
}

__global__ void fill_kernel(const int* __restrict__ src, const int* __restrict__ dst,
                            const int* __restrict__ rowptr, int* __restrict__ cursor,
                            int* __restrict__ nbr, int NM, int E)
{
    int e = blockIdx.x * blockDim.x + threadIdx.x;
    if (e >= E) return;
    int s = src[e], d = dst[e];
    int p0 = atomicAdd(&cursor[d], 1);
    nbr[rowptr[d] + p0] = s;
    int p1 = atomicAdd(&cursor[NM + s], 1);
    nbr[rowptr[NM + s] + p1] = d;
}

// canonicalize each row's neighbor list -> order-independent downstream sums
__global__ void sort_rows_kernel(const int* __restrict__ rowptr, int* __restrict__ nbr, int N)
{
    int r = blockIdx.x * blockDim.x + threadIdx.x;
    if (r >= N) return;
    int beg = rowptr[r], end = rowptr[r + 1];
    for (int i = beg + 1; i < end; ++i) {
        int key = nbr[i];
        int j = i - 1;
        while (j >= beg && nbr[j] > key) { nbr[j + 1] = nbr[j]; --j; }
        nbr[j + 1] = key;
    }
}

// ======================= f32 CSR mean-gather (r3-proven) =======================
template<int D>
__global__ void gather_mean_kernel(const float* __restrict__ feat,
                                   const int* __restrict__ rowptr, int rowbase,
                                   const int* __restrict__ nbr,
                                   float* __restrict__ out, int nRows)
{
    constexpr int LPR = D / 4;
    constexpr int RPB = 256 / LPR;
    const int lane = threadIdx.x % LPR;
    const int r    = threadIdx.x / LPR;
    const int row  = blockIdx.x * RPB + r;
    if (row >= nRows) return;

    const int beg = rowptr[rowbase + row];
    const int end = rowptr[rowbase + row + 1];
    const float4* f4 = reinterpret_cast<const float4*>(feat);

    float ax = 0.f, ay = 0.f, az = 0.f, aw = 0.f;
    float bx = 0.f, by = 0.f, bz = 0.f, bw = 0.f;
    int i = beg;
    for (; i + 1 < end; i += 2) {
        int n0 = nbr[i], n1 = nbr[i + 1];
        float4 v0 = f4[(size_t)n0 * LPR + lane];
        float4 v1 = f4[(size_t)n1 * LPR + lane];
        ax += v0.x; ay += v0.y; az += v0.z; aw += v0.w;
        bx += v1.x; by += v1.y; bz += v1.z; bw += v1.w;
    }
    if (i < end) {
        int n0 = nbr[i];
        float4 v0 = f4[(size_t)n0 * LPR + lane];
        ax += v0.x; ay += v0.y; az += v0.z; aw += v0.w;
    }
    ax += bx; ay += by; az += bz; aw += bw;

    const int cnt = end - beg;
    const float inv = (cnt > 0) ? (1.f / (float)cnt) : 0.f;
    float4 o; o.x = ax * inv; o.y = ay * inv; o.z = az * inv; o.w = aw * inv;
    reinterpret_cast<float4*>(out)[(size_t)row * LPR + lane] = o;
}

// ======================= projection: out = feat @ w (128 -> 64), f32 (r3-proven) =======================
template<int R>
__global__ void proj_kernel(const float* __restrict__ feat, const float* __restrict__ w,
                            float* __restrict__ out, int n)
{
    __shared__ float4 fs[R][HID / 4];
    const int j = threadIdx.x;               // 0..63
    const int base = blockIdx.x * R;
    const float4* f4 = reinterpret_cast<const float4*>(feat);

    for (int t = j; t < R * 32; t += 64) {
        int r = t >> 5, k = t & 31;
        int row = base + r;
        if (row < n) fs[r][k] = f4[(size_t)row * 32 + k];
    }
    __syncthreads();

    float acc[R];
#pragma unroll
    for (int r = 0; r < R; ++r) acc[r] = 0.f;

    for (int k4 = 0; k4 < 32; ++k4) {
        const float* wp = w + (size_t)(4 * k4) * OUTD + j;
        float w0 = wp[0 * OUTD], w1 = wp[1 * OUTD], w2 = wp[2 * OUTD], w3 = wp[3 * OUTD];
#pragma unroll
        for (int r = 0; r < R; ++r) {
            float4 v = fs[r][k4];
            acc[r] = fmaf(v.x, w0, acc[r]);
            acc[r] = fmaf(v.y, w1, acc[r]);
            acc[r] = fmaf(v.z, w2, acc[r]);
            acc[r] = fmaf(v.w, w3, acc[r]);
        }
    }
    for (int r = 0; r < R; ++r) {
        int row = base + r;
        if (row < n) out[(size_t)row * OUTD + j] = acc[r];
    }
}

// ======================= final: out = LN(meanproj + bl + feat @ wr), f32 (r3-proven) =======================
template<int R>
__global__ void final_kernel(const float* __restrict__ meanproj,
                             const float* __restrict__ feat,
                             const float* __restrict__ bl, const float* __restrict__ wr,
                             const float* __restrict__ g, const float* __restrict__ beta,
                             float* __restrict__ out, int n)
{
    __shared__ float4 fs[R][HID / 4];
    const int j = threadIdx.x;               // 0..63
    const int base = blockIdx.x * R;
    const float4* f4 = reinterpret_cast<const float4*>(feat);

    for (int t = j; t < R * 32; t += 64) {
        int r = t >> 5, k = t & 31;
        int row = base + r;
        if (row < n) fs[r][k] = f4[(size_t)row * 32 + k];
    }
    __syncthreads();

    const float blj = bl[j];
    float acc[R];
#pragma unroll
    for (int r = 0; r < R; ++r) {
        int row = base + r;
        acc[r] = (row < n) ? (meanproj[(size_t)row * OUTD + j] + blj) : 0.f;
    }

    for (int k4 = 0; k4 < 32; ++k4) {
        const float* wp = wr + (size_t)(4 * k4) * OUTD + j;
        float w0 = wp[0 * OUTD], w1 = wp[1 * OUTD], w2 = wp[2 * OUTD], w3 = wp[3 * OUTD];
#pragma unroll
        for (int r = 0; r < R; ++r) {
            float4 v = fs[r][k4];
            acc[r] = fmaf(v.x, w0, acc[r]);
            acc[r] = fmaf(v.y, w1, acc[r]);
            acc[r] = fmaf(v.z, w2, acc[r]);
            acc[r] = fmaf(v.w, w3, acc[r]);
        }
    }

    const float gv = g[j], bv = beta[j];
#pragma unroll
    for (int r = 0; r < R; ++r) {
        float v = acc[r];
        float s = v, q = v * v;
        for (int o = 32; o > 0; o >>= 1) { s += __shfl_down(s, o); q += __shfl_down(q, o); }
        s = __shfl(s, 0); q = __shfl(q, 0);
        float mu = s * (1.f / OUTD);
        float rstd = rsqrtf(q * (1.f / OUTD) - mu * mu + 1e-5f);
        int row = base + r;
        if (row < n) out[(size_t)row * OUTD + j] = (v - mu) * rstd * gv + bv;
    }
}

extern "C" void kernel_launch(void* const* d_in, const int* in_sizes, int n_in,
                              void* d_out, int out_size, void* d_ws, size_t ws_size,
                              hipStream_t stream)
{
    const float* x_user   = (const float*)d_in[0];
    const float* x_movie  = (const float*)d_in[1];
    const int*   src      = (const int*)d_in[2];
    const int*   dst      = (const int*)d_in[3];
    const float* enc_u_w  = (const float*)d_in[4];
    const float* enc_u_b  = (const float*)d_in[5];
    const float* enc_u_g  = (const float*)d_in[6];
    const float* enc_u_be = (const float*)d_in[7];
    const float* enc_m_w  = (const float*)d_in[8];
    const float* enc_m_b  = (const float*)d_in[9];
    const float* enc_m_g  = (const float*)d_in[10];
    const float* enc_m_be = (const float*)d_in[11];
    const float* c1_m_wl  = (const float*)d_in[12];
    const float* c1_m_bl  = (const float*)d_in[13];
    const float* c1_m_wr  = (const float*)d_in[14];
    const float* c1_u_wl  = (const float*)d_in[15];
    const float* c1_u_bl  = (const float*)d_in[16];
    const float* c1_u_wr  = (const float*)d_in[17];
    const float* ln1_u_g  = (const float*)d_in[18];
    const float* ln1_u_b  = (const float*)d_in[19];
    const float* ln1_m_g  = (const float*)d_in[20];
    const float* ln1_m_b  = (const float*)d_in[21];
    const float* c2_m_wl  = (const float*)d_in[22];
    const float* c2_m_bl  = (const float*)d_in[23];
    const float* c2_m_wr  = (const float*)d_in[24];
    const float* c2_u_wl  = (const float*)d_in[25];
    const float* c2_u_bl  = (const float*)d_in[26];
    const float* c2_u_wr  = (const float*)d_in[27];
    const float* ln2_u_g  = (const float*)d_in[28];
    const float* ln2_u_b  = (const float*)d_in[29];
    const float* ln2_m_g  = (const float*)d_in[30];
    const float* ln2_m_b  = (const float*)d_in[31];

    const int NU = in_sizes[0] / 16;
    const int NM = in_sizes[1] / FMDIM;
    const int E  = in_sizes[2];
    const int N  = NM + NU;

    // -------- workspace: r3-proven layout + small bf16 weight-frag region --------
    float* ws = (float*)d_ws;
    float* hu  = ws;                              // NU*128 f32
    float* hm  = hu  + (size_t)NU * HID;          // NM*128
    float* am1 = hm  + (size_t)NM * HID;          // NM*128
    float* au1 = am1 + (size_t)NM * HID;          // NU*128
    // weight frags (bf16 shorts), 16B-aligned since all counts are even
    short* wfu   = (short*)(au1 + (size_t)NU * HID);  // 8*1*512
    short* wfm   = wfu   + 8 * 1  * 512;              // 8*13*512
    short* wf1ml = wfm   + 8 * 13 * 512;
    short* wf1mr = wf1ml + 8 * 4  * 512;
    short* wf1ul = wf1mr + 8 * 4  * 512;
    short* wf1ur = wf1ul + 8 * 4  * 512;
    int* rp      = (int*)(wf1ur + 8 * 4 * 512);
    int* cursor  = rp + (N + 1);
    int* partials= cursor + N;
    int* nbr     = partials + 64;
    // overlays (r3-proven): layer-2 buffers over dead hu/hm; m1/u1 in-place
    float* pu  = hu;                          // NU*64
    float* au2 = hu + (size_t)NU * OUTD;      // NU*64
    float* pm  = hm;                          // NM*64
    float* am2 = hm + (size_t)NM * OUTD;      // NM*64
    float* m1  = am1;                         // in-place
    float* u1  = au1;                         // in-place

    float* out_u = (float*)d_out;
    float* out_m = out_u + (size_t)NU * OUTD;

    // -------- weight repacks (bf16 fragments) --------
    auto repack = [&](const float* W, short* out, int K, int Ncols, int KT) {
        int total = (Ncols >> 4) * KT * 512;
        repack_w_kernel<<<(total + 255) / 256, 256, 0, stream>>>(W, out, K, Ncols, KT);
    };
    repack(enc_u_w, wfu,   16,  128, 1);
    repack(enc_m_w, wfm,   404, 128, 13);
    repack(c1_m_wl, wf1ml, 128, 128, 4);
    repack(c1_m_wr, wf1mr, 128, 128, 4);
    repack(c1_u_wl, wf1ul, 128, 128, 4);
    repack(c1_u_wr, wf1ur, 128, 128, 4);

    // -------- CSR build (r3-proven) --------
    hipMemsetAsync(rp, 0, (size_t)(2 * N + 1) * sizeof(int), stream);
    deg_csr_kernel<<<(E + 255) / 256, 256, 0, stream>>>(src, dst, rp, NM, E);
    {
        int nP = (N + 4095) / 4096;
        scan_partial_kernel<<<nP, 256, 0, stream>>>(rp, partials, N);
        scan_partials_kernel<<<1, 64, 0, stream>>>(partials, nP);
        scan_add_kernel<<<(N + 255) / 256, 256, 0, stream>>>(rp, partials, N, 2 * E);
    }
    fill_kernel<<<(E + 255) / 256, 256, 0, stream>>>(src, dst, rp, cursor, nbr, NM, E);
    sort_rows_kernel<<<(N + 255) / 256, 256, 0, stream>>>(rp, nbr, N);

    const int mtU = NU / 16, mtM = NM / 16;      // 6250, 3125 (exact)
    const int gbU = (mtU + 3) / 4, gbM = (mtM + 3) / 4;

    // -------- encoders: MFMA from f32 activations, relu->LN, f32 out --------
    mfma_f32_kernel<8, 1, false, 0><<<gbU, 256, 0, stream>>>(
        x_user, nullptr, 16, 0, (const bf16x8*)wfu, nullptr,
        enc_u_b, enc_u_g, enc_u_be, hu, mtU);
    mfma_f32_kernel<8, 13, false, 0><<<gbM, 256, 0, stream>>>(
        x_movie, nullptr, FMDIM, 0, (const bf16x8*)wfm, nullptr,
        enc_m_b, enc_m_g, enc_m_be, hm, mtM);

    // -------- layer-1 gathers (f32, r3-proven) --------
    gather_mean_kernel<HID><<<(NM + 7) / 8, 256, 0, stream>>>(hu, rp, 0,  nbr, am1, NM);
    gather_mean_kernel<HID><<<(NU + 7) / 8, 256, 0, stream>>>(hm, rp, NM, nbr, au1, NU);

    // -------- layer-1 combine: dual MFMA, LN->relu, f32 out (in-place over mean) --------
    mfma_f32_kernel<8, 4, true, 1><<<gbM, 256, 0, stream>>>(
        am1, hm, HID, HID, (const bf16x8*)wf1ml, (const bf16x8*)wf1mr,
        c1_m_bl, ln1_m_g, ln1_m_b, m1, mtM);
    mfma_f32_kernel<8, 4, true, 1><<<gbU, 256, 0, stream>>>(
        au1, hu, HID, HID, (const bf16x8*)wf1ul, (const bf16x8*)wf1ur,
        c1_u_bl, ln1_u_g, ln1_u_b, u1, mtU);

    // -------- layer-2: project 128->64 before aggregating (f32, r3-proven) --------
    proj_kernel<8><<<(NU + 7) / 8, 64, 0, stream>>>(u1, c2_m_wl, pu, NU);
    proj_kernel<8><<<(NM + 7) / 8, 64, 0, stream>>>(m1, c2_u_wl, pm, NM);

    // -------- layer-2 gathers (f32, r3-proven) --------
    gather_mean_kernel<OUTD><<<(NM + 15) / 16, 256, 0, stream>>>(pu, rp, 0,  nbr, am2, NM);
    gather_mean_kernel<OUTD><<<(NU + 15) / 16, 256, 0, stream>>>(pm, rp, NM, nbr, au2, NU);

    // -------- final combine + LN -> d_out (f32, r3-proven) --------
    final_kernel<8><<<(NU + 7) / 8, 64, 0, stream>>>(au2, u1, c2_u_bl, c2_u_wr, ln2_u_g, ln2_u_b, out_u, NU);
    final_kernel<8><<<(NM + 7) / 8, 64, 0, stream>>>(am2, m1, c2_m_bl, c2_m_wr, ln2_m_g, ln2_m_b, out_m, NM);
}

// Round 10
// 766.161 us; speedup vs baseline: 7.5576x; 1.0898x over previous
//
#include <hip/hip_runtime.h>
#include <hip/hip_bf16.h>

#define HID 128
#define OUTD 64
#define FMDIM 404
#define SORT_CAP 96

using bf16x8 = __attribute__((ext_vector_type(8))) short;   // 8 bf16 in 4 VGPRs
using f32x4  = __attribute__((ext_vector_type(4))) float;

static __device__ __forceinline__ short f2b(float f) {
    __hip_bfloat16 h = __float2bfloat16(f);          // RNE
    return *reinterpret_cast<short*>(&h);
}

// guarded float4 load: address always in-bounds, value zero when k0+4 > Kin (Kin % 4 == 0)
static __device__ __forceinline__ float4 ld4_guard(const float* rowp, int k0, int Kin) {
    bool ok = (k0 + 4 <= Kin);
    const float4* p = reinterpret_cast<const float4*>(rowp + (ok ? k0 : 0));
    float4 v = *p;
    return ok ? v : float4{0.f, 0.f, 0.f, 0.f};
}

static __device__ __forceinline__ bf16x8 ldcvt8(const float* rowp, int k0, int Kin) {
    float4 f0 = ld4_guard(rowp, k0, Kin);
    float4 f1 = ld4_guard(rowp, k0 + 4, Kin);
    bf16x8 r;
    r[0] = f2b(f0.x); r[1] = f2b(f0.y); r[2] = f2b(f0.z); r[3] = f2b(f0.w);
    r[4] = f2b(f1.x); r[5] = f2b(f1.y); r[6] = f2b(f1.z); r[7] = f2b(f1.w);
    return r;
}

// ======================= weight repack: f32 W[K][N] -> bf16 frag layout =======================
__global__ void repack_w_kernel(const float* __restrict__ W, short* __restrict__ out,
                                int K, int N, int KT)
{
    int idx = blockIdx.x * blockDim.x + threadIdx.x;
    int total = (N >> 4) * KT * 512;
    if (idx >= total) return;
    int j    = idx & 7;
    int lane = (idx >> 3) & 63;
    int grp  = idx >> 9;
    int kk   = grp % KT, nt = grp / KT;
    int k    = kk * 32 + (lane >> 4) * 8 + j;
    int col  = nt * 16 + (lane & 15);
    out[idx] = (k < K) ? f2b(W[(size_t)k * N + col]) : (short)0;
}

// ======================= MFMA GEMM from f32 activations + LN epilogue, f32 out =======================
// EPI 0: relu then LN (encoder); 1: LN then relu (sage1). One 16-row tile per wave.
template<int NT, int KT, bool DUAL, int EPI>
__global__ __launch_bounds__(256) void mfma_f32_kernel(
    const float* __restrict__ A1, const float* __restrict__ A2, int Kin1, int Kin2,
    const bf16x8* __restrict__ W1, const bf16x8* __restrict__ W2,
    const float* __restrict__ bias, const float* __restrict__ g, const float* __restrict__ beta,
    float* __restrict__ out, int mtiles)
{
    constexpr int N = NT * 16;
    const int lane = threadIdx.x & 63;
    const int wave = threadIdx.x >> 6;
    const int t = blockIdx.x * 4 + wave;
    if (t >= mtiles) return;

    const int lr = lane & 15;                 // A-row / D-col within tile
    const int lk = lane >> 4;                 // k-group
    const int row = t * 16 + lr;
    const float* a1p = A1 + (size_t)row * Kin1;
    const float* a2p = DUAL ? (A2 + (size_t)row * Kin2) : nullptr;

    f32x4 acc[NT];
#pragma unroll
    for (int n = 0; n < NT; ++n) acc[n] = f32x4{0.f, 0.f, 0.f, 0.f};

#pragma unroll
    for (int kk = 0; kk < KT; ++kk) {
        const int k0 = kk * 32 + lk * 8;
        bf16x8 a1 = ldcvt8(a1p, k0, Kin1);
        bf16x8 a2;
        if constexpr (DUAL) a2 = ldcvt8(a2p, k0, Kin2);
#pragma unroll
        for (int n = 0; n < NT; ++n) {
            bf16x8 b1 = W1[(size_t)(n * KT + kk) * 64 + lane];
            acc[n] = __builtin_amdgcn_mfma_f32_16x16x32_bf16(a1, b1, acc[n], 0, 0, 0);
            if constexpr (DUAL) {
                bf16x8 b2 = W2[(size_t)(n * KT + kk) * 64 + lane];
                acc[n] = __builtin_amdgcn_mfma_f32_16x16x32_bf16(a2, b2, acc[n], 0, 0, 0);
            }
        }
    }

    const int rowbase = t * 16;
    float v[NT][4];
#pragma unroll
    for (int n = 0; n < NT; ++n) {
        const float bc = bias[n * 16 + lr];
#pragma unroll
        for (int q = 0; q < 4; ++q) {
            float x = acc[n][q] + bc;
            if constexpr (EPI == 0) x = fmaxf(x, 0.f);
            v[n][q] = x;
        }
    }
    float gcol[NT], becol[NT];
#pragma unroll
    for (int n = 0; n < NT; ++n) { gcol[n] = g[n * 16 + lr]; becol[n] = beta[n * 16 + lr]; }
#pragma unroll
    for (int q = 0; q < 4; ++q) {
        float s = 0.f, ss = 0.f;
#pragma unroll
        for (int n = 0; n < NT; ++n) { s += v[n][q]; ss += v[n][q] * v[n][q]; }
#pragma unroll
        for (int m = 1; m < 16; m <<= 1) {
            s  += __shfl_xor(s, m);
            ss += __shfl_xor(ss, m);
        }
        const float mu   = s * (1.f / N);
        const float rstd = rsqrtf(ss * (1.f / N) - mu * mu + 1e-5f);
#pragma unroll
        for (int n = 0; n < NT; ++n) {
            float o = (v[n][q] - mu) * rstd * gcol[n] + becol[n];
            if constexpr (EPI == 1) o = fmaxf(o, 0.f);
            out[(size_t)(rowbase + lk * 4 + q) * N + n * 16 + lr] = o;
        }
    }
}

// ======================= CSR build =======================
__global__ void deg_csr_kernel(const int* __restrict__ src, const int* __restrict__ dst,
                               int* __restrict__ deg, int NM, int E)
{
    int e = blockIdx.x * blockDim.x + threadIdx.x;
    if (e < E) {
        atomicAdd(&deg[dst[e]], 1);
        atomicAdd(&deg[NM + src[e]], 1);
    }
}

__global__ void scan_partial_kernel(int* __restrict__ data, int* __restrict__ partials, int N)
{
    __shared__ int sh[256];
    const int tid = threadIdx.x;
    const int base = blockIdx.x * 4096 + tid * 16;
    int vals[16];
    int s = 0;
#pragma unroll
    for (int i = 0; i < 16; ++i) {
        int v = (base + i < N) ? data[base + i] : 0;
        vals[i] = s;
        s += v;
    }
    sh[tid] = s;
    __syncthreads();
    for (int off = 1; off < 256; off <<= 1) {
        int t = 0;
        if (tid >= off) t = sh[tid - off];
        __syncthreads();
        sh[tid] += t;
        __syncthreads();
    }
    int excl = (tid == 0) ? 0 : sh[tid - 1];
    if (tid == 255) partials[blockIdx.x] = sh[255];
#pragma unroll
    for (int i = 0; i < 16; ++i)
        if (base + i < N) data[base + i] = excl + vals[i];
}

// fused: each block wave-scans the (<=64) partials itself, then adds the prefix.
// removes the serial single-thread scan_partials dispatch entirely.
__global__ void scan_add_kernel(int* __restrict__ data, const int* __restrict__ partials,
                                int N, int total, int nP)
{
    __shared__ int pref[64];
    const int tid = threadIdx.x;
    if (tid < 64) {
        int v = (tid < nP) ? partials[tid] : 0;
        for (int off = 1; off < 64; off <<= 1) {
            int t = __shfl_up(v, off);
            if (tid >= off) v += t;
        }
        pref[tid] = v;                      // inclusive prefix
    }
    __syncthreads();
    int idx = blockIdx.x * blockDim.x + tid;
    if (idx < N) {
        int p = idx >> 12;
        int excl = (p == 0) ? 0 : pref[p - 1];
        data[idx] += excl;
    }
    if (idx == 0) data[N] = total;
}

__global__ void fill_kernel(const int* __restrict__ src, const int* __restrict__ dst,
                            const int* __restrict__ rowptr, int* __restrict__ cursor,
                            int* __restrict__ nbr, int NM, int E)
{
    int e = blockIdx.x * blockDim.x + threadIdx.x;
    if (e >= E) return;
    int s = src[e], d = dst[e];
    int p0 = atomicAdd(&cursor[d], 1);
    nbr[rowptr[d] + p0] = s;
    int p1 = atomicAdd(&cursor[NM + s], 1);
    nbr[rowptr[NM + s] + p1] = d;
}

// canonicalize each row's neighbor list (sorted multiset) -> order-independent sums.
// LDS-staged insertion sort: buf[i][tid] layout is bank-conflict-free; ~30x lower
// latency than the global-memory version. Fallback to global sort for degree > CAP.
__global__ __launch_bounds__(128) void sort_rows_kernel(const int* __restrict__ rowptr,
                                                        int* __restrict__ nbr, int N)
{
    __shared__ int buf[SORT_CAP][128];
    const int tid = threadIdx.x;
    const int r = blockIdx.x * 128 + tid;
    if (r >= N) return;
    const int beg = rowptr[r], end = rowptr[r + 1];
    const int d = end - beg;
    if (d <= 1) return;
    if (d <= SORT_CAP) {
        for (int i = 0; i < d; ++i) buf[i][tid] = nbr[beg + i];
        for (int i = 1; i < d; ++i) {
            int key = buf[i][tid];
            int j = i - 1;
            while (j >= 0 && buf[j][tid] > key) { buf[j + 1][tid] = buf[j][tid]; --j; }
            buf[j + 1][tid] = key;
        }
        for (int i = 0; i < d; ++i) nbr[beg + i] = buf[i][tid];
    } else {
        for (int i = beg + 1; i < end; ++i) {
            int key = nbr[i];
            int j = i - 1;
            while (j >= beg && nbr[j] > key) { nbr[j + 1] = nbr[j]; --j; }
            nbr[j + 1] = key;
        }
    }
}

// ======================= f32 CSR mean-gather =======================
template<int D>
__global__ void gather_mean_kernel(const float* __restrict__ feat,
                                   const int* __restrict__ rowptr, int rowbase,
                                   const int* __restrict__ nbr,
                                   float* __restrict__ out, int nRows)
{
    constexpr int LPR = D / 4;
    constexpr int RPB = 256 / LPR;
    const int lane = threadIdx.x % LPR;
    const int r    = threadIdx.x / LPR;
    const int row  = blockIdx.x * RPB + r;
    if (row >= nRows) return;

    const int beg = rowptr[rowbase + row];
    const int end = rowptr[rowbase + row + 1];
    const float4* f4 = reinterpret_cast<const float4*>(feat);

    float ax = 0.f, ay = 0.f, az = 0.f, aw = 0.f;
    float bx = 0.f, by = 0.f, bz = 0.f, bw = 0.f;
    int i = beg;
    for (; i + 1 < end; i += 2) {
        int n0 = nbr[i], n1 = nbr[i + 1];
        float4 v0 = f4[(size_t)n0 * LPR + lane];
        float4 v1 = f4[(size_t)n1 * LPR + lane];
        ax += v0.x; ay += v0.y; az += v0.z; aw += v0.w;
        bx += v1.x; by += v1.y; bz += v1.z; bw += v1.w;
    }
    if (i < end) {
        int n0 = nbr[i];
        float4 v0 = f4[(size_t)n0 * LPR + lane];
        ax += v0.x; ay += v0.y; az += v0.z; aw += v0.w;
    }
    ax += bx; ay += by; az += bz; aw += bw;

    const int cnt = end - beg;
    const float inv = (cnt > 0) ? (1.f / (float)cnt) : 0.f;
    float4 o; o.x = ax * inv; o.y = ay * inv; o.z = az * inv; o.w = aw * inv;
    reinterpret_cast<float4*>(out)[(size_t)row * LPR + lane] = o;
}

// ======================= projection: out = feat @ w (128 -> 64), f32 =======================
template<int R>
__global__ void proj_kernel(const float* __restrict__ feat, const float* __restrict__ w,
                            float* __restrict__ out, int n)
{
    __shared__ float4 fs[R][HID / 4];
    const int j = threadIdx.x;               // 0..63
    const int base = blockIdx.x * R;
    const float4* f4 = reinterpret_cast<const float4*>(feat);

    for (int t = j; t < R * 32; t += 64) {
        int r = t >> 5, k = t & 31;
        int row = base + r;
        if (row < n) fs[r][k] = f4[(size_t)row * 32 + k];
    }
    __syncthreads();

    float acc[R];
#pragma unroll
    for (int r = 0; r < R; ++r) acc[r] = 0.f;

    for (int k4 = 0; k4 < 32; ++k4) {
        const float* wp = w + (size_t)(4 * k4) * OUTD + j;
        float w0 = wp[0 * OUTD], w1 = wp[1 * OUTD], w2 = wp[2 * OUTD], w3 = wp[3 * OUTD];
#pragma unroll
        for (int r = 0; r < R; ++r) {
            float4 v = fs[r][k4];
            acc[r] = fmaf(v.x, w0, acc[r]);
            acc[r] = fmaf(v.y, w1, acc[r]);
            acc[r] = fmaf(v.z, w2, acc[r]);
            acc[r] = fmaf(v.w, w3, acc[r]);
        }
    }
    for (int r = 0; r < R; ++r) {
        int row = base + r;
        if (row < n) out[(size_t)row * OUTD + j] = acc[r];
    }
}

// ======================= final: out = LN(meanproj + bl + feat @ wr), f32 =======================
template<int R>
__global__ void final_kernel(const float* __restrict__ meanproj,
                             const float* __restrict__ feat,
                             const float* __restrict__ bl, const float* __restrict__ wr,
                             const float* __restrict__ g, const float* __restrict__ beta,
                             float* __restrict__ out, int n)
{
    __shared__ float4 fs[R][HID / 4];
    const int j = threadIdx.x;               // 0..63
    const int base = blockIdx.x * R;
    const float4* f4 = reinterpret_cast<const float4*>(feat);

    for (int t = j; t < R * 32; t += 64) {
        int r = t >> 5, k = t & 31;
        int row = base + r;
        if (row < n) fs[r][k] = f4[(size_t)row * 32 + k];
    }
    __syncthreads();

    const float blj = bl[j];
    float acc[R];
#pragma unroll
    for (int r = 0; r < R; ++r) {
        int row = base + r;
        acc[r] = (row < n) ? (meanproj[(size_t)row * OUTD + j] + blj) : 0.f;
    }

    for (int k4 = 0; k4 < 32; ++k4) {
        const float* wp = wr + (size_t)(4 * k4) * OUTD + j;
        float w0 = wp[0 * OUTD], w1 = wp[1 * OUTD], w2 = wp[2 * OUTD], w3 = wp[3 * OUTD];
#pragma unroll
        for (int r = 0; r < R; ++r) {
            float4 v = fs[r][k4];
            acc[r] = fmaf(v.x, w0, acc[r]);
            acc[r] = fmaf(v.y, w1, acc[r]);
            acc[r] = fmaf(v.z, w2, acc[r]);
            acc[r] = fmaf(v.w, w3, acc[r]);
        }
    }

    const float gv = g[j], bv = beta[j];
#pragma unroll
    for (int r = 0; r < R; ++r) {
        float v = acc[r];
        float s = v, q = v * v;
        for (int o = 32; o > 0; o >>= 1) { s += __shfl_down(s, o); q += __shfl_down(q, o); }
        s = __shfl(s, 0); q = __shfl(q, 0);
        float mu = s * (1.f / OUTD);
        float rstd = rsqrtf(q * (1.f / OUTD) - mu * mu + 1e-5f);
        int row = base + r;
        if (row < n) out[(size_t)row * OUTD + j] = (v - mu) * rstd * gv + bv;
    }
}

extern "C" void kernel_launch(void* const* d_in, const int* in_sizes, int n_in,
                              void* d_out, int out_size, void* d_ws, size_t ws_size,
                              hipStream_t stream)
{
    const float* x_user   = (const float*)d_in[0];
    const float* x_movie  = (const float*)d_in[1];
    const int*   src      = (const int*)d_in[2];
    const int*   dst      = (const int*)d_in[3];
    const float* enc_u_w  = (const float*)d_in[4];
    const float* enc_u_b  = (const float*)d_in[5];
    const float* enc_u_g  = (const float*)d_in[6];
    const float* enc_u_be = (const float*)d_in[7];
    const float* enc_m_w  = (const float*)d_in[8];
    const float* enc_m_b  = (const float*)d_in[9];
    const float* enc_m_g  = (const float*)d_in[10];
    const float* enc_m_be = (const float*)d_in[11];
    const float* c1_m_wl  = (const float*)d_in[12];
    const float* c1_m_bl  = (const float*)d_in[13];
    const float* c1_m_wr  = (const float*)d_in[14];
    const float* c1_u_wl  = (const float*)d_in[15];
    const float* c1_u_bl  = (const float*)d_in[16];
    const float* c1_u_wr  = (const float*)d_in[17];
    const float* ln1_u_g  = (const float*)d_in[18];
    const float* ln1_u_b  = (const float*)d_in[19];
    const float* ln1_m_g  = (const float*)d_in[20];
    const float* ln1_m_b  = (const float*)d_in[21];
    const float* c2_m_wl  = (const float*)d_in[22];
    const float* c2_m_bl  = (const float*)d_in[23];
    const float* c2_m_wr  = (const float*)d_in[24];
    const float* c2_u_wl  = (const float*)d_in[25];
    const float* c2_u_bl  = (const float*)d_in[26];
    const float* c2_u_wr  = (const float*)d_in[27];
    const float* ln2_u_g  = (const float*)d_in[28];
    const float* ln2_u_b  = (const float*)d_in[29];
    const float* ln2_m_g  = (const float*)d_in[30];
    const float* ln2_m_b  = (const float*)d_in[31];

    const int NU = in_sizes[0] / 16;
    const int NM = in_sizes[1] / FMDIM;
    const int E  = in_sizes[2];
    const int N  = NM + NU;

    // -------- workspace: r9-proven layout --------
    float* ws = (float*)d_ws;
    float* hu  = ws;                              // NU*128 f32
    float* hm  = hu  + (size_t)NU * HID;          // NM*128
    float* am1 = hm  + (size_t)NM * HID;          // NM*128
    float* au1 = am1 + (size_t)NM * HID;          // NU*128
    short* wfu   = (short*)(au1 + (size_t)NU * HID);
    short* wfm   = wfu   + 8 * 1  * 512;
    short* wf1ml = wfm   + 8 * 13 * 512;
    short* wf1mr = wf1ml + 8 * 4  * 512;
    short* wf1ul = wf1mr + 8 * 4  * 512;
    short* wf1ur = wf1ul + 8 * 4  * 512;
    int* rp      = (int*)(wf1ur + 8 * 4 * 512);
    int* cursor  = rp + (N + 1);
    int* partials= cursor + N;
    int* nbr     = partials + 64;
    // overlays: layer-2 buffers over dead hu/hm; m1/u1 in-place
    float* pu  = hu;                          // NU*64
    float* au2 = hu + (size_t)NU * OUTD;      // NU*64
    float* pm  = hm;                          // NM*64
    float* am2 = hm + (size_t)NM * OUTD;      // NM*64
    float* m1  = am1;                         // in-place
    float* u1  = au1;                         // in-place

    float* out_u = (float*)d_out;
    float* out_m = out_u + (size_t)NU * OUTD;

    // -------- weight repacks (bf16 fragments) --------
    auto repack = [&](const float* W, short* out, int K, int Ncols, int KT) {
        int total = (Ncols >> 4) * KT * 512;
        repack_w_kernel<<<(total + 255) / 256, 256, 0, stream>>>(W, out, K, Ncols, KT);
    };
    repack(enc_u_w, wfu,   16,  128, 1);
    repack(enc_m_w, wfm,   404, 128, 13);
    repack(c1_m_wl, wf1ml, 128, 128, 4);
    repack(c1_m_wr, wf1mr, 128, 128, 4);
    repack(c1_u_wl, wf1ul, 128, 128, 4);
    repack(c1_u_wr, wf1ur, 128, 128, 4);

    // -------- CSR build --------
    hipMemsetAsync(rp, 0, (size_t)(2 * N + 1) * sizeof(int), stream);
    deg_csr_kernel<<<(E + 255) / 256, 256, 0, stream>>>(src, dst, rp, NM, E);
    {
        int nP = (N + 4095) / 4096;               // 37 for N=150K (<= 64 by construction)
        scan_partial_kernel<<<nP, 256, 0, stream>>>(rp, partials, N);
        scan_add_kernel<<<(N + 255) / 256, 256, 0, stream>>>(rp, partials, N, 2 * E, nP);
    }
    fill_kernel<<<(E + 255) / 256, 256, 0, stream>>>(src, dst, rp, cursor, nbr, NM, E);
    sort_rows_kernel<<<(N + 127) / 128, 128, 0, stream>>>(rp, nbr, N);

    const int mtU = NU / 16, mtM = NM / 16;      // 6250, 3125 (exact)
    const int gbU = (mtU + 3) / 4, gbM = (mtM + 3) / 4;

    // -------- encoders: MFMA from f32 activations, relu->LN, f32 out --------
    mfma_f32_kernel<8, 1, false, 0><<<gbU, 256, 0, stream>>>(
        x_user, nullptr, 16, 0, (const bf16x8*)wfu, nullptr,
        enc_u_b, enc_u_g, enc_u_be, hu, mtU);
    mfma_f32_kernel<8, 13, false, 0><<<gbM, 256, 0, stream>>>(
        x_movie, nullptr, FMDIM, 0, (const bf16x8*)wfm, nullptr,
        enc_m_b, enc_m_g, enc_m_be, hm, mtM);

    // -------- layer-1 gathers (f32) --------
    gather_mean_kernel<HID><<<(NM + 7) / 8, 256, 0, stream>>>(hu, rp, 0,  nbr, am1, NM);
    gather_mean_kernel<HID><<<(NU + 7) / 8, 256, 0, stream>>>(hm, rp, NM, nbr, au1, NU);

    // -------- layer-1 combine: dual MFMA, LN->relu, f32 out (in-place over mean) --------
    mfma_f32_kernel<8, 4, true, 1><<<gbM, 256, 0, stream>>>(
        am1, hm, HID, HID, (const bf16x8*)wf1ml, (const bf16x8*)wf1mr,
        c1_m_bl, ln1_m_g, ln1_m_b, m1, mtM);
    mfma_f32_kernel<8, 4, true, 1><<<gbU, 256, 0, stream>>>(
        au1, hu, HID, HID, (const bf16x8*)wf1ul, (const bf16x8*)wf1ur,
        c1_u_bl, ln1_u_g, ln1_u_b, u1, mtU);

    // -------- layer-2: project 128->64 before aggregating (f32) --------
    proj_kernel<8><<<(NU + 7) / 8, 64, 0, stream>>>(u1, c2_m_wl, pu, NU);
    proj_kernel<8><<<(NM + 7) / 8, 64, 0, stream>>>(m1, c2_u_wl, pm, NM);

    // -------- layer-2 gathers (f32) --------
    gather_mean_kernel<OUTD><<<(NM + 15) / 16, 256, 0, stream>>>(pu, rp, 0,  nbr, am2, NM);
    gather_mean_kernel<OUTD><<<(NU + 15) / 16, 256, 0, stream>>>(pm, rp, NM, nbr, au2, NU);

    // -------- final combine + LN -> d_out (f32) --------
    final_kernel<8><<<(NU + 7) / 8, 64, 0, stream>>>(au2, u1, c2_u_bl, c2_u_wr, ln2_u_g, ln2_u_b, out_u, NU);
    final_kernel<8><<<(NM + 7) / 8, 64, 0, stream>>>(am2, m1, c2_m_bl, c2_m_wr, ln2_m_g, ln2_m_b, out_m, NM);
}

// Round 11
// 675.617 us; speedup vs baseline: 8.5704x; 1.1340x over previous
//
#include <hip/hip_runtime.h>
#include <hip/hip_bf16.h>

#define HID 128
#define OUTD 64
#define FMDIM 404
#define SORT_CAP 96

using bf16x8 = __attribute__((ext_vector_type(8))) short;   // 8 bf16 in 4 VGPRs
using f32x4  = __attribute__((ext_vector_type(4))) float;
using u16x8  = __attribute__((ext_vector_type(8))) unsigned short;

static __device__ __forceinline__ short f2b(float f) {
    __hip_bfloat16 h = __float2bfloat16(f);          // RNE
    return *reinterpret_cast<short*>(&h);
}
static __device__ __forceinline__ float b2f(unsigned short u) {
    return __uint_as_float(((unsigned)u) << 16);
}

// guarded float4 load: address always in-bounds, value zero when k0+4 > Kin (Kin % 4 == 0)
static __device__ __forceinline__ float4 ld4_guard(const float* rowp, int k0, int Kin) {
    bool ok = (k0 + 4 <= Kin);
    const float4* p = reinterpret_cast<const float4*>(rowp + (ok ? k0 : 0));
    float4 v = *p;
    return ok ? v : float4{0.f, 0.f, 0.f, 0.f};
}

static __device__ __forceinline__ bf16x8 ldcvt8(const float* rowp, int k0, int Kin) {
    float4 f0 = ld4_guard(rowp, k0, Kin);
    float4 f1 = ld4_guard(rowp, k0 + 4, Kin);
    bf16x8 r;
    r[0] = f2b(f0.x); r[1] = f2b(f0.y); r[2] = f2b(f0.z); r[3] = f2b(f0.w);
    r[4] = f2b(f1.x); r[5] = f2b(f1.y); r[6] = f2b(f1.z); r[7] = f2b(f1.w);
    return r;
}

// ======================= weight repack: f32 W[K][N] -> bf16 frag layout =======================
__global__ void repack_w_kernel(const float* __restrict__ W, short* __restrict__ out,
                                int K, int N, int KT)
{
    int idx = blockIdx.x * blockDim.x + threadIdx.x;
    int total = (N >> 4) * KT * 512;
    if (idx >= total) return;
    int j    = idx & 7;
    int lane = (idx >> 3) & 63;
    int grp  = idx >> 9;
    int kk   = grp % KT, nt = grp / KT;
    int k    = kk * 32 + (lane >> 4) * 8 + j;
    int col  = nt * 16 + (lane & 15);
    out[idx] = (k < K) ? f2b(W[(size_t)k * N + col]) : (short)0;
}

// ======================= MFMA GEMM + LN epilogue =======================
// EPI 0: relu->LN (encoder); 1: LN->relu (sage1). One 16-row tile per wave.
// A1 f32 (in-register cvt); A2 either f32 (cvt) or bf16 direct per A2BF.
// OUTB: store bf16 table, else f32.
template<int NT, int KT, bool DUAL, bool A2BF, int EPI, bool OUTB>
__global__ __launch_bounds__(256) void mfma_f32_kernel(
    const float* __restrict__ A1, const float* __restrict__ A2f,
    const bf16x8* __restrict__ A2b, int Kin1, int Kin2,
    const bf16x8* __restrict__ W1, const bf16x8* __restrict__ W2,
    const float* __restrict__ bias, const float* __restrict__ g, const float* __restrict__ beta,
    float* __restrict__ outF, short* __restrict__ outB, int mtiles)
{
    constexpr int N = NT * 16;
    const int lane = threadIdx.x & 63;
    const int wave = threadIdx.x >> 6;
    const int t = blockIdx.x * 4 + wave;
    if (t >= mtiles) return;

    const int lr = lane & 15;                 // A-row / D-col within tile
    const int lk = lane >> 4;                 // k-group
    const int row = t * 16 + lr;
    const float* a1p = A1 + (size_t)row * Kin1;
    const float* a2p = (DUAL && !A2BF) ? (A2f + (size_t)row * Kin2) : nullptr;

    f32x4 acc[NT];
#pragma unroll
    for (int n = 0; n < NT; ++n) acc[n] = f32x4{0.f, 0.f, 0.f, 0.f};

#pragma unroll
    for (int kk = 0; kk < KT; ++kk) {
        const int k0 = kk * 32 + lk * 8;
        bf16x8 a1 = ldcvt8(a1p, k0, Kin1);
        bf16x8 a2;
        if constexpr (DUAL) {
            if constexpr (A2BF) a2 = A2b[(size_t)row * (KT * 4) + kk * 4 + lk];
            else                a2 = ldcvt8(a2p, k0, Kin2);
        }
#pragma unroll
        for (int n = 0; n < NT; ++n) {
            bf16x8 b1 = W1[(size_t)(n * KT + kk) * 64 + lane];
            acc[n] = __builtin_amdgcn_mfma_f32_16x16x32_bf16(a1, b1, acc[n], 0, 0, 0);
            if constexpr (DUAL) {
                bf16x8 b2 = W2[(size_t)(n * KT + kk) * 64 + lane];
                acc[n] = __builtin_amdgcn_mfma_f32_16x16x32_bf16(a2, b2, acc[n], 0, 0, 0);
            }
        }
    }

    const int rowbase = t * 16;
    float v[NT][4];
#pragma unroll
    for (int n = 0; n < NT; ++n) {
        const float bc = bias[n * 16 + lr];
#pragma unroll
        for (int q = 0; q < 4; ++q) {
            float x = acc[n][q] + bc;
            if constexpr (EPI == 0) x = fmaxf(x, 0.f);
            v[n][q] = x;
        }
    }
    float gcol[NT], becol[NT];
#pragma unroll
    for (int n = 0; n < NT; ++n) { gcol[n] = g[n * 16 + lr]; becol[n] = beta[n * 16 + lr]; }
#pragma unroll
    for (int q = 0; q < 4; ++q) {
        float s = 0.f, ss = 0.f;
#pragma unroll
        for (int n = 0; n < NT; ++n) { s += v[n][q]; ss += v[n][q] * v[n][q]; }
#pragma unroll
        for (int m = 1; m < 16; m <<= 1) {
            s  += __shfl_xor(s, m);
            ss += __shfl_xor(ss, m);
        }
        const float mu   = s * (1.f / N);
        const float rstd = rsqrtf(ss * (1.f / N) - mu * mu + 1e-5f);
#pragma unroll
        for (int n = 0; n < NT; ++n) {
            float o = (v[n][q] - mu) * rstd * gcol[n] + becol[n];
            if constexpr (EPI == 1) o = fmaxf(o, 0.f);
            size_t idx = (size_t)(rowbase + lk * 4 + q) * N + n * 16 + lr;
            if constexpr (OUTB) outB[idx] = f2b(o);
            else                outF[idx] = o;
        }
    }
}

// ======================= CSR build =======================
__global__ void deg_csr_kernel(const int* __restrict__ src, const int* __restrict__ dst,
                               int* __restrict__ deg, int NM, int E)
{
    int e = blockIdx.x * blockDim.x + threadIdx.x;
    if (e < E) {
        atomicAdd(&deg[dst[e]], 1);
        atomicAdd(&deg[NM + src[e]], 1);
    }
}

__global__ void scan_partial_kernel(int* __restrict__ data, int* __restrict__ partials, int N)
{
    __shared__ int sh[256];
    const int tid = threadIdx.x;
    const int base = blockIdx.x * 4096 + tid * 16;
    int vals[16];
    int s = 0;
#pragma unroll
    for (int i = 0; i < 16; ++i) {
        int v = (base + i < N) ? data[base + i] : 0;
        vals[i] = s;
        s += v;
    }
    sh[tid] = s;
    __syncthreads();
    for (int off = 1; off < 256; off <<= 1) {
        int t = 0;
        if (tid >= off) t = sh[tid - off];
        __syncthreads();
        sh[tid] += t;
        __syncthreads();
    }
    int excl = (tid == 0) ? 0 : sh[tid - 1];
    if (tid == 255) partials[blockIdx.x] = sh[255];
#pragma unroll
    for (int i = 0; i < 16; ++i)
        if (base + i < N) data[base + i] = excl + vals[i];
}

// fused: each block wave-scans the (<=64) partials itself, then adds the prefix.
__global__ void scan_add_kernel(int* __restrict__ data, const int* __restrict__ partials,
                                int N, int total, int nP)
{
    __shared__ int pref[64];
    const int tid = threadIdx.x;
    if (tid < 64) {
        int v = (tid < nP) ? partials[tid] : 0;
        for (int off = 1; off < 64; off <<= 1) {
            int t = __shfl_up(v, off);
            if (tid >= off) v += t;
        }
        pref[tid] = v;                      // inclusive prefix
    }
    __syncthreads();
    int idx = blockIdx.x * blockDim.x + tid;
    if (idx < N) {
        int p = idx >> 12;
        int excl = (p == 0) ? 0 : pref[p - 1];
        data[idx] += excl;
    }
    if (idx == 0) data[N] = total;
}

__global__ void fill_kernel(const int* __restrict__ src, const int* __restrict__ dst,
                            const int* __restrict__ rowptr, int* __restrict__ cursor,
                            int* __restrict__ nbr, int NM, int E)
{
    int e = blockIdx.x * blockDim.x + threadIdx.x;
    if (e >= E) return;
    int s = src[e], d = dst[e];
    int p0 = atomicAdd(&cursor[d], 1);
    nbr[rowptr[d] + p0] = s;
    int p1 = atomicAdd(&cursor[NM + s], 1);
    nbr[rowptr[NM + s] + p1] = d;
}

// canonicalize each row's neighbor list (sorted multiset) -> order-independent sums.
__global__ __launch_bounds__(128) void sort_rows_kernel(const int* __restrict__ rowptr,
                                                        int* __restrict__ nbr, int N)
{
    __shared__ int buf[SORT_CAP][128];
    const int tid = threadIdx.x;
    const int r = blockIdx.x * 128 + tid;
    if (r >= N) return;
    const int beg = rowptr[r], end = rowptr[r + 1];
    const int d = end - beg;
    if (d <= 1) return;
    if (d <= SORT_CAP) {
        for (int i = 0; i < d; ++i) buf[i][tid] = nbr[beg + i];
        for (int i = 1; i < d; ++i) {
            int key = buf[i][tid];
            int j = i - 1;
            while (j >= 0 && buf[j][tid] > key) { buf[j + 1][tid] = buf[j][tid]; --j; }
            buf[j + 1][tid] = key;
        }
        for (int i = 0; i < d; ++i) nbr[beg + i] = buf[i][tid];
    } else {
        for (int i = beg + 1; i < end; ++i) {
            int key = nbr[i];
            int j = i - 1;
            while (j >= beg && nbr[j] > key) { nbr[j + 1] = nbr[j]; --j; }
            nbr[j + 1] = key;
        }
    }
}

// ======================= bf16-in mean-gather, D=128, f32 out =======================
// 16 lanes per row (u16x8 = 16B each), 16 rows per 256-thread block.
__global__ void gather_mean128_kernel(const unsigned short* __restrict__ feat,
                                      const int* __restrict__ rowptr, int rowbase,
                                      const int* __restrict__ nbr,
                                      float* __restrict__ out, int nRows)
{
    const int lane = threadIdx.x & 15;
    const int r    = threadIdx.x >> 4;
    const int row  = blockIdx.x * 16 + r;
    if (row >= nRows) return;
    const int beg = rowptr[rowbase + row];
    const int end = rowptr[rowbase + row + 1];

    float a[8], b[8];
#pragma unroll
    for (int j = 0; j < 8; ++j) { a[j] = 0.f; b[j] = 0.f; }
    int i = beg;
    for (; i + 1 < end; i += 2) {
        int n0 = nbr[i], n1 = nbr[i + 1];
        u16x8 v0 = *(const u16x8*)(feat + (size_t)n0 * 128 + lane * 8);
        u16x8 v1 = *(const u16x8*)(feat + (size_t)n1 * 128 + lane * 8);
#pragma unroll
        for (int j = 0; j < 8; ++j) { a[j] += b2f(v0[j]); b[j] += b2f(v1[j]); }
    }
    if (i < end) {
        int n0 = nbr[i];
        u16x8 v0 = *(const u16x8*)(feat + (size_t)n0 * 128 + lane * 8);
#pragma unroll
        for (int j = 0; j < 8; ++j) a[j] += b2f(v0[j]);
    }
    const int cnt = end - beg;
    const float inv = (cnt > 0) ? (1.f / (float)cnt) : 0.f;
    float* o = out + (size_t)row * 128 + lane * 8;
    float4 o0, o1;
    o0.x = (a[0]+b[0])*inv; o0.y = (a[1]+b[1])*inv; o0.z = (a[2]+b[2])*inv; o0.w = (a[3]+b[3])*inv;
    o1.x = (a[4]+b[4])*inv; o1.y = (a[5]+b[5])*inv; o1.z = (a[6]+b[6])*inv; o1.w = (a[7]+b[7])*inv;
    reinterpret_cast<float4*>(o)[0] = o0;
    reinterpret_cast<float4*>(o)[1] = o1;
}

// ======================= bf16-in mean-gather, D=64, f32 out =======================
// 8 lanes per row, 32 rows per 256-thread block.
__global__ void gather_mean64_kernel(const unsigned short* __restrict__ feat,
                                     const int* __restrict__ rowptr, int rowbase,
                                     const int* __restrict__ nbr,
                                     float* __restrict__ out, int nRows)
{
    const int lane = threadIdx.x & 7;
    const int r    = threadIdx.x >> 3;
    const int row  = blockIdx.x * 32 + r;
    if (row >= nRows) return;
    const int beg = rowptr[rowbase + row];
    const int end = rowptr[rowbase + row + 1];

    float a[8], b[8];
#pragma unroll
    for (int j = 0; j < 8; ++j) { a[j] = 0.f; b[j] = 0.f; }
    int i = beg;
    for (; i + 1 < end; i += 2) {
        int n0 = nbr[i], n1 = nbr[i + 1];
        u16x8 v0 = *(const u16x8*)(feat + (size_t)n0 * 64 + lane * 8);
        u16x8 v1 = *(const u16x8*)(feat + (size_t)n1 * 64 + lane * 8);
#pragma unroll
        for (int j = 0; j < 8; ++j) { a[j] += b2f(v0[j]); b[j] += b2f(v1[j]); }
    }
    if (i < end) {
        int n0 = nbr[i];
        u16x8 v0 = *(const u16x8*)(feat + (size_t)n0 * 64 + lane * 8);
#pragma unroll
        for (int j = 0; j < 8; ++j) a[j] += b2f(v0[j]);
    }
    const int cnt = end - beg;
    const float inv = (cnt > 0) ? (1.f / (float)cnt) : 0.f;
    float* o = out + (size_t)row * 64 + lane * 8;
    float4 o0, o1;
    o0.x = (a[0]+b[0])*inv; o0.y = (a[1]+b[1])*inv; o0.z = (a[2]+b[2])*inv; o0.w = (a[3]+b[3])*inv;
    o1.x = (a[4]+b[4])*inv; o1.y = (a[5]+b[5])*inv; o1.z = (a[6]+b[6])*inv; o1.w = (a[7]+b[7])*inv;
    reinterpret_cast<float4*>(o)[0] = o0;
    reinterpret_cast<float4*>(o)[1] = o1;
}

// ======================= projection: out16 = bf16(feat @ w) (128 -> 64) =======================
template<int R>
__global__ void proj_kernel(const float* __restrict__ feat, const float* __restrict__ w,
                            short* __restrict__ out, int n)
{
    __shared__ float4 fs[R][HID / 4];
    const int j = threadIdx.x;               // 0..63
    const int base = blockIdx.x * R;
    const float4* f4 = reinterpret_cast<const float4*>(feat);

    for (int t = j; t < R * 32; t += 64) {
        int r = t >> 5, k = t & 31;
        int row = base + r;
        if (row < n) fs[r][k] = f4[(size_t)row * 32 + k];
    }
    __syncthreads();

    float acc[R];
#pragma unroll
    for (int r = 0; r < R; ++r) acc[r] = 0.f;

    for (int k4 = 0; k4 < 32; ++k4) {
        const float* wp = w + (size_t)(4 * k4) * OUTD + j;
        float w0 = wp[0 * OUTD], w1 = wp[1 * OUTD], w2 = wp[2 * OUTD], w3 = wp[3 * OUTD];
#pragma unroll
        for (int r = 0; r < R; ++r) {
            float4 v = fs[r][k4];
            acc[r] = fmaf(v.x, w0, acc[r]);
            acc[r] = fmaf(v.y, w1, acc[r]);
            acc[r] = fmaf(v.z, w2, acc[r]);
            acc[r] = fmaf(v.w, w3, acc[r]);
        }
    }
    for (int r = 0; r < R; ++r) {
        int row = base + r;
        if (row < n) out[(size_t)row * OUTD + j] = f2b(acc[r]);
    }
}

// ======================= final: out = LN(meanproj + bl + feat @ wr), f32 =======================
template<int R>
__global__ void final_kernel(const float* __restrict__ meanproj,
                             const float* __restrict__ feat,
                             const float* __restrict__ bl, const float* __restrict__ wr,
                             const float* __restrict__ g, const float* __restrict__ beta,
                             float* __restrict__ out, int n)
{
    __shared__ float4 fs[R][HID / 4];
    const int j = threadIdx.x;               // 0..63
    const int base = blockIdx.x * R;
    const float4* f4 = reinterpret_cast<const float4*>(feat);

    for (int t = j; t < R * 32; t += 64) {
        int r = t >> 5, k = t & 31;
        int row = base + r;
        if (row < n) fs[r][k] = f4[(size_t)row * 32 + k];
    }
    __syncthreads();

    const float blj = bl[j];
    float acc[R];
#pragma unroll
    for (int r = 0; r < R; ++r) {
        int row = base + r;
        acc[r] = (row < n) ? (meanproj[(size_t)row * OUTD + j] + blj) : 0.f;
    }

    for (int k4 = 0; k4 < 32; ++k4) {
        const float* wp = wr + (size_t)(4 * k4) * OUTD + j;
        float w0 = wp[0 * OUTD], w1 = wp[1 * OUTD], w2 = wp[2 * OUTD], w3 = wp[3 * OUTD];
#pragma unroll
        for (int r = 0; r < R; ++r) {
            float4 v = fs[r][k4];
            acc[r] = fmaf(v.x, w0, acc[r]);
            acc[r] = fmaf(v.y, w1, acc[r]);
            acc[r] = fmaf(v.z, w2, acc[r]);
            acc[r] = fmaf(v.w, w3, acc[r]);
        }
    }

    const float gv = g[j], bv = beta[j];
#pragma unroll
    for (int r = 0; r < R; ++r) {
        float v = acc[r];
        float s = v, q = v * v;
        for (int o = 32; o > 0; o >>= 1) { s += __shfl_down(s, o); q += __shfl_down(q, o); }
        s = __shfl(s, 0); q = __shfl(q, 0);
        float mu = s * (1.f / OUTD);
        float rstd = rsqrtf(q * (1.f / OUTD) - mu * mu + 1e-5f);
        int row = base + r;
        if (row < n) out[(size_t)row * OUTD + j] = (v - mu) * rstd * gv + bv;
    }
}

extern "C" void kernel_launch(void* const* d_in, const int* in_sizes, int n_in,
                              void* d_out, int out_size, void* d_ws, size_t ws_size,
                              hipStream_t stream)
{
    const float* x_user   = (const float*)d_in[0];
    const float* x_movie  = (const float*)d_in[1];
    const int*   src      = (const int*)d_in[2];
    const int*   dst      = (const int*)d_in[3];
    const float* enc_u_w  = (const float*)d_in[4];
    const float* enc_u_b  = (const float*)d_in[5];
    const float* enc_u_g  = (const float*)d_in[6];
    const float* enc_u_be = (const float*)d_in[7];
    const float* enc_m_w  = (const float*)d_in[8];
    const float* enc_m_b  = (const float*)d_in[9];
    const float* enc_m_g  = (const float*)d_in[10];
    const float* enc_m_be = (const float*)d_in[11];
    const float* c1_m_wl  = (const float*)d_in[12];
    const float* c1_m_bl  = (const float*)d_in[13];
    const float* c1_m_wr  = (const float*)d_in[14];
    const float* c1_u_wl  = (const float*)d_in[15];
    const float* c1_u_bl  = (const float*)d_in[16];
    const float* c1_u_wr  = (const float*)d_in[17];
    const float* ln1_u_g  = (const float*)d_in[18];
    const float* ln1_u_b  = (const float*)d_in[19];
    const float* ln1_m_g  = (const float*)d_in[20];
    const float* ln1_m_b  = (const float*)d_in[21];
    const float* c2_m_wl  = (const float*)d_in[22];
    const float* c2_m_bl  = (const float*)d_in[23];
    const float* c2_m_wr  = (const float*)d_in[24];
    const float* c2_u_wl  = (const float*)d_in[25];
    const float* c2_u_bl  = (const float*)d_in[26];
    const float* c2_u_wr  = (const float*)d_in[27];
    const float* ln2_u_g  = (const float*)d_in[28];
    const float* ln2_u_b  = (const float*)d_in[29];
    const float* ln2_m_g  = (const float*)d_in[30];
    const float* ln2_m_b  = (const float*)d_in[31];

    const int NU = in_sizes[0] / 16;
    const int NM = in_sizes[1] / FMDIM;
    const int E  = in_sizes[2];
    const int N  = NM + NU;

    // -------- workspace layout --------
    float* ws = (float*)d_ws;
    float* am1   = ws;                                  // NM*128 f32 (gather out / sage1_m A1 / m1)
    float* au1   = am1 + (size_t)NM * HID;              // NU*128 f32 (gather out / sage1_u A1 / u1)
    short* hub16 = (short*)(au1 + (size_t)NU * HID);    // NU*128 bf16 (enc_u out)
    short* hmb16 = hub16 + (size_t)NU * HID;            // NM*128 bf16 (enc_m out)
    short* pub16 = hmb16 + (size_t)NM * HID;            // NU*64 bf16 (proj_u out)
    short* pmb16 = pub16 + (size_t)NU * OUTD;           // NM*64 bf16 (proj_m out)
    short* wfu   = pmb16 + (size_t)NM * OUTD;
    short* wfm   = wfu   + 8 * 1  * 512;
    short* wf1ml = wfm   + 8 * 13 * 512;
    short* wf1mr = wf1ml + 8 * 4  * 512;
    short* wf1ul = wf1mr + 8 * 4  * 512;
    short* wf1ur = wf1ul + 8 * 4  * 512;
    int* rp      = (int*)(wf1ur + 8 * 4 * 512);
    int* cursor  = rp + (N + 1);
    int* partials= cursor + N;
    int* nbr     = partials + 64;
    // overlays: au2/am2 exactly over dead hub16/hmb16 (dead after sage1; written by gather64)
    float* au2 = (float*)hub16;                         // NU*64 f32 == NU*128 bf16 bytes
    float* am2 = (float*)hmb16;                         // NM*64 f32 == NM*128 bf16 bytes
    float* m1  = am1;                                   // in-place
    float* u1  = au1;                                   // in-place

    float* out_u = (float*)d_out;
    float* out_m = out_u + (size_t)NU * OUTD;

    // -------- weight repacks (bf16 fragments) --------
    auto repack = [&](const float* W, short* out, int K, int Ncols, int KT) {
        int total = (Ncols >> 4) * KT * 512;
        repack_w_kernel<<<(total + 255) / 256, 256, 0, stream>>>(W, out, K, Ncols, KT);
    };
    repack(enc_u_w, wfu,   16,  128, 1);
    repack(enc_m_w, wfm,   404, 128, 13);
    repack(c1_m_wl, wf1ml, 128, 128, 4);
    repack(c1_m_wr, wf1mr, 128, 128, 4);
    repack(c1_u_wl, wf1ul, 128, 128, 4);
    repack(c1_u_wr, wf1ur, 128, 128, 4);

    // -------- CSR build --------
    hipMemsetAsync(rp, 0, (size_t)(2 * N + 1) * sizeof(int), stream);
    deg_csr_kernel<<<(E + 255) / 256, 256, 0, stream>>>(src, dst, rp, NM, E);
    {
        int nP = (N + 4095) / 4096;               // 37 for N=150K (<= 64)
        scan_partial_kernel<<<nP, 256, 0, stream>>>(rp, partials, N);
        scan_add_kernel<<<(N + 255) / 256, 256, 0, stream>>>(rp, partials, N, 2 * E, nP);
    }
    fill_kernel<<<(E + 255) / 256, 256, 0, stream>>>(src, dst, rp, cursor, nbr, NM, E);
    sort_rows_kernel<<<(N + 127) / 128, 128, 0, stream>>>(rp, nbr, N);

    const int mtU = NU / 16, mtM = NM / 16;      // 6250, 3125 (exact)
    const int gbU = (mtU + 3) / 4, gbM = (mtM + 3) / 4;

    // -------- encoders: MFMA from f32 inputs, relu->LN, bf16 table out --------
    mfma_f32_kernel<8, 1, false, false, 0, true><<<gbU, 256, 0, stream>>>(
        x_user, nullptr, nullptr, 16, 0, (const bf16x8*)wfu, nullptr,
        enc_u_b, enc_u_g, enc_u_be, nullptr, hub16, mtU);
    mfma_f32_kernel<8, 13, false, false, 0, true><<<gbM, 256, 0, stream>>>(
        x_movie, nullptr, nullptr, FMDIM, 0, (const bf16x8*)wfm, nullptr,
        enc_m_b, enc_m_g, enc_m_be, nullptr, hmb16, mtM);

    // -------- layer-1 gathers: bf16 in -> f32 mean out --------
    gather_mean128_kernel<<<(NM + 15) / 16, 256, 0, stream>>>(
        (const unsigned short*)hub16, rp, 0,  nbr, am1, NM);
    gather_mean128_kernel<<<(NU + 15) / 16, 256, 0, stream>>>(
        (const unsigned short*)hmb16, rp, NM, nbr, au1, NU);

    // -------- layer-1 combine: A1 f32 mean (cvt), A2 bf16 table direct; LN->relu; f32 out --------
    mfma_f32_kernel<8, 4, true, true, 1, false><<<gbM, 256, 0, stream>>>(
        am1, nullptr, (const bf16x8*)hmb16, HID, HID,
        (const bf16x8*)wf1ml, (const bf16x8*)wf1mr,
        c1_m_bl, ln1_m_g, ln1_m_b, m1, nullptr, mtM);
    mfma_f32_kernel<8, 4, true, true, 1, false><<<gbU, 256, 0, stream>>>(
        au1, nullptr, (const bf16x8*)hub16, HID, HID,
        (const bf16x8*)wf1ul, (const bf16x8*)wf1ur,
        c1_u_bl, ln1_u_g, ln1_u_b, u1, nullptr, mtU);

    // -------- layer-2: project 128->64 before aggregating; bf16 table out --------
    proj_kernel<8><<<(NU + 7) / 8, 64, 0, stream>>>(u1, c2_m_wl, pub16, NU);
    proj_kernel<8><<<(NM + 7) / 8, 64, 0, stream>>>(m1, c2_u_wl, pmb16, NM);

    // -------- layer-2 gathers: bf16 in -> f32 mean out (overlay over dead enc tables) --------
    gather_mean64_kernel<<<(NM + 31) / 32, 256, 0, stream>>>(
        (const unsigned short*)pub16, rp, 0,  nbr, am2, NM);
    gather_mean64_kernel<<<(NU + 31) / 32, 256, 0, stream>>>(
        (const unsigned short*)pmb16, rp, NM, nbr, au2, NU);

    // -------- final combine + LN -> d_out (f32) --------
    final_kernel<8><<<(NU + 7) / 8, 64, 0, stream>>>(au2, u1, c2_u_bl, c2_u_wr, ln2_u_g, ln2_u_b, out_u, NU);
    final_kernel<8><<<(NM + 7) / 8, 64, 0, stream>>>(am2, m1, c2_m_bl, c2_m_wr, ln2_m_g, ln2_m_b, out_m, NM);
}

// Round 12
// 645.327 us; speedup vs baseline: 8.9727x; 1.0469x over previous
//
#include <hip/hip_runtime.h>
#include <hip/hip_bf16.h>

#define HID 128
#define OUTD 64
#define FMDIM 404

using bf16x8 = __attribute__((ext_vector_type(8))) short;   // 8 bf16 in 4 VGPRs
using f32x4  = __attribute__((ext_vector_type(4))) float;
using u16x8  = __attribute__((ext_vector_type(8))) unsigned short;

#define QSCALE 65536.f
#define QINV   (1.f / 65536.f)

static __device__ __forceinline__ short f2b(float f) {
    __hip_bfloat16 h = __float2bfloat16(f);          // RNE
    return *reinterpret_cast<short*>(&h);
}
static __device__ __forceinline__ float b2f(unsigned short u) {
    return __uint_as_float(((unsigned)u) << 16);
}
// fixed-point quantize for order-independent (associative) gather sums
static __device__ __forceinline__ int q16(unsigned short u) {
    return __float2int_rn(b2f(u) * QSCALE);
}

// guarded float4 load: address always in-bounds, value zero when k0+4 > Kin (Kin % 4 == 0)
static __device__ __forceinline__ float4 ld4_guard(const float* rowp, int k0, int Kin) {
    bool ok = (k0 + 4 <= Kin);
    const float4* p = reinterpret_cast<const float4*>(rowp + (ok ? k0 : 0));
    float4 v = *p;
    return ok ? v : float4{0.f, 0.f, 0.f, 0.f};
}

static __device__ __forceinline__ bf16x8 ldcvt8(const float* rowp, int k0, int Kin) {
    float4 f0 = ld4_guard(rowp, k0, Kin);
    float4 f1 = ld4_guard(rowp, k0 + 4, Kin);
    bf16x8 r;
    r[0] = f2b(f0.x); r[1] = f2b(f0.y); r[2] = f2b(f0.z); r[3] = f2b(f0.w);
    r[4] = f2b(f1.x); r[5] = f2b(f1.y); r[6] = f2b(f1.z); r[7] = f2b(f1.w);
    return r;
}

// ======================= weight repack: f32 W[K][N] -> bf16 frag layout =======================
__global__ void repack_w_kernel(const float* __restrict__ W, short* __restrict__ out,
                                int K, int N, int KT)
{
    int idx = blockIdx.x * blockDim.x + threadIdx.x;
    int total = (N >> 4) * KT * 512;
    if (idx >= total) return;
    int j    = idx & 7;
    int lane = (idx >> 3) & 63;
    int grp  = idx >> 9;
    int kk   = grp % KT, nt = grp / KT;
    int k    = kk * 32 + (lane >> 4) * 8 + j;
    int col  = nt * 16 + (lane & 15);
    out[idx] = (k < K) ? f2b(W[(size_t)k * N + col]) : (short)0;
}

// ======================= encoder MFMA: f32 in, relu->LN, bf16 table out =======================
template<int NT, int KT>
__global__ __launch_bounds__(256) void enc_mfma_kernel(
    const float* __restrict__ A1, int Kin1,
    const bf16x8* __restrict__ W1,
    const float* __restrict__ bias, const float* __restrict__ g, const float* __restrict__ beta,
    short* __restrict__ outB, int mtiles)
{
    constexpr int N = NT * 16;
    const int lane = threadIdx.x & 63;
    const int wave = threadIdx.x >> 6;
    const int t = blockIdx.x * 4 + wave;
    if (t >= mtiles) return;

    const int lr = lane & 15;
    const int lk = lane >> 4;
    const int row = t * 16 + lr;
    const float* a1p = A1 + (size_t)row * Kin1;

    f32x4 acc[NT];
#pragma unroll
    for (int n = 0; n < NT; ++n) acc[n] = f32x4{0.f, 0.f, 0.f, 0.f};

#pragma unroll
    for (int kk = 0; kk < KT; ++kk) {
        const int k0 = kk * 32 + lk * 8;
        bf16x8 a1 = ldcvt8(a1p, k0, Kin1);
#pragma unroll
        for (int n = 0; n < NT; ++n) {
            bf16x8 b1 = W1[(size_t)(n * KT + kk) * 64 + lane];
            acc[n] = __builtin_amdgcn_mfma_f32_16x16x32_bf16(a1, b1, acc[n], 0, 0, 0);
        }
    }

    const int rowbase = t * 16;
    float v[NT][4];
#pragma unroll
    for (int n = 0; n < NT; ++n) {
        const float bc = bias[n * 16 + lr];
#pragma unroll
        for (int q = 0; q < 4; ++q) v[n][q] = fmaxf(acc[n][q] + bc, 0.f);
    }
    float gcol[NT], becol[NT];
#pragma unroll
    for (int n = 0; n < NT; ++n) { gcol[n] = g[n * 16 + lr]; becol[n] = beta[n * 16 + lr]; }
#pragma unroll
    for (int q = 0; q < 4; ++q) {
        float s = 0.f, ss = 0.f;
#pragma unroll
        for (int n = 0; n < NT; ++n) { s += v[n][q]; ss += v[n][q] * v[n][q]; }
#pragma unroll
        for (int m = 1; m < 16; m <<= 1) {
            s  += __shfl_xor(s, m);
            ss += __shfl_xor(ss, m);
        }
        const float mu   = s * (1.f / N);
        const float rstd = rsqrtf(ss * (1.f / N) - mu * mu + 1e-5f);
#pragma unroll
        for (int n = 0; n < NT; ++n) {
            float o = (v[n][q] - mu) * rstd * gcol[n] + becol[n];
            outB[(size_t)(rowbase + lk * 4 + q) * N + n * 16 + lr] = f2b(o);
        }
    }
}

// ======================= sage1 fused: in-register int-sum gather + dual MFMA + LN->relu =======================
// A1 = mean over CSR row of gfeat (bf16 [*,128]) via order-independent fixed-point sums;
// A2 = own bf16 table row (direct frags). out = relu(LN(A1@W1 + A2@W2 + bias)) f32.
__global__ __launch_bounds__(256) void sage1_fused_kernel(
    const unsigned short* __restrict__ gfeat,
    const int* __restrict__ rowptr, int rowbase, const int* __restrict__ nbr,
    const bf16x8* __restrict__ A2b,
    const bf16x8* __restrict__ W1, const bf16x8* __restrict__ W2,
    const float* __restrict__ bias, const float* __restrict__ g, const float* __restrict__ beta,
    float* __restrict__ out, int mtiles)
{
    constexpr int NT = 8, KT = 4, N = 128;
    const int lane = threadIdx.x & 63;
    const int wave = threadIdx.x >> 6;
    const int t = blockIdx.x * 4 + wave;
    if (t >= mtiles) return;

    const int lr = lane & 15;
    const int lk = lane >> 4;
    const int row = t * 16 + lr;

    // ---- gather: lane (lr,lk) accumulates its A-fragment's 32 features (4 kk-chunks x 8) ----
    const int beg = rowptr[rowbase + row];
    const int end = rowptr[rowbase + row + 1];
    int iacc[KT][8];
#pragma unroll
    for (int kk = 0; kk < KT; ++kk)
#pragma unroll
        for (int j = 0; j < 8; ++j) iacc[kk][j] = 0;

    for (int i = beg; i < end; ++i) {
        const int nb = nbr[i];
        const u16x8* rp = reinterpret_cast<const u16x8*>(gfeat + (size_t)nb * 128);
#pragma unroll
        for (int kk = 0; kk < KT; ++kk) {
            u16x8 vv = rp[kk * 4 + lk];
#pragma unroll
            for (int j = 0; j < 8; ++j) iacc[kk][j] += q16(vv[j]);
        }
    }
    const int cnt = end - beg;
    const float sc = ((cnt > 0) ? (1.f / (float)cnt) : 0.f) * QINV;
    bf16x8 a1f[KT];
#pragma unroll
    for (int kk = 0; kk < KT; ++kk)
#pragma unroll
        for (int j = 0; j < 8; ++j) a1f[kk][j] = f2b((float)iacc[kk][j] * sc);

    // ---- dual MFMA ----
    f32x4 acc[NT];
#pragma unroll
    for (int n = 0; n < NT; ++n) acc[n] = f32x4{0.f, 0.f, 0.f, 0.f};
#pragma unroll
    for (int kk = 0; kk < KT; ++kk) {
        bf16x8 a2 = A2b[(size_t)row * (KT * 4) + kk * 4 + lk];
#pragma unroll
        for (int n = 0; n < NT; ++n) {
            bf16x8 b1 = W1[(size_t)(n * KT + kk) * 64 + lane];
            acc[n] = __builtin_amdgcn_mfma_f32_16x16x32_bf16(a1f[kk], b1, acc[n], 0, 0, 0);
            bf16x8 b2 = W2[(size_t)(n * KT + kk) * 64 + lane];
            acc[n] = __builtin_amdgcn_mfma_f32_16x16x32_bf16(a2, b2, acc[n], 0, 0, 0);
        }
    }

    // ---- epilogue: bias, LN, relu, f32 out ----
    const int rowbase2 = t * 16;
    float v[NT][4];
#pragma unroll
    for (int n = 0; n < NT; ++n) {
        const float bc = bias[n * 16 + lr];
#pragma unroll
        for (int q = 0; q < 4; ++q) v[n][q] = acc[n][q] + bc;
    }
    float gcol[NT], becol[NT];
#pragma unroll
    for (int n = 0; n < NT; ++n) { gcol[n] = g[n * 16 + lr]; becol[n] = beta[n * 16 + lr]; }
#pragma unroll
    for (int q = 0; q < 4; ++q) {
        float s = 0.f, ss = 0.f;
#pragma unroll
        for (int n = 0; n < NT; ++n) { s += v[n][q]; ss += v[n][q] * v[n][q]; }
#pragma unroll
        for (int m = 1; m < 16; m <<= 1) {
            s  += __shfl_xor(s, m);
            ss += __shfl_xor(ss, m);
        }
        const float mu   = s * (1.f / N);
        const float rstd = rsqrtf(ss * (1.f / N) - mu * mu + 1e-5f);
#pragma unroll
        for (int n = 0; n < NT; ++n) {
            float o = fmaxf((v[n][q] - mu) * rstd * gcol[n] + becol[n], 0.f);
            out[(size_t)(rowbase2 + lk * 4 + q) * N + n * 16 + lr] = o;
        }
    }
}

// ======================= CSR build =======================
__global__ void deg_csr_kernel(const int* __restrict__ src, const int* __restrict__ dst,
                               int* __restrict__ deg, int NM, int E)
{
    int e = blockIdx.x * blockDim.x + threadIdx.x;
    if (e < E) {
        atomicAdd(&deg[dst[e]], 1);
        atomicAdd(&deg[NM + src[e]], 1);
    }
}

__global__ void scan_partial_kernel(int* __restrict__ data, int* __restrict__ partials, int N)
{
    __shared__ int sh[256];
    const int tid = threadIdx.x;
    const int base = blockIdx.x * 4096 + tid * 16;
    int vals[16];
    int s = 0;
#pragma unroll
    for (int i = 0; i < 16; ++i) {
        int v = (base + i < N) ? data[base + i] : 0;
        vals[i] = s;
        s += v;
    }
    sh[tid] = s;
    __syncthreads();
    for (int off = 1; off < 256; off <<= 1) {
        int t = 0;
        if (tid >= off) t = sh[tid - off];
        __syncthreads();
        sh[tid] += t;
        __syncthreads();
    }
    int excl = (tid == 0) ? 0 : sh[tid - 1];
    if (tid == 255) partials[blockIdx.x] = sh[255];
#pragma unroll
    for (int i = 0; i < 16; ++i)
        if (base + i < N) data[base + i] = excl + vals[i];
}

// fused: each block wave-scans the (<=64) partials itself, then adds the prefix.
__global__ void scan_add_kernel(int* __restrict__ data, const int* __restrict__ partials,
                                int N, int total, int nP)
{
    __shared__ int pref[64];
    const int tid = threadIdx.x;
    if (tid < 64) {
        int v = (tid < nP) ? partials[tid] : 0;
        for (int off = 1; off < 64; off <<= 1) {
            int t = __shfl_up(v, off);
            if (tid >= off) v += t;
        }
        pref[tid] = v;                      // inclusive prefix
    }
    __syncthreads();
    int idx = blockIdx.x * blockDim.x + tid;
    if (idx < N) {
        int p = idx >> 12;
        int excl = (p == 0) ? 0 : pref[p - 1];
        data[idx] += excl;
    }
    if (idx == 0) data[N] = total;
}

__global__ void fill_kernel(const int* __restrict__ src, const int* __restrict__ dst,
                            const int* __restrict__ rowptr, int* __restrict__ cursor,
                            int* __restrict__ nbr, int NM, int E)
{
    int e = blockIdx.x * blockDim.x + threadIdx.x;
    if (e >= E) return;
    int s = src[e], d = dst[e];
    int p0 = atomicAdd(&cursor[d], 1);
    nbr[rowptr[d] + p0] = s;
    int p1 = atomicAdd(&cursor[NM + s], 1);
    nbr[rowptr[NM + s] + p1] = d;
}

// ======================= projection: out16 = bf16(feat @ w) (128 -> 64) =======================
template<int R>
__global__ void proj_kernel(const float* __restrict__ feat, const float* __restrict__ w,
                            short* __restrict__ out, int n)
{
    __shared__ float4 fs[R][HID / 4];
    const int j = threadIdx.x;               // 0..63
    const int base = blockIdx.x * R;
    const float4* f4 = reinterpret_cast<const float4*>(feat);

    for (int t = j; t < R * 32; t += 64) {
        int r = t >> 5, k = t & 31;
        int row = base + r;
        if (row < n) fs[r][k] = f4[(size_t)row * 32 + k];
    }
    __syncthreads();

    float acc[R];
#pragma unroll
    for (int r = 0; r < R; ++r) acc[r] = 0.f;

    for (int k4 = 0; k4 < 32; ++k4) {
        const float* wp = w + (size_t)(4 * k4) * OUTD + j;
        float w0 = wp[0 * OUTD], w1 = wp[1 * OUTD], w2 = wp[2 * OUTD], w3 = wp[3 * OUTD];
#pragma unroll
        for (int r = 0; r < R; ++r) {
            float4 v = fs[r][k4];
            acc[r] = fmaf(v.x, w0, acc[r]);
            acc[r] = fmaf(v.y, w1, acc[r]);
            acc[r] = fmaf(v.z, w2, acc[r]);
            acc[r] = fmaf(v.w, w3, acc[r]);
        }
    }
    for (int r = 0; r < R; ++r) {
        int row = base + r;
        if (row < n) out[(size_t)row * OUTD + j] = f2b(acc[r]);
    }
}

// ======================= final fused: inline int-sum gather64 + LN(mean + bl + feat @ wr) =======================
// thread j sums col j of each row's neighbors from bf16 proj table (coalesced 128B/neighbor).
template<int R>
__global__ void final_kernel(const unsigned short* __restrict__ pfeat,
                             const int* __restrict__ rowptr, int rowbase,
                             const int* __restrict__ nbr,
                             const float* __restrict__ feat,
                             const float* __restrict__ bl, const float* __restrict__ wr,
                             const float* __restrict__ g, const float* __restrict__ beta,
                             float* __restrict__ out, int n)
{
    __shared__ float4 fs[R][HID / 4];
    const int j = threadIdx.x;               // 0..63
    const int base = blockIdx.x * R;
    const float4* f4 = reinterpret_cast<const float4*>(feat);

    for (int t = j; t < R * 32; t += 64) {
        int r = t >> 5, k = t & 31;
        int row = base + r;
        if (row < n) fs[r][k] = f4[(size_t)row * 32 + k];
    }
    __syncthreads();

    const float blj = bl[j];
    float acc[R];
#pragma unroll
    for (int r = 0; r < R; ++r) {
        int row = base + r;
        if (row < n) {
            const int beg = rowptr[rowbase + row];
            const int end = rowptr[rowbase + row + 1];
            int isum = 0;
            for (int i = beg; i < end; ++i)
                isum += q16(pfeat[(size_t)nbr[i] * OUTD + j]);
            const int cnt = end - beg;
            const float sc = ((cnt > 0) ? (1.f / (float)cnt) : 0.f) * QINV;
            acc[r] = (float)isum * sc + blj;
        } else acc[r] = 0.f;
    }

    for (int k4 = 0; k4 < 32; ++k4) {
        const float* wp = wr + (size_t)(4 * k4) * OUTD + j;
        float w0 = wp[0 * OUTD], w1 = wp[1 * OUTD], w2 = wp[2 * OUTD], w3 = wp[3 * OUTD];
#pragma unroll
        for (int r = 0; r < R; ++r) {
            float4 v = fs[r][k4];
            acc[r] = fmaf(v.x, w0, acc[r]);
            acc[r] = fmaf(v.y, w1, acc[r]);
            acc[r] = fmaf(v.z, w2, acc[r]);
            acc[r] = fmaf(v.w, w3, acc[r]);
        }
    }

    const float gv = g[j], bv = beta[j];
#pragma unroll
    for (int r = 0; r < R; ++r) {
        float v = acc[r];
        float s = v, q = v * v;
        for (int o = 32; o > 0; o >>= 1) { s += __shfl_down(s, o); q += __shfl_down(q, o); }
        s = __shfl(s, 0); q = __shfl(q, 0);
        float mu = s * (1.f / OUTD);
        float rstd = rsqrtf(q * (1.f / OUTD) - mu * mu + 1e-5f);
        int row = base + r;
        if (row < n) out[(size_t)row * OUTD + j] = (v - mu) * rstd * gv + bv;
    }
}

extern "C" void kernel_launch(void* const* d_in, const int* in_sizes, int n_in,
                              void* d_out, int out_size, void* d_ws, size_t ws_size,
                              hipStream_t stream)
{
    const float* x_user   = (const float*)d_in[0];
    const float* x_movie  = (const float*)d_in[1];
    const int*   src      = (const int*)d_in[2];
    const int*   dst      = (const int*)d_in[3];
    const float* enc_u_w  = (const float*)d_in[4];
    const float* enc_u_b  = (const float*)d_in[5];
    const float* enc_u_g  = (const float*)d_in[6];
    const float* enc_u_be = (const float*)d_in[7];
    const float* enc_m_w  = (const float*)d_in[8];
    const float* enc_m_b  = (const float*)d_in[9];
    const float* enc_m_g  = (const float*)d_in[10];
    const float* enc_m_be = (const float*)d_in[11];
    const float* c1_m_wl  = (const float*)d_in[12];
    const float* c1_m_bl  = (const float*)d_in[13];
    const float* c1_m_wr  = (const float*)d_in[14];
    const float* c1_u_wl  = (const float*)d_in[15];
    const float* c1_u_bl  = (const float*)d_in[16];
    const float* c1_u_wr  = (const float*)d_in[17];
    const float* ln1_u_g  = (const float*)d_in[18];
    const float* ln1_u_b  = (const float*)d_in[19];
    const float* ln1_m_g  = (const float*)d_in[20];
    const float* ln1_m_b  = (const float*)d_in[21];
    const float* c2_m_wl  = (const float*)d_in[22];
    const float* c2_m_bl  = (const float*)d_in[23];
    const float* c2_m_wr  = (const float*)d_in[24];
    const float* c2_u_wl  = (const float*)d_in[25];
    const float* c2_u_bl  = (const float*)d_in[26];
    const float* c2_u_wr  = (const float*)d_in[27];
    const float* ln2_u_g  = (const float*)d_in[28];
    const float* ln2_u_b  = (const float*)d_in[29];
    const float* ln2_m_g  = (const float*)d_in[30];
    const float* ln2_m_b  = (const float*)d_in[31];

    const int NU = in_sizes[0] / 16;
    const int NM = in_sizes[1] / FMDIM;
    const int E  = in_sizes[2];
    const int N  = NM + NU;

    // -------- workspace layout (r11-identical) --------
    float* ws = (float*)d_ws;
    float* am1   = ws;                                  // NM*128 f32 (sage1_m out = m1)
    float* au1   = am1 + (size_t)NM * HID;              // NU*128 f32 (sage1_u out = u1)
    short* hub16 = (short*)(au1 + (size_t)NU * HID);    // NU*128 bf16 (enc_u out)
    short* hmb16 = hub16 + (size_t)NU * HID;            // NM*128 bf16 (enc_m out)
    short* pub16 = hmb16 + (size_t)NM * HID;            // NU*64 bf16 (proj_u out)
    short* pmb16 = pub16 + (size_t)NU * OUTD;           // NM*64 bf16 (proj_m out)
    short* wfu   = pmb16 + (size_t)NM * OUTD;
    short* wfm   = wfu   + 8 * 1  * 512;
    short* wf1ml = wfm   + 8 * 13 * 512;
    short* wf1mr = wf1ml + 8 * 4  * 512;
    short* wf1ul = wf1mr + 8 * 4  * 512;
    short* wf1ur = wf1ul + 8 * 4  * 512;
    int* rp      = (int*)(wf1ur + 8 * 4 * 512);
    int* cursor  = rp + (N + 1);
    int* partials= cursor + N;
    int* nbr     = partials + 64;
    float* m1  = am1;
    float* u1  = au1;

    float* out_u = (float*)d_out;
    float* out_m = out_u + (size_t)NU * OUTD;

    // -------- weight repacks (bf16 fragments) --------
    auto repack = [&](const float* W, short* out, int K, int Ncols, int KT) {
        int total = (Ncols >> 4) * KT * 512;
        repack_w_kernel<<<(total + 255) / 256, 256, 0, stream>>>(W, out, K, Ncols, KT);
    };
    repack(enc_u_w, wfu,   16,  128, 1);
    repack(enc_m_w, wfm,   404, 128, 13);
    repack(c1_m_wl, wf1ml, 128, 128, 4);
    repack(c1_m_wr, wf1mr, 128, 128, 4);
    repack(c1_u_wl, wf1ul, 128, 128, 4);
    repack(c1_u_wr, wf1ur, 128, 128, 4);

    // -------- CSR build (no sort: gather sums are order-independent by construction) --------
    hipMemsetAsync(rp, 0, (size_t)(2 * N + 1) * sizeof(int), stream);
    deg_csr_kernel<<<(E + 255) / 256, 256, 0, stream>>>(src, dst, rp, NM, E);
    {
        int nP = (N + 4095) / 4096;
        scan_partial_kernel<<<nP, 256, 0, stream>>>(rp, partials, N);
        scan_add_kernel<<<(N + 255) / 256, 256, 0, stream>>>(rp, partials, N, 2 * E, nP);
    }
    fill_kernel<<<(E + 255) / 256, 256, 0, stream>>>(src, dst, rp, cursor, nbr, NM, E);

    const int mtU = NU / 16, mtM = NM / 16;      // 6250, 3125 (exact)
    const int gbU = (mtU + 3) / 4, gbM = (mtM + 3) / 4;

    // -------- encoders: MFMA, relu->LN, bf16 table out --------
    enc_mfma_kernel<8, 1><<<gbU, 256, 0, stream>>>(
        x_user, 16, (const bf16x8*)wfu, enc_u_b, enc_u_g, enc_u_be, hub16, mtU);
    enc_mfma_kernel<8, 13><<<gbM, 256, 0, stream>>>(
        x_movie, FMDIM, (const bf16x8*)wfm, enc_m_b, enc_m_g, enc_m_be, hmb16, mtM);

    // -------- layer-1: fused gather + dual MFMA + LN->relu --------
    sage1_fused_kernel<<<gbM, 256, 0, stream>>>(
        (const unsigned short*)hub16, rp, 0, nbr, (const bf16x8*)hmb16,
        (const bf16x8*)wf1ml, (const bf16x8*)wf1mr,
        c1_m_bl, ln1_m_g, ln1_m_b, m1, mtM);
    sage1_fused_kernel<<<gbU, 256, 0, stream>>>(
        (const unsigned short*)hmb16, rp, NM, nbr, (const bf16x8*)hub16,
        (const bf16x8*)wf1ul, (const bf16x8*)wf1ur,
        c1_u_bl, ln1_u_g, ln1_u_b, u1, mtU);

    // -------- layer-2: project 128->64 before aggregating; bf16 table out --------
    proj_kernel<8><<<(NU + 7) / 8, 64, 0, stream>>>(u1, c2_m_wl, pub16, NU);
    proj_kernel<8><<<(NM + 7) / 8, 64, 0, stream>>>(m1, c2_u_wl, pmb16, NM);

    // -------- final: fused gather64 + combine + LN -> d_out --------
    final_kernel<8><<<(NU + 7) / 8, 64, 0, stream>>>(
        (const unsigned short*)pmb16, rp, NM, nbr, u1,
        c2_u_bl, c2_u_wr, ln2_u_g, ln2_u_b, out_u, NU);
    final_kernel<8><<<(NM + 7) / 8, 64, 0, stream>>>(
        (const unsigned short*)pub16, rp, 0, nbr, m1,
        c2_m_bl, c2_m_wr, ln2_m_g, ln2_m_b, out_m, NM);
}

// Round 13
// 638.396 us; speedup vs baseline: 9.0701x; 1.0109x over previous
//
#include <hip/hip_runtime.h>
#include <hip/hip_bf16.h>

#define HID 128
#define OUTD 64
#define FMDIM 404
#define NB 64

using bf16x8 = __attribute__((ext_vector_type(8))) short;   // 8 bf16 in 4 VGPRs
using f32x4  = __attribute__((ext_vector_type(4))) float;
using u16x8  = __attribute__((ext_vector_type(8))) unsigned short;

#define QSCALE 65536.f
#define QINV   (1.f / 65536.f)

static __device__ __forceinline__ short f2b(float f) {
    __hip_bfloat16 h = __float2bfloat16(f);          // RNE
    return *reinterpret_cast<short*>(&h);
}
static __device__ __forceinline__ float b2f(unsigned short u) {
    return __uint_as_float(((unsigned)u) << 16);
}
// fixed-point quantize for order-independent (associative) gather sums
static __device__ __forceinline__ int q16(unsigned short u) {
    return __float2int_rn(b2f(u) * QSCALE);
}

// guarded float4 load: address always in-bounds, value zero when k0+4 > Kin (Kin % 4 == 0)
static __device__ __forceinline__ float4 ld4_guard(const float* rowp, int k0, int Kin) {
    bool ok = (k0 + 4 <= Kin);
    const float4* p = reinterpret_cast<const float4*>(rowp + (ok ? k0 : 0));
    float4 v = *p;
    return ok ? v : float4{0.f, 0.f, 0.f, 0.f};
}

static __device__ __forceinline__ bf16x8 ldcvt8(const float* rowp, int k0, int Kin) {
    float4 f0 = ld4_guard(rowp, k0, Kin);
    float4 f1 = ld4_guard(rowp, k0 + 4, Kin);
    bf16x8 r;
    r[0] = f2b(f0.x); r[1] = f2b(f0.y); r[2] = f2b(f0.z); r[3] = f2b(f0.w);
    r[4] = f2b(f1.x); r[5] = f2b(f1.y); r[6] = f2b(f1.z); r[7] = f2b(f1.w);
    return r;
}

// ======================= weight repack: f32 W[K][N] -> bf16 frag layout =======================
__global__ void repack_w_kernel(const float* __restrict__ W, short* __restrict__ out,
                                int K, int N, int KT)
{
    int idx = blockIdx.x * blockDim.x + threadIdx.x;
    int total = (N >> 4) * KT * 512;
    if (idx >= total) return;
    int j    = idx & 7;
    int lane = (idx >> 3) & 63;
    int grp  = idx >> 9;
    int kk   = grp % KT, nt = grp / KT;
    int k    = kk * 32 + (lane >> 4) * 8 + j;
    int col  = nt * 16 + (lane & 15);
    out[idx] = (k < K) ? f2b(W[(size_t)k * N + col]) : (short)0;
}

// ======================= encoder MFMA: f32 in, relu->LN, bf16 table out =======================
template<int NT, int KT>
__global__ __launch_bounds__(256) void enc_mfma_kernel(
    const float* __restrict__ A1, int Kin1,
    const bf16x8* __restrict__ W1,
    const float* __restrict__ bias, const float* __restrict__ g, const float* __restrict__ beta,
    short* __restrict__ outB, int mtiles)
{
    constexpr int N = NT * 16;
    const int lane = threadIdx.x & 63;
    const int wave = threadIdx.x >> 6;
    const int t = blockIdx.x * 4 + wave;
    if (t >= mtiles) return;

    const int lr = lane & 15;
    const int lk = lane >> 4;
    const int row = t * 16 + lr;
    const float* a1p = A1 + (size_t)row * Kin1;

    f32x4 acc[NT];
#pragma unroll
    for (int n = 0; n < NT; ++n) acc[n] = f32x4{0.f, 0.f, 0.f, 0.f};

#pragma unroll
    for (int kk = 0; kk < KT; ++kk) {
        const int k0 = kk * 32 + lk * 8;
        bf16x8 a1 = ldcvt8(a1p, k0, Kin1);
#pragma unroll
        for (int n = 0; n < NT; ++n) {
            bf16x8 b1 = W1[(size_t)(n * KT + kk) * 64 + lane];
            acc[n] = __builtin_amdgcn_mfma_f32_16x16x32_bf16(a1, b1, acc[n], 0, 0, 0);
        }
    }

    const int rowbase = t * 16;
    float v[NT][4];
#pragma unroll
    for (int n = 0; n < NT; ++n) {
        const float bc = bias[n * 16 + lr];
#pragma unroll
        for (int q = 0; q < 4; ++q) v[n][q] = fmaxf(acc[n][q] + bc, 0.f);
    }
    float gcol[NT], becol[NT];
#pragma unroll
    for (int n = 0; n < NT; ++n) { gcol[n] = g[n * 16 + lr]; becol[n] = beta[n * 16 + lr]; }
#pragma unroll
    for (int q = 0; q < 4; ++q) {
        float s = 0.f, ss = 0.f;
#pragma unroll
        for (int n = 0; n < NT; ++n) { s += v[n][q]; ss += v[n][q] * v[n][q]; }
#pragma unroll
        for (int m = 1; m < 16; m <<= 1) {
            s  += __shfl_xor(s, m);
            ss += __shfl_xor(ss, m);
        }
        const float mu   = s * (1.f / N);
        const float rstd = rsqrtf(ss * (1.f / N) - mu * mu + 1e-5f);
#pragma unroll
        for (int n = 0; n < NT; ++n) {
            float o = (v[n][q] - mu) * rstd * gcol[n] + becol[n];
            outB[(size_t)(rowbase + lk * 4 + q) * N + n * 16 + lr] = f2b(o);
        }
    }
}

// ======================= sage1 fused: in-register int-sum gather + dual MFMA + LN->relu =======================
__global__ __launch_bounds__(256) void sage1_fused_kernel(
    const unsigned short* __restrict__ gfeat,
    const int* __restrict__ rowptr, int rowbase, const int* __restrict__ nbr,
    const bf16x8* __restrict__ A2b,
    const bf16x8* __restrict__ W1, const bf16x8* __restrict__ W2,
    const float* __restrict__ bias, const float* __restrict__ g, const float* __restrict__ beta,
    float* __restrict__ out, int mtiles)
{
    constexpr int NT = 8, KT = 4, N = 128;
    const int lane = threadIdx.x & 63;
    const int wave = threadIdx.x >> 6;
    const int t = blockIdx.x * 4 + wave;
    if (t >= mtiles) return;

    const int lr = lane & 15;
    const int lk = lane >> 4;
    const int row = t * 16 + lr;

    const int beg = rowptr[rowbase + row];
    const int end = rowptr[rowbase + row + 1];
    int iacc[KT][8];
#pragma unroll
    for (int kk = 0; kk < KT; ++kk)
#pragma unroll
        for (int j = 0; j < 8; ++j) iacc[kk][j] = 0;

    for (int i = beg; i < end; ++i) {
        const int nb = nbr[i];
        const u16x8* rp = reinterpret_cast<const u16x8*>(gfeat + (size_t)nb * 128);
#pragma unroll
        for (int kk = 0; kk < KT; ++kk) {
            u16x8 vv = rp[kk * 4 + lk];
#pragma unroll
            for (int j = 0; j < 8; ++j) iacc[kk][j] += q16(vv[j]);
        }
    }
    const int cnt = end - beg;
    const float sc = ((cnt > 0) ? (1.f / (float)cnt) : 0.f) * QINV;
    bf16x8 a1f[KT];
#pragma unroll
    for (int kk = 0; kk < KT; ++kk)
#pragma unroll
        for (int j = 0; j < 8; ++j) a1f[kk][j] = f2b((float)iacc[kk][j] * sc);

    f32x4 acc[NT];
#pragma unroll
    for (int n = 0; n < NT; ++n) acc[n] = f32x4{0.f, 0.f, 0.f, 0.f};
#pragma unroll
    for (int kk = 0; kk < KT; ++kk) {
        bf16x8 a2 = A2b[(size_t)row * (KT * 4) + kk * 4 + lk];
#pragma unroll
        for (int n = 0; n < NT; ++n) {
            bf16x8 b1 = W1[(size_t)(n * KT + kk) * 64 + lane];
            acc[n] = __builtin_amdgcn_mfma_f32_16x16x32_bf16(a1f[kk], b1, acc[n], 0, 0, 0);
            bf16x8 b2 = W2[(size_t)(n * KT + kk) * 64 + lane];
            acc[n] = __builtin_amdgcn_mfma_f32_16x16x32_bf16(a2, b2, acc[n], 0, 0, 0);
        }
    }

    const int rowbase2 = t * 16;
    float v[NT][4];
#pragma unroll
    for (int n = 0; n < NT; ++n) {
        const float bc = bias[n * 16 + lr];
#pragma unroll
        for (int q = 0; q < 4; ++q) v[n][q] = acc[n][q] + bc;
    }
    float gcol[NT], becol[NT];
#pragma unroll
    for (int n = 0; n < NT; ++n) { gcol[n] = g[n * 16 + lr]; becol[n] = beta[n * 16 + lr]; }
#pragma unroll
    for (int q = 0; q < 4; ++q) {
        float s = 0.f, ss = 0.f;
#pragma unroll
        for (int n = 0; n < NT; ++n) { s += v[n][q]; ss += v[n][q] * v[n][q]; }
#pragma unroll
        for (int m = 1; m < 16; m <<= 1) {
            s  += __shfl_xor(s, m);
            ss += __shfl_xor(ss, m);
        }
        const float mu   = s * (1.f / N);
        const float rstd = rsqrtf(ss * (1.f / N) - mu * mu + 1e-5f);
#pragma unroll
        for (int n = 0; n < NT; ++n) {
            float o = fmaxf((v[n][q] - mu) * rstd * gcol[n] + becol[n], 0.f);
            out[(size_t)(rowbase2 + lk * 4 + q) * N + n * 16 + lr] = o;
        }
    }
}

// ======================= CSR build =======================
__global__ void deg_csr_kernel(const int* __restrict__ src, const int* __restrict__ dst,
                               int* __restrict__ deg, int NM, int E)
{
    int e = blockIdx.x * blockDim.x + threadIdx.x;
    if (e < E) {
        atomicAdd(&deg[dst[e]], 1);
        atomicAdd(&deg[NM + src[e]], 1);
    }
}

__global__ void scan_partial_kernel(int* __restrict__ data, int* __restrict__ partials, int N)
{
    __shared__ int sh[256];
    const int tid = threadIdx.x;
    const int base = blockIdx.x * 4096 + tid * 16;
    int vals[16];
    int s = 0;
#pragma unroll
    for (int i = 0; i < 16; ++i) {
        int v = (base + i < N) ? data[base + i] : 0;
        vals[i] = s;
        s += v;
    }
    sh[tid] = s;
    __syncthreads();
    for (int off = 1; off < 256; off <<= 1) {
        int t = 0;
        if (tid >= off) t = sh[tid - off];
        __syncthreads();
        sh[tid] += t;
        __syncthreads();
    }
    int excl = (tid == 0) ? 0 : sh[tid - 1];
    if (tid == 255) partials[blockIdx.x] = sh[255];
#pragma unroll
    for (int i = 0; i < 16; ++i)
        if (base + i < N) data[base + i] = excl + vals[i];
}

__global__ void scan_add_kernel(int* __restrict__ data, const int* __restrict__ partials,
                                int N, int total, int nP)
{
    __shared__ int pref[64];
    const int tid = threadIdx.x;
    if (tid < 64) {
        int v = (tid < nP) ? partials[tid] : 0;
        for (int off = 1; off < 64; off <<= 1) {
            int t = __shfl_up(v, off);
            if (tid >= off) v += t;
        }
        pref[tid] = v;                      // inclusive prefix
    }
    __syncthreads();
    int idx = blockIdx.x * blockDim.x + tid;
    if (idx < N) {
        int p = idx >> 12;
        int excl = (p == 0) ? 0 : pref[p - 1];
        data[idx] += excl;
    }
    if (idx == 0) data[N] = total;
}

// ======================= bucketed fill (write-combining) =======================
// Pass A: stage (row,val) pairs grouped by row-range bucket; per-block contiguous
// runs per bucket => ~full-line writes from a single block/XCD.
__global__ __launch_bounds__(256) void bucket_stage_kernel(
    const int* __restrict__ src, const int* __restrict__ dst,
    const int* __restrict__ rowptr, int* __restrict__ bcur,
    int2* __restrict__ stg, int NM, int NU, int BSZ_M, int BSZ_U, int E)
{
    __shared__ int hist[2 * NB];
    __shared__ int basep[2 * NB];
    __shared__ int bbase[2 * NB];
    const int tid = threadIdx.x;
    const long e0 = (long)blockIdx.x * 2048;

    if (tid < 2 * NB) {
        hist[tid] = 0;
        if (tid < NB) bbase[tid] = rowptr[min(tid * BSZ_M, NM)];
        else          bbase[tid] = rowptr[NM + min((tid - NB) * BSZ_U, NU)];
    }
    __syncthreads();

    int es[8], ed[8];
#pragma unroll
    for (int i = 0; i < 8; ++i) {
        long e = e0 + i * 256 + tid;
        if (e < E) {
            es[i] = src[e]; ed[i] = dst[e];
            atomicAdd(&hist[ed[i] / BSZ_M], 1);
            atomicAdd(&hist[NB + es[i] / BSZ_U], 1);
        } else { es[i] = -1; ed[i] = -1; }
    }
    __syncthreads();
    if (tid < 2 * NB) {
        basep[tid] = atomicAdd(&bcur[tid], hist[tid]);
        hist[tid] = 0;                        // reuse as running in-block cursor
    }
    __syncthreads();
#pragma unroll
    for (int i = 0; i < 8; ++i) {
        if (ed[i] >= 0) {
            int b  = ed[i] / BSZ_M;
            int p  = atomicAdd(&hist[b], 1);
            stg[(long)bbase[b] + basep[b] + p] = make_int2(ed[i], es[i]);
            int b2 = es[i] / BSZ_U;
            int p2 = atomicAdd(&hist[NB + b2], 1);
            stg[(long)bbase[NB + b2] + basep[NB + b2] + p2] = make_int2(NM + es[i], ed[i]);
        }
    }
}

// Pass B: one block per bucket commits its window; nbr writes stay in a ~128KB
// L2-resident window owned by a single block/XCD.
__global__ __launch_bounds__(256) void bucket_commit_kernel(
    const int2* __restrict__ stg, const int* __restrict__ rowptr,
    int* __restrict__ cursor, int* __restrict__ nbr,
    int NM, int NU, int BSZ_M, int BSZ_U)
{
    const int i = blockIdx.x;                 // 0 .. 2*NB-1
    int w0, w1;
    if (i < NB) {
        w0 = rowptr[min(i * BSZ_M, NM)];
        w1 = rowptr[min((i + 1) * BSZ_M, NM)];
    } else {
        int j = i - NB;
        w0 = rowptr[NM + min(j * BSZ_U, NU)];
        w1 = rowptr[NM + min((j + 1) * BSZ_U, NU)];
    }
    for (int k = w0 + (int)threadIdx.x; k < w1; k += (int)blockDim.x) {
        int2 ent = stg[k];
        int slot = rowptr[ent.x] + atomicAdd(&cursor[ent.x], 1);
        nbr[slot] = ent.y;
    }
}

// ======================= projection: out16 = bf16(feat @ w) (128 -> 64) =======================
template<int R>
__global__ void proj_kernel(const float* __restrict__ feat, const float* __restrict__ w,
                            short* __restrict__ out, int n)
{
    __shared__ float4 fs[R][HID / 4];
    const int j = threadIdx.x;               // 0..63
    const int base = blockIdx.x * R;
    const float4* f4 = reinterpret_cast<const float4*>(feat);

    for (int t = j; t < R * 32; t += 64) {
        int r = t >> 5, k = t & 31;
        int row = base + r;
        if (row < n) fs[r][k] = f4[(size_t)row * 32 + k];
    }
    __syncthreads();

    float acc[R];
#pragma unroll
    for (int r = 0; r < R; ++r) acc[r] = 0.f;

    for (int k4 = 0; k4 < 32; ++k4) {
        const float* wp = w + (size_t)(4 * k4) * OUTD + j;
        float w0 = wp[0 * OUTD], w1 = wp[1 * OUTD], w2 = wp[2 * OUTD], w3 = wp[3 * OUTD];
#pragma unroll
        for (int r = 0; r < R; ++r) {
            float4 v = fs[r][k4];
            acc[r] = fmaf(v.x, w0, acc[r]);
            acc[r] = fmaf(v.y, w1, acc[r]);
            acc[r] = fmaf(v.z, w2, acc[r]);
            acc[r] = fmaf(v.w, w3, acc[r]);
        }
    }
    for (int r = 0; r < R; ++r) {
        int row = base + r;
        if (row < n) out[(size_t)row * OUTD + j] = f2b(acc[r]);
    }
}

// ======================= final fused: inline int-sum gather64 + LN(mean + bl + feat @ wr) =======================
template<int R>
__global__ void final_kernel(const unsigned short* __restrict__ pfeat,
                             const int* __restrict__ rowptr, int rowbase,
                             const int* __restrict__ nbr,
                             const float* __restrict__ feat,
                             const float* __restrict__ bl, const float* __restrict__ wr,
                             const float* __restrict__ g, const float* __restrict__ beta,
                             float* __restrict__ out, int n)
{
    __shared__ float4 fs[R][HID / 4];
    const int j = threadIdx.x;               // 0..63
    const int base = blockIdx.x * R;
    const float4* f4 = reinterpret_cast<const float4*>(feat);

    for (int t = j; t < R * 32; t += 64) {
        int r = t >> 5, k = t & 31;
        int row = base + r;
        if (row < n) fs[r][k] = f4[(size_t)row * 32 + k];
    }
    __syncthreads();

    const float blj = bl[j];
    float acc[R];
#pragma unroll
    for (int r = 0; r < R; ++r) {
        int row = base + r;
        if (row < n) {
            const int beg = rowptr[rowbase + row];
            const int end = rowptr[rowbase + row + 1];
            int isum = 0;
            for (int i = beg; i < end; ++i)
                isum += q16(pfeat[(size_t)nbr[i] * OUTD + j]);
            const int cnt = end - beg;
            const float sc = ((cnt > 0) ? (1.f / (float)cnt) : 0.f) * QINV;
            acc[r] = (float)isum * sc + blj;
        } else acc[r] = 0.f;
    }

    for (int k4 = 0; k4 < 32; ++k4) {
        const float* wp = wr + (size_t)(4 * k4) * OUTD + j;
        float w0 = wp[0 * OUTD], w1 = wp[1 * OUTD], w2 = wp[2 * OUTD], w3 = wp[3 * OUTD];
#pragma unroll
        for (int r = 0; r < R; ++r) {
            float4 v = fs[r][k4];
            acc[r] = fmaf(v.x, w0, acc[r]);
            acc[r] = fmaf(v.y, w1, acc[r]);
            acc[r] = fmaf(v.z, w2, acc[r]);
            acc[r] = fmaf(v.w, w3, acc[r]);
        }
    }

    const float gv = g[j], bv = beta[j];
#pragma unroll
    for (int r = 0; r < R; ++r) {
        float v = acc[r];
        float s = v, q = v * v;
        for (int o = 32; o > 0; o >>= 1) { s += __shfl_down(s, o); q += __shfl_down(q, o); }
        s = __shfl(s, 0); q = __shfl(q, 0);
        float mu = s * (1.f / OUTD);
        float rstd = rsqrtf(q * (1.f / OUTD) - mu * mu + 1e-5f);
        int row = base + r;
        if (row < n) out[(size_t)row * OUTD + j] = (v - mu) * rstd * gv + bv;
    }
}

extern "C" void kernel_launch(void* const* d_in, const int* in_sizes, int n_in,
                              void* d_out, int out_size, void* d_ws, size_t ws_size,
                              hipStream_t stream)
{
    const float* x_user   = (const float*)d_in[0];
    const float* x_movie  = (const float*)d_in[1];
    const int*   src      = (const int*)d_in[2];
    const int*   dst      = (const int*)d_in[3];
    const float* enc_u_w  = (const float*)d_in[4];
    const float* enc_u_b  = (const float*)d_in[5];
    const float* enc_u_g  = (const float*)d_in[6];
    const float* enc_u_be = (const float*)d_in[7];
    const float* enc_m_w  = (const float*)d_in[8];
    const float* enc_m_b  = (const float*)d_in[9];
    const float* enc_m_g  = (const float*)d_in[10];
    const float* enc_m_be = (const float*)d_in[11];
    const float* c1_m_wl  = (const float*)d_in[12];
    const float* c1_m_bl  = (const float*)d_in[13];
    const float* c1_m_wr  = (const float*)d_in[14];
    const float* c1_u_wl  = (const float*)d_in[15];
    const float* c1_u_bl  = (const float*)d_in[16];
    const float* c1_u_wr  = (const float*)d_in[17];
    const float* ln1_u_g  = (const float*)d_in[18];
    const float* ln1_u_b  = (const float*)d_in[19];
    const float* ln1_m_g  = (const float*)d_in[20];
    const float* ln1_m_b  = (const float*)d_in[21];
    const float* c2_m_wl  = (const float*)d_in[22];
    const float* c2_m_bl  = (const float*)d_in[23];
    const float* c2_m_wr  = (const float*)d_in[24];
    const float* c2_u_wl  = (const float*)d_in[25];
    const float* c2_u_bl  = (const float*)d_in[26];
    const float* c2_u_wr  = (const float*)d_in[27];
    const float* ln2_u_g  = (const float*)d_in[28];
    const float* ln2_u_b  = (const float*)d_in[29];
    const float* ln2_m_g  = (const float*)d_in[30];
    const float* ln2_m_b  = (const float*)d_in[31];

    const int NU = in_sizes[0] / 16;
    const int NM = in_sizes[1] / FMDIM;
    const int E  = in_sizes[2];
    const int N  = NM + NU;
    const int BSZ_M = (NM + NB - 1) / NB;
    const int BSZ_U = (NU + NB - 1) / NB;

    // -------- workspace layout --------
    float* ws = (float*)d_ws;
    float* am1   = ws;                                  // NM*128 f32 (sage1_m out = m1)
    float* au1   = am1 + (size_t)NM * HID;              // NU*128 f32 (sage1_u out = u1)
    short* hub16 = (short*)(au1 + (size_t)NU * HID);    // NU*128 bf16 (enc_u out)
    short* hmb16 = hub16 + (size_t)NU * HID;            // NM*128 bf16 (enc_m out)
    short* pub16 = hmb16 + (size_t)NM * HID;            // NU*64 bf16 (proj_u out)
    short* pmb16 = pub16 + (size_t)NU * OUTD;           // NM*64 bf16 (proj_m out)
    short* wfu   = pmb16 + (size_t)NM * OUTD;
    short* wfm   = wfu   + 8 * 1  * 512;
    short* wf1ml = wfm   + 8 * 13 * 512;
    short* wf1mr = wf1ml + 8 * 4  * 512;
    short* wf1ul = wf1mr + 8 * 4  * 512;
    short* wf1ur = wf1ul + 8 * 4  * 512;
    int* rp      = (int*)(wf1ur + 8 * 4 * 512);
    int* cursor  = rp + (N + 1);
    int* partials= cursor + N;
    int* bcur    = partials + 64;                       // 128 bucket cursors
    int* after   = bcur + 128;
    int2* stg    = (int2*)(((uintptr_t)after + 15) & ~(uintptr_t)15);  // 2E staged pairs
    int* nbr     = (int*)(stg + (size_t)2 * E);
    float* m1  = am1;
    float* u1  = au1;

    float* out_u = (float*)d_out;
    float* out_m = out_u + (size_t)NU * OUTD;

    // -------- weight repacks (bf16 fragments) --------
    auto repack = [&](const float* W, short* out, int K, int Ncols, int KT) {
        int total = (Ncols >> 4) * KT * 512;
        repack_w_kernel<<<(total + 255) / 256, 256, 0, stream>>>(W, out, K, Ncols, KT);
    };
    repack(enc_u_w, wfu,   16,  128, 1);
    repack(enc_m_w, wfm,   404, 128, 13);
    repack(c1_m_wl, wf1ml, 128, 128, 4);
    repack(c1_m_wr, wf1mr, 128, 128, 4);
    repack(c1_u_wl, wf1ul, 128, 128, 4);
    repack(c1_u_wr, wf1ur, 128, 128, 4);

    // -------- CSR build (bucketed fill; sums downstream are order-independent) --------
    hipMemsetAsync(rp, 0, (size_t)(2 * N + 1 + 64 + 128) * sizeof(int), stream);
    deg_csr_kernel<<<(E + 255) / 256, 256, 0, stream>>>(src, dst, rp, NM, E);
    {
        int nP = (N + 4095) / 4096;
        scan_partial_kernel<<<nP, 256, 0, stream>>>(rp, partials, N);
        scan_add_kernel<<<(N + 255) / 256, 256, 0, stream>>>(rp, partials, N, 2 * E, nP);
    }
    bucket_stage_kernel<<<(E + 2047) / 2048, 256, 0, stream>>>(
        src, dst, rp, bcur, stg, NM, NU, BSZ_M, BSZ_U, E);
    bucket_commit_kernel<<<2 * NB, 256, 0, stream>>>(
        stg, rp, cursor, nbr, NM, NU, BSZ_M, BSZ_U);

    const int mtU = NU / 16, mtM = NM / 16;      // 6250, 3125 (exact)
    const int gbU = (mtU + 3) / 4, gbM = (mtM + 3) / 4;

    // -------- encoders: MFMA, relu->LN, bf16 table out --------
    enc_mfma_kernel<8, 1><<<gbU, 256, 0, stream>>>(
        x_user, 16, (const bf16x8*)wfu, enc_u_b, enc_u_g, enc_u_be, hub16, mtU);
    enc_mfma_kernel<8, 13><<<gbM, 256, 0, stream>>>(
        x_movie, FMDIM, (const bf16x8*)wfm, enc_m_b, enc_m_g, enc_m_be, hmb16, mtM);

    // -------- layer-1: fused gather + dual MFMA + LN->relu --------
    sage1_fused_kernel<<<gbM, 256, 0, stream>>>(
        (const unsigned short*)hub16, rp, 0, nbr, (const bf16x8*)hmb16,
        (const bf16x8*)wf1ml, (const bf16x8*)wf1mr,
        c1_m_bl, ln1_m_g, ln1_m_b, m1, mtM);
    sage1_fused_kernel<<<gbU, 256, 0, stream>>>(
        (const unsigned short*)hmb16, rp, NM, nbr, (const bf16x8*)hub16,
        (const bf16x8*)wf1ul, (const bf16x8*)wf1ur,
        c1_u_bl, ln1_u_g, ln1_u_b, u1, mtU);

    // -------- layer-2: project 128->64 before aggregating; bf16 table out --------
    proj_kernel<8><<<(NU + 7) / 8, 64, 0, stream>>>(u1, c2_m_wl, pub16, NU);
    proj_kernel<8><<<(NM + 7) / 8, 64, 0, stream>>>(m1, c2_u_wl, pmb16, NM);

    // -------- final: fused gather64 + combine + LN -> d_out --------
    final_kernel<8><<<(NU + 7) / 8, 64, 0, stream>>>(
        (const unsigned short*)pmb16, rp, NM, nbr, u1,
        c2_u_bl, c2_u_wr, ln2_u_g, ln2_u_b, out_u, NU);
    final_kernel<8><<<(NM + 7) / 8, 64, 0, stream>>>(
        (const unsigned short*)pub16, rp, 0, nbr, m1,
        c2_m_bl, c2_m_wr, ln2_m_g, ln2_m_b, out_m, NM);
}

// Round 14
// 615.527 us; speedup vs baseline: 9.4071x; 1.0372x over previous
//
#include <hip/hip_runtime.h>
#include <hip/hip_bf16.h>

#define HID 128
#define OUTD 64
#define FMDIM 404
#define NB 64

using bf16x8 = __attribute__((ext_vector_type(8))) short;   // 8 bf16 in 4 VGPRs
using f32x4  = __attribute__((ext_vector_type(4))) float;
using u16x8  = __attribute__((ext_vector_type(8))) unsigned short;

#define QSCALE 65536.f
#define QINV   (1.f / 65536.f)

static __device__ __forceinline__ short f2b(float f) {
    __hip_bfloat16 h = __float2bfloat16(f);          // RNE
    return *reinterpret_cast<short*>(&h);
}
static __device__ __forceinline__ float b2f(unsigned short u) {
    return __uint_as_float(((unsigned)u) << 16);
}
// fixed-point quantize for order-independent (associative) gather sums
static __device__ __forceinline__ int q16(unsigned short u) {
    return __float2int_rn(b2f(u) * QSCALE);
}

// guarded float4 load: address always in-bounds, value zero when k0+4 > Kin (Kin % 4 == 0)
static __device__ __forceinline__ float4 ld4_guard(const float* rowp, int k0, int Kin) {
    bool ok = (k0 + 4 <= Kin);
    const float4* p = reinterpret_cast<const float4*>(rowp + (ok ? k0 : 0));
    float4 v = *p;
    return ok ? v : float4{0.f, 0.f, 0.f, 0.f};
}

static __device__ __forceinline__ bf16x8 ldcvt8(const float* rowp, int k0, int Kin) {
    float4 f0 = ld4_guard(rowp, k0, Kin);
    float4 f1 = ld4_guard(rowp, k0 + 4, Kin);
    bf16x8 r;
    r[0] = f2b(f0.x); r[1] = f2b(f0.y); r[2] = f2b(f0.z); r[3] = f2b(f0.w);
    r[4] = f2b(f1.x); r[5] = f2b(f1.y); r[6] = f2b(f1.z); r[7] = f2b(f1.w);
    return r;
}

// ======================= weight repack: f32 W[K][N] -> bf16 frag layout =======================
__global__ void repack_w_kernel(const float* __restrict__ W, short* __restrict__ out,
                                int K, int N, int KT)
{
    int idx = blockIdx.x * blockDim.x + threadIdx.x;
    int total = (N >> 4) * KT * 512;
    if (idx >= total) return;
    int j    = idx & 7;
    int lane = (idx >> 3) & 63;
    int grp  = idx >> 9;
    int kk   = grp % KT, nt = grp / KT;
    int k    = kk * 32 + (lane >> 4) * 8 + j;
    int col  = nt * 16 + (lane & 15);
    out[idx] = (k < K) ? f2b(W[(size_t)k * N + col]) : (short)0;
}

// ======================= encoder MFMA: f32 in, relu->LN, bf16 table out =======================
template<int NT, int KT>
__global__ __launch_bounds__(256) void enc_mfma_kernel(
    const float* __restrict__ A1, int Kin1,
    const bf16x8* __restrict__ W1,
    const float* __restrict__ bias, const float* __restrict__ g, const float* __restrict__ beta,
    short* __restrict__ outB, int mtiles)
{
    constexpr int N = NT * 16;
    const int lane = threadIdx.x & 63;
    const int wave = threadIdx.x >> 6;
    const int t = blockIdx.x * 4 + wave;
    if (t >= mtiles) return;

    const int lr = lane & 15;
    const int lk = lane >> 4;
    const int row = t * 16 + lr;
    const float* a1p = A1 + (size_t)row * Kin1;

    f32x4 acc[NT];
#pragma unroll
    for (int n = 0; n < NT; ++n) acc[n] = f32x4{0.f, 0.f, 0.f, 0.f};

#pragma unroll
    for (int kk = 0; kk < KT; ++kk) {
        const int k0 = kk * 32 + lk * 8;
        bf16x8 a1 = ldcvt8(a1p, k0, Kin1);
#pragma unroll
        for (int n = 0; n < NT; ++n) {
            bf16x8 b1 = W1[(size_t)(n * KT + kk) * 64 + lane];
            acc[n] = __builtin_amdgcn_mfma_f32_16x16x32_bf16(a1, b1, acc[n], 0, 0, 0);
        }
    }

    const int rowbase = t * 16;
    float v[NT][4];
#pragma unroll
    for (int n = 0; n < NT; ++n) {
        const float bc = bias[n * 16 + lr];
#pragma unroll
        for (int q = 0; q < 4; ++q) v[n][q] = fmaxf(acc[n][q] + bc, 0.f);
    }
    float gcol[NT], becol[NT];
#pragma unroll
    for (int n = 0; n < NT; ++n) { gcol[n] = g[n * 16 + lr]; becol[n] = beta[n * 16 + lr]; }
#pragma unroll
    for (int q = 0; q < 4; ++q) {
        float s = 0.f, ss = 0.f;
#pragma unroll
        for (int n = 0; n < NT; ++n) { s += v[n][q]; ss += v[n][q] * v[n][q]; }
#pragma unroll
        for (int m = 1; m < 16; m <<= 1) {
            s  += __shfl_xor(s, m);
            ss += __shfl_xor(ss, m);
        }
        const float mu   = s * (1.f / N);
        const float rstd = rsqrtf(ss * (1.f / N) - mu * mu + 1e-5f);
#pragma unroll
        for (int n = 0; n < NT; ++n) {
            float o = (v[n][q] - mu) * rstd * gcol[n] + becol[n];
            outB[(size_t)(rowbase + lk * 4 + q) * N + n * 16 + lr] = f2b(o);
        }
    }
}

// ======================= sage1 fused: int-sum gather + dual MFMA + LN->relu, bf16 out =======================
__global__ __launch_bounds__(256) void sage1_fused_kernel(
    const unsigned short* __restrict__ gfeat,
    const int* __restrict__ rowptr, int rowbase, const int* __restrict__ nbr,
    const bf16x8* __restrict__ A2b,
    const bf16x8* __restrict__ W1, const bf16x8* __restrict__ W2,
    const float* __restrict__ bias, const float* __restrict__ g, const float* __restrict__ beta,
    short* __restrict__ out, int mtiles)
{
    constexpr int NT = 8, KT = 4, N = 128;
    const int lane = threadIdx.x & 63;
    const int wave = threadIdx.x >> 6;
    const int t = blockIdx.x * 4 + wave;
    if (t >= mtiles) return;

    const int lr = lane & 15;
    const int lk = lane >> 4;
    const int row = t * 16 + lr;

    const int beg = rowptr[rowbase + row];
    const int end = rowptr[rowbase + row + 1];
    int iacc[KT][8];
#pragma unroll
    for (int kk = 0; kk < KT; ++kk)
#pragma unroll
        for (int j = 0; j < 8; ++j) iacc[kk][j] = 0;

    for (int i = beg; i < end; ++i) {
        const int nb = nbr[i];
        const u16x8* rp = reinterpret_cast<const u16x8*>(gfeat + (size_t)nb * 128);
#pragma unroll
        for (int kk = 0; kk < KT; ++kk) {
            u16x8 vv = rp[kk * 4 + lk];
#pragma unroll
            for (int j = 0; j < 8; ++j) iacc[kk][j] += q16(vv[j]);
        }
    }
    const int cnt = end - beg;
    const float sc = ((cnt > 0) ? (1.f / (float)cnt) : 0.f) * QINV;
    bf16x8 a1f[KT];
#pragma unroll
    for (int kk = 0; kk < KT; ++kk)
#pragma unroll
        for (int j = 0; j < 8; ++j) a1f[kk][j] = f2b((float)iacc[kk][j] * sc);

    f32x4 acc[NT];
#pragma unroll
    for (int n = 0; n < NT; ++n) acc[n] = f32x4{0.f, 0.f, 0.f, 0.f};
#pragma unroll
    for (int kk = 0; kk < KT; ++kk) {
        bf16x8 a2 = A2b[(size_t)row * (KT * 4) + kk * 4 + lk];
#pragma unroll
        for (int n = 0; n < NT; ++n) {
            bf16x8 b1 = W1[(size_t)(n * KT + kk) * 64 + lane];
            acc[n] = __builtin_amdgcn_mfma_f32_16x16x32_bf16(a1f[kk], b1, acc[n], 0, 0, 0);
            bf16x8 b2 = W2[(size_t)(n * KT + kk) * 64 + lane];
            acc[n] = __builtin_amdgcn_mfma_f32_16x16x32_bf16(a2, b2, acc[n], 0, 0, 0);
        }
    }

    const int rowbase2 = t * 16;
    float v[NT][4];
#pragma unroll
    for (int n = 0; n < NT; ++n) {
        const float bc = bias[n * 16 + lr];
#pragma unroll
        for (int q = 0; q < 4; ++q) v[n][q] = acc[n][q] + bc;
    }
    float gcol[NT], becol[NT];
#pragma unroll
    for (int n = 0; n < NT; ++n) { gcol[n] = g[n * 16 + lr]; becol[n] = beta[n * 16 + lr]; }
#pragma unroll
    for (int q = 0; q < 4; ++q) {
        float s = 0.f, ss = 0.f;
#pragma unroll
        for (int n = 0; n < NT; ++n) { s += v[n][q]; ss += v[n][q] * v[n][q]; }
#pragma unroll
        for (int m = 1; m < 16; m <<= 1) {
            s  += __shfl_xor(s, m);
            ss += __shfl_xor(ss, m);
        }
        const float mu   = s * (1.f / N);
        const float rstd = rsqrtf(ss * (1.f / N) - mu * mu + 1e-5f);
#pragma unroll
        for (int n = 0; n < NT; ++n) {
            float o = fmaxf((v[n][q] - mu) * rstd * gcol[n] + becol[n], 0.f);
            out[(size_t)(rowbase2 + lk * 4 + q) * N + n * 16 + lr] = f2b(o);
        }
    }
}

// ======================= CSR build =======================
__global__ void deg_csr_kernel(const int* __restrict__ src, const int* __restrict__ dst,
                               int* __restrict__ deg, int NM, int E)
{
    int e = blockIdx.x * blockDim.x + threadIdx.x;
    if (e < E) {
        atomicAdd(&deg[dst[e]], 1);
        atomicAdd(&deg[NM + src[e]], 1);
    }
}

__global__ void scan_partial_kernel(int* __restrict__ data, int* __restrict__ partials, int N)
{
    __shared__ int sh[256];
    const int tid = threadIdx.x;
    const int base = blockIdx.x * 4096 + tid * 16;
    int vals[16];
    int s = 0;
#pragma unroll
    for (int i = 0; i < 16; ++i) {
        int v = (base + i < N) ? data[base + i] : 0;
        vals[i] = s;
        s += v;
    }
    sh[tid] = s;
    __syncthreads();
    for (int off = 1; off < 256; off <<= 1) {
        int t = 0;
        if (tid >= off) t = sh[tid - off];
        __syncthreads();
        sh[tid] += t;
        __syncthreads();
    }
    int excl = (tid == 0) ? 0 : sh[tid - 1];
    if (tid == 255) partials[blockIdx.x] = sh[255];
#pragma unroll
    for (int i = 0; i < 16; ++i)
        if (base + i < N) data[base + i] = excl + vals[i];
}

__global__ void scan_add_kernel(int* __restrict__ data, const int* __restrict__ partials,
                                int N, int total, int nP)
{
    __shared__ int pref[64];
    const int tid = threadIdx.x;
    if (tid < 64) {
        int v = (tid < nP) ? partials[tid] : 0;
        for (int off = 1; off < 64; off <<= 1) {
            int t = __shfl_up(v, off);
            if (tid >= off) v += t;
        }
        pref[tid] = v;                      // inclusive prefix
    }
    __syncthreads();
    int idx = blockIdx.x * blockDim.x + tid;
    if (idx < N) {
        int p = idx >> 12;
        int excl = (p == 0) ? 0 : pref[p - 1];
        data[idx] += excl;
    }
    if (idx == 0) data[N] = total;
}

// ======================= bucketed fill (write-combining) =======================
__global__ __launch_bounds__(256) void bucket_stage_kernel(
    const int* __restrict__ src, const int* __restrict__ dst,
    const int* __restrict__ rowptr, int* __restrict__ bcur,
    int2* __restrict__ stg, int NM, int NU, int BSZ_M, int BSZ_U, int E)
{
    __shared__ int hist[2 * NB];
    __shared__ int basep[2 * NB];
    __shared__ int bbase[2 * NB];
    const int tid = threadIdx.x;
    const long e0 = (long)blockIdx.x * 2048;

    if (tid < 2 * NB) {
        hist[tid] = 0;
        if (tid < NB) bbase[tid] = rowptr[min(tid * BSZ_M, NM)];
        else          bbase[tid] = rowptr[NM + min((tid - NB) * BSZ_U, NU)];
    }
    __syncthreads();

    int es[8], ed[8];
#pragma unroll
    for (int i = 0; i < 8; ++i) {
        long e = e0 + i * 256 + tid;
        if (e < E) {
            es[i] = src[e]; ed[i] = dst[e];
            atomicAdd(&hist[ed[i] / BSZ_M], 1);
            atomicAdd(&hist[NB + es[i] / BSZ_U], 1);
        } else { es[i] = -1; ed[i] = -1; }
    }
    __syncthreads();
    if (tid < 2 * NB) {
        basep[tid] = atomicAdd(&bcur[tid], hist[tid]);
        hist[tid] = 0;                        // reuse as running in-block cursor
    }
    __syncthreads();
#pragma unroll
    for (int i = 0; i < 8; ++i) {
        if (ed[i] >= 0) {
            int b  = ed[i] / BSZ_M;
            int p  = atomicAdd(&hist[b], 1);
            stg[(long)bbase[b] + basep[b] + p] = make_int2(ed[i], es[i]);
            int b2 = es[i] / BSZ_U;
            int p2 = atomicAdd(&hist[NB + b2], 1);
            stg[(long)bbase[NB + b2] + basep[NB + b2] + p2] = make_int2(NM + es[i], ed[i]);
        }
    }
}

__global__ __launch_bounds__(256) void bucket_commit_kernel(
    const int2* __restrict__ stg, const int* __restrict__ rowptr,
    int* __restrict__ cursor, int* __restrict__ nbr,
    int NM, int NU, int BSZ_M, int BSZ_U)
{
    const int i = blockIdx.x;                 // 0 .. 2*NB-1
    int w0, w1;
    if (i < NB) {
        w0 = rowptr[min(i * BSZ_M, NM)];
        w1 = rowptr[min((i + 1) * BSZ_M, NM)];
    } else {
        int j = i - NB;
        w0 = rowptr[NM + min(j * BSZ_U, NU)];
        w1 = rowptr[NM + min((j + 1) * BSZ_U, NU)];
    }
    for (int k = w0 + (int)threadIdx.x; k < w1; k += (int)blockDim.x) {
        int2 ent = stg[k];
        int slot = rowptr[ent.x] + atomicAdd(&cursor[ent.x], 1);
        nbr[slot] = ent.y;
    }
}

// ======================= projection: out16 = bf16(feat16 @ w) (128 -> 64) =======================
template<int R>
__global__ void proj_kernel(const unsigned short* __restrict__ feat, const float* __restrict__ w,
                            short* __restrict__ out, int n)
{
    __shared__ float4 fs[R][HID / 4];
    const int j = threadIdx.x;               // 0..63
    const int base = blockIdx.x * R;

    for (int t = j; t < R * 16; t += 64) {
        int r = t >> 4, k = t & 15;
        int row = base + r;
        if (row < n) {
            u16x8 v = *(const u16x8*)(feat + (size_t)row * HID + k * 8);
            fs[r][2 * k]     = float4{b2f(v[0]), b2f(v[1]), b2f(v[2]), b2f(v[3])};
            fs[r][2 * k + 1] = float4{b2f(v[4]), b2f(v[5]), b2f(v[6]), b2f(v[7])};
        }
    }
    __syncthreads();

    float acc[R];
#pragma unroll
    for (int r = 0; r < R; ++r) acc[r] = 0.f;

    for (int k4 = 0; k4 < 32; ++k4) {
        const float* wp = w + (size_t)(4 * k4) * OUTD + j;
        float w0 = wp[0 * OUTD], w1 = wp[1 * OUTD], w2 = wp[2 * OUTD], w3 = wp[3 * OUTD];
#pragma unroll
        for (int r = 0; r < R; ++r) {
            float4 v = fs[r][k4];
            acc[r] = fmaf(v.x, w0, acc[r]);
            acc[r] = fmaf(v.y, w1, acc[r]);
            acc[r] = fmaf(v.z, w2, acc[r]);
            acc[r] = fmaf(v.w, w3, acc[r]);
        }
    }
    for (int r = 0; r < R; ++r) {
        int row = base + r;
        if (row < n) out[(size_t)row * OUTD + j] = f2b(acc[r]);
    }
}

// ======================= final fused: int-sum gather64 + LN(mean + bl + feat16 @ wr) =======================
template<int R>
__global__ void final_kernel(const unsigned short* __restrict__ pfeat,
                             const int* __restrict__ rowptr, int rowbase,
                             const int* __restrict__ nbr,
                             const unsigned short* __restrict__ feat,
                             const float* __restrict__ bl, const float* __restrict__ wr,
                             const float* __restrict__ g, const float* __restrict__ beta,
                             float* __restrict__ out, int n)
{
    __shared__ float4 fs[R][HID / 4];
    const int j = threadIdx.x;               // 0..63
    const int base = blockIdx.x * R;

    for (int t = j; t < R * 16; t += 64) {
        int r = t >> 4, k = t & 15;
        int row = base + r;
        if (row < n) {
            u16x8 v = *(const u16x8*)(feat + (size_t)row * HID + k * 8);
            fs[r][2 * k]     = float4{b2f(v[0]), b2f(v[1]), b2f(v[2]), b2f(v[3])};
            fs[r][2 * k + 1] = float4{b2f(v[4]), b2f(v[5]), b2f(v[6]), b2f(v[7])};
        }
    }
    __syncthreads();

    const float blj = bl[j];
    float acc[R];
#pragma unroll
    for (int r = 0; r < R; ++r) {
        int row = base + r;
        if (row < n) {
            const int beg = rowptr[rowbase + row];
            const int end = rowptr[rowbase + row + 1];
            int isum = 0;
            for (int i = beg; i < end; ++i)
                isum += q16(pfeat[(size_t)nbr[i] * OUTD + j]);
            const int cnt = end - beg;
            const float sc = ((cnt > 0) ? (1.f / (float)cnt) : 0.f) * QINV;
            acc[r] = (float)isum * sc + blj;
        } else acc[r] = 0.f;
    }

    for (int k4 = 0; k4 < 32; ++k4) {
        const float* wp = wr + (size_t)(4 * k4) * OUTD + j;
        float w0 = wp[0 * OUTD], w1 = wp[1 * OUTD], w2 = wp[2 * OUTD], w3 = wp[3 * OUTD];
#pragma unroll
        for (int r = 0; r < R; ++r) {
            float4 v = fs[r][k4];
            acc[r] = fmaf(v.x, w0, acc[r]);
            acc[r] = fmaf(v.y, w1, acc[r]);
            acc[r] = fmaf(v.z, w2, acc[r]);
            acc[r] = fmaf(v.w, w3, acc[r]);
        }
    }

    const float gv = g[j], bv = beta[j];
#pragma unroll
    for (int r = 0; r < R; ++r) {
        float v = acc[r];
        float s = v, q = v * v;
        for (int o = 32; o > 0; o >>= 1) { s += __shfl_down(s, o); q += __shfl_down(q, o); }
        s = __shfl(s, 0); q = __shfl(q, 0);
        float mu = s * (1.f / OUTD);
        float rstd = rsqrtf(q * (1.f / OUTD) - mu * mu + 1e-5f);
        int row = base + r;
        if (row < n) out[(size_t)row * OUTD + j] = (v - mu) * rstd * gv + bv;
    }
}

extern "C" void kernel_launch(void* const* d_in, const int* in_sizes, int n_in,
                              void* d_out, int out_size, void* d_ws, size_t ws_size,
                              hipStream_t stream)
{
    const float* x_user   = (const float*)d_in[0];
    const float* x_movie  = (const float*)d_in[1];
    const int*   src      = (const int*)d_in[2];
    const int*   dst      = (const int*)d_in[3];
    const float* enc_u_w  = (const float*)d_in[4];
    const float* enc_u_b  = (const float*)d_in[5];
    const float* enc_u_g  = (const float*)d_in[6];
    const float* enc_u_be = (const float*)d_in[7];
    const float* enc_m_w  = (const float*)d_in[8];
    const float* enc_m_b  = (const float*)d_in[9];
    const float* enc_m_g  = (const float*)d_in[10];
    const float* enc_m_be = (const float*)d_in[11];
    const float* c1_m_wl  = (const float*)d_in[12];
    const float* c1_m_bl  = (const float*)d_in[13];
    const float* c1_m_wr  = (const float*)d_in[14];
    const float* c1_u_wl  = (const float*)d_in[15];
    const float* c1_u_bl  = (const float*)d_in[16];
    const float* c1_u_wr  = (const float*)d_in[17];
    const float* ln1_u_g  = (const float*)d_in[18];
    const float* ln1_u_b  = (const float*)d_in[19];
    const float* ln1_m_g  = (const float*)d_in[20];
    const float* ln1_m_b  = (const float*)d_in[21];
    const float* c2_m_wl  = (const float*)d_in[22];
    const float* c2_m_bl  = (const float*)d_in[23];
    const float* c2_m_wr  = (const float*)d_in[24];
    const float* c2_u_wl  = (const float*)d_in[25];
    const float* c2_u_bl  = (const float*)d_in[26];
    const float* c2_u_wr  = (const float*)d_in[27];
    const float* ln2_u_g  = (const float*)d_in[28];
    const float* ln2_u_b  = (const float*)d_in[29];
    const float* ln2_m_g  = (const float*)d_in[30];
    const float* ln2_m_b  = (const float*)d_in[31];

    const int NU = in_sizes[0] / 16;
    const int NM = in_sizes[1] / FMDIM;
    const int E  = in_sizes[2];
    const int N  = NM + NU;
    const int BSZ_M = (NM + NB - 1) / NB;
    const int BSZ_U = (NU + NB - 1) / NB;

    // -------- workspace layout (all bf16 tables; no overlays) --------
    short* hub16 = (short*)d_ws;                        // NU*128 bf16 (enc_u out)
    short* hmb16 = hub16 + (size_t)NU * HID;            // NM*128 bf16 (enc_m out)
    short* u1b16 = hmb16 + (size_t)NM * HID;            // NU*128 bf16 (sage1_u out)
    short* m1b16 = u1b16 + (size_t)NU * HID;            // NM*128 bf16 (sage1_m out)
    short* pub16 = m1b16 + (size_t)NM * HID;            // NU*64 bf16 (proj_u out)
    short* pmb16 = pub16 + (size_t)NU * OUTD;           // NM*64 bf16 (proj_m out)
    short* wfu   = pmb16 + (size_t)NM * OUTD;
    short* wfm   = wfu   + 8 * 1  * 512;
    short* wf1ml = wfm   + 8 * 13 * 512;
    short* wf1mr = wf1ml + 8 * 4  * 512;
    short* wf1ul = wf1mr + 8 * 4  * 512;
    short* wf1ur = wf1ul + 8 * 4  * 512;
    int* rp      = (int*)(wf1ur + 8 * 4 * 512);
    int* cursor  = rp + (N + 1);
    int* partials= cursor + N;
    int* bcur    = partials + 64;                       // 128 bucket cursors
    int* after   = bcur + 128;
    int2* stg    = (int2*)(((uintptr_t)after + 15) & ~(uintptr_t)15);  // 2E staged pairs
    int* nbr     = (int*)(stg + (size_t)2 * E);

    float* out_u = (float*)d_out;
    float* out_m = out_u + (size_t)NU * OUTD;

    // -------- weight repacks (bf16 fragments) --------
    auto repack = [&](const float* W, short* out, int K, int Ncols, int KT) {
        int total = (Ncols >> 4) * KT * 512;
        repack_w_kernel<<<(total + 255) / 256, 256, 0, stream>>>(W, out, K, Ncols, KT);
    };
    repack(enc_u_w, wfu,   16,  128, 1);
    repack(enc_m_w, wfm,   404, 128, 13);
    repack(c1_m_wl, wf1ml, 128, 128, 4);
    repack(c1_m_wr, wf1mr, 128, 128, 4);
    repack(c1_u_wl, wf1ul, 128, 128, 4);
    repack(c1_u_wr, wf1ur, 128, 128, 4);

    // -------- CSR build (bucketed fill) --------
    hipMemsetAsync(rp, 0, (size_t)(2 * N + 1 + 64 + 128) * sizeof(int), stream);
    deg_csr_kernel<<<(E + 255) / 256, 256, 0, stream>>>(src, dst, rp, NM, E);
    {
        int nP = (N + 4095) / 4096;
        scan_partial_kernel<<<nP, 256, 0, stream>>>(rp, partials, N);
        scan_add_kernel<<<(N + 255) / 256, 256, 0, stream>>>(rp, partials, N, 2 * E, nP);
    }
    bucket_stage_kernel<<<(E + 2047) / 2048, 256, 0, stream>>>(
        src, dst, rp, bcur, stg, NM, NU, BSZ_M, BSZ_U, E);
    bucket_commit_kernel<<<2 * NB, 256, 0, stream>>>(
        stg, rp, cursor, nbr, NM, NU, BSZ_M, BSZ_U);

    const int mtU = NU / 16, mtM = NM / 16;      // 6250, 3125 (exact)
    const int gbU = (mtU + 3) / 4, gbM = (mtM + 3) / 4;

    // -------- encoders: MFMA, relu->LN, bf16 table out --------
    enc_mfma_kernel<8, 1><<<gbU, 256, 0, stream>>>(
        x_user, 16, (const bf16x8*)wfu, enc_u_b, enc_u_g, enc_u_be, hub16, mtU);
    enc_mfma_kernel<8, 13><<<gbM, 256, 0, stream>>>(
        x_movie, FMDIM, (const bf16x8*)wfm, enc_m_b, enc_m_g, enc_m_be, hmb16, mtM);

    // -------- layer-1: fused gather + dual MFMA + LN->relu, bf16 out --------
    sage1_fused_kernel<<<gbM, 256, 0, stream>>>(
        (const unsigned short*)hub16, rp, 0, nbr, (const bf16x8*)hmb16,
        (const bf16x8*)wf1ml, (const bf16x8*)wf1mr,
        c1_m_bl, ln1_m_g, ln1_m_b, m1b16, mtM);
    sage1_fused_kernel<<<gbU, 256, 0, stream>>>(
        (const unsigned short*)hmb16, rp, NM, nbr, (const bf16x8*)hub16,
        (const bf16x8*)wf1ul, (const bf16x8*)wf1ur,
        c1_u_bl, ln1_u_g, ln1_u_b, u1b16, mtU);

    // -------- layer-2: project 128->64 before aggregating; bf16 table out --------
    proj_kernel<8><<<(NU + 7) / 8, 64, 0, stream>>>((const unsigned short*)u1b16, c2_m_wl, pub16, NU);
    proj_kernel<8><<<(NM + 7) / 8, 64, 0, stream>>>((const unsigned short*)m1b16, c2_u_wl, pmb16, NM);

    // -------- final: fused gather64 + combine + LN -> d_out --------
    final_kernel<8><<<(NU + 7) / 8, 64, 0, stream>>>(
        (const unsigned short*)pmb16, rp, NM, nbr, (const unsigned short*)u1b16,
        c2_u_bl, c2_u_wr, ln2_u_g, ln2_u_b, out_u, NU);
    final_kernel<8><<<(NM + 7) / 8, 64, 0, stream>>>(
        (const unsigned short*)pub16, rp, 0, nbr, (const unsigned short*)m1b16,
        c2_m_bl, c2_m_wr, ln2_m_g, ln2_m_b, out_m, NM);
}